// Round 15
// baseline (2373.048 us; speedup 1.0000x reference)
//
#include <hip/hip_runtime.h>
#include <math.h>

// ---------- helpers ----------
__device__ __forceinline__ float silu_f(float x) { return x / (1.0f + __expf(-x)); }

// LayerNorm across a 64-lane wave; two reduce chains explicitly interleaved
__device__ __forceinline__ float ln64(float v, float g, float b) {
  float s = v, s2 = v * v;
#pragma unroll
  for (int m = 32; m > 0; m >>= 1) {
    s  += __shfl_xor(s,  m, 64);
    s2 += __shfl_xor(s2, m, 64);
  }
  float mean = s * 0.015625f;
  float var  = fmaxf(s2 * 0.015625f - mean * mean, 0.0f);
  return (v - mean) * rsqrtf(var + 1e-5f) * g + b;
}

// ---------- FUSED: node embed -> h, hw1/hw2(layer0), agg=0 ----------
__global__ __launch_bounds__(256) void k_embed_msgw(
    const float* __restrict__ x, const float* __restrict__ neW,
    const float* __restrict__ neB, const float* __restrict__ neG,
    const float* __restrict__ neBe, const float* __restrict__ W,   // msg_w[0], rows 0..127
    float* __restrict__ h, float* __restrict__ hw1, float* __restrict__ hw2,
    float* __restrict__ agg, int n) {
  __shared__ float sRow[4][64];
  const int row = (blockIdx.x * 256 + threadIdx.x) >> 6;
  const int wv = threadIdx.x >> 6;
  const int j  = threadIdx.x & 63;
  if (row >= n) return;

  const float* xr = x + (size_t)row * 16;
  float acc = neB[j];
#pragma unroll
  for (int k = 0; k < 16; k += 4) {
    float4 xv = *(const float4*)&xr[k];
    acc += xv.x * neW[(k + 0) * 64 + j] + xv.y * neW[(k + 1) * 64 + j] +
           xv.z * neW[(k + 2) * 64 + j] + xv.w * neW[(k + 3) * 64 + j];
  }
  float hv = silu_f(ln64(acc, neG[j], neBe[j]));
  h[(size_t)row * 64 + j] = hv;
  agg[(size_t)row * 64 + j] = 0.0f;
  sRow[wv][j] = hv;                    // same-wave write->read: ordered

  float a1 = 0.0f, a2 = 0.0f;
#pragma unroll
  for (int k = 0; k < 64; k += 4) {
    float4 r = *(const float4*)&sRow[wv][k];
    a1 += r.x * W[(k + 0) * 64 + j] + r.y * W[(k + 1) * 64 + j] +
          r.z * W[(k + 2) * 64 + j] + r.w * W[(k + 3) * 64 + j];
    a2 += r.x * W[(64 + k + 0) * 64 + j] + r.y * W[(64 + k + 1) * 64 + j] +
          r.z * W[(64 + k + 2) * 64 + j] + r.w * W[(64 + k + 3) * 64 + j];
  }
  hw1[(size_t)row * 64 + j] = a1;
  hw2[(size_t)row * 64 + j] = a2;
}

// ---------- edge embedding (ONCE, layer-independent): ebuf = silu(LN(ea@eeW)) ----------
__global__ __launch_bounds__(256) void k_edge_embed(
    const float* __restrict__ ea, const float* __restrict__ eeW,
    const float* __restrict__ eeB, const float* __restrict__ eeG,
    const float* __restrict__ eeBe, float* __restrict__ ebuf, int nedges) {
  __shared__ float sEA[4][32];         // per-wave 4 edges x 8 attrs

  const int wv = threadIdx.x >> 6;
  const int j  = threadIdx.x & 63;
  const int ebase = (blockIdx.x * 4 + wv) * 4;
  if (ebase >= nedges) return;

  if (j < 32) {
    long long gi = (long long)ebase * 8 + j;
    long long gmax = (long long)nedges * 8 - 1;
    if (gi > gmax) gi = gmax;
    sEA[wv][j] = ea[gi];               // same-wave write->read: ordered
  }

  float ewc[8];
#pragma unroll
  for (int k = 0; k < 8; ++k) ewc[k] = eeW[k * 64 + j];
  const float eb = eeB[j], eg = eeG[j], ebe = eeBe[j];

#pragma unroll
  for (int e = 0; e < 4; ++e) {
    const float* ar = &sEA[wv][e * 8];
    float ev = eb;
#pragma unroll
    for (int k = 0; k < 8; ++k) ev += ar[k] * ewc[k];
    ev = silu_f(ln64(ev, eg, ebe));
    if (ebase + e < nedges) ebuf[(size_t)(ebase + e) * 64 + j] = ev;
  }
}

// ---------- edge message: 16 edges/wave = 4 sequential groups of 4 ----------
// m = LN(silu(hw1[dst] + hw2[src] + e@W3 + msg_b)); agg[dst] += m
// All 4 groups' ebuf rows loaded up-front (HBM latency paid once), then the
// proven r12 body runs per group; unroll(1) stops cross-group reg hoisting.
#define EPW 4
#define GRP 4
__global__ __launch_bounds__(256) void k_edge_msg_pre4(
    const float* __restrict__ ebuf, const float* __restrict__ W3,
    const float* __restrict__ msgB, const float* __restrict__ msgG,
    const float* __restrict__ msgBe,
    const float* __restrict__ hw1, const float* __restrict__ hw2,
    const int* __restrict__ srcI, const int* __restrict__ dstI,
    float* __restrict__ agg, int nedges) {
  __shared__ float sE[4][GRP][EPW][64];   // 16 KB

  const int wv = threadIdx.x >> 6;
  const int j  = threadIdx.x & 63;
  const int wbase = (blockIdx.x * 4 + wv) * (EPW * GRP);
  if (wbase >= nedges) return;

  // stage all 16 e-rows: 4 coalesced float4 loads issued back-to-back
  {
    const long long gmax = (long long)nedges * 64 - 4;
    long long g0 = (long long)wbase * 64 + j * 4;
    long long t0 = g0;        if (t0 > gmax) t0 = gmax;
    long long t1 = g0 + 256;  if (t1 > gmax) t1 = gmax;
    long long t2 = g0 + 512;  if (t2 > gmax) t2 = gmax;
    long long t3 = g0 + 768;  if (t3 > gmax) t3 = gmax;
    float4 v0 = *(const float4*)&ebuf[t0];
    float4 v1 = *(const float4*)&ebuf[t1];
    float4 v2 = *(const float4*)&ebuf[t2];
    float4 v3 = *(const float4*)&ebuf[t3];
    *(float4*)&sE[wv][0][j >> 4][(j & 15) * 4] = v0;   // same-wave: ordered
    *(float4*)&sE[wv][1][j >> 4][(j & 15) * 4] = v1;
    *(float4*)&sE[wv][2][j >> 4][(j & 15) * 4] = v2;
    *(float4*)&sE[wv][3][j >> 4][(j & 15) * 4] = v3;
  }

  const float bj = msgB[j], mg = msgG[j], mbe = msgBe[j];

#pragma unroll 1   // groups sequential BY DESIGN: no cross-group reg pressure
  for (int grp = 0; grp < GRP; ++grp) {
    const int ebase = wbase + grp * EPW;

    // gathers issued at group top; consumed only in epilogue (MAC hides them)
    int dIdx[EPW];
    float g1[EPW], g2[EPW];
#pragma unroll
    for (int e = 0; e < EPW; ++e) {
      int ce = min(ebase + e, nedges - 1);
      int s = srcI[ce];
      dIdx[e] = dstI[ce];
      g1[e] = hw1[(size_t)dIdx[e] * 64 + j];
      g2[e] = hw2[(size_t)s * 64 + j];
    }

    // MAC from LDS + L1-resident W3
    float macc[EPW] = {0.f, 0.f, 0.f, 0.f};
#pragma unroll
    for (int k = 0; k < 64; k += 4) {
      float w0 = W3[(k + 0) * 64 + j];
      float w1 = W3[(k + 1) * 64 + j];
      float w2 = W3[(k + 2) * 64 + j];
      float w3 = W3[(k + 3) * 64 + j];
#pragma unroll
      for (int e = 0; e < EPW; ++e) {
        float4 ev4 = *(const float4*)&sE[wv][grp][e][k];
        macc[e] += ev4.x * w0 + ev4.y * w1 + ev4.z * w2 + ev4.w * w3;
      }
    }

    // epilogue: fold gathers + bias, silu, LN, scatter-add
#pragma unroll
    for (int e = 0; e < EPW; ++e) {
      float m = ln64(silu_f(macc[e] + g1[e] + g2[e] + bj), mg, mbe);
      if (ebase + e < nedges) unsafeAtomicAdd(&agg[(size_t)dIdx[e] * 64 + j], m);
    }
  }
}

// ---------- edge message FALLBACK (ws too small): r9 proven kernel ----------
__global__ __launch_bounds__(256) void k_edge_msg_fb(
    const float* __restrict__ ea, const float* __restrict__ eeW,
    const float* __restrict__ eeB, const float* __restrict__ eeG,
    const float* __restrict__ eeBe,
    const float* __restrict__ W3, const float* __restrict__ msgB,
    const float* __restrict__ msgG, const float* __restrict__ msgBe,
    const float* __restrict__ hw1, const float* __restrict__ hw2,
    const int* __restrict__ srcI, const int* __restrict__ dstI,
    float* __restrict__ agg, int nedges) {
  __shared__ float sE[4][EPW][64];
  __shared__ float sEA[4][EPW * 8];

  const int wv = threadIdx.x >> 6;
  const int j  = threadIdx.x & 63;
  const int ebase = (blockIdx.x * 4 + wv) * EPW;
  if (ebase >= nedges) return;

  if (j < 32) {
    long long gi = (long long)ebase * 8 + j;
    long long gmax = (long long)nedges * 8 - 1;
    if (gi > gmax) gi = gmax;
    sEA[wv][j] = ea[gi];
  }

  const float bj = msgB[j];
  int dIdx[EPW];
  float acc[EPW];
#pragma unroll
  for (int e = 0; e < EPW; ++e) {
    int ce = min(ebase + e, nedges - 1);
    int s = srcI[ce];
    dIdx[e] = dstI[ce];
    acc[e] = hw1[(size_t)dIdx[e] * 64 + j] + hw2[(size_t)s * 64 + j] + bj;
  }
  {
    float ewc[8];
#pragma unroll
    for (int k = 0; k < 8; ++k) ewc[k] = eeW[k * 64 + j];
    const float eb = eeB[j], eg = eeG[j], ebe = eeBe[j];
#pragma unroll
    for (int e = 0; e < EPW; ++e) {
      const float* ar = &sEA[wv][e * 8];
      float ev = eb;
#pragma unroll
      for (int k = 0; k < 8; ++k) ev += ar[k] * ewc[k];
      ev = silu_f(ln64(ev, eg, ebe));
      sE[wv][e][j] = ev;
    }
  }
#pragma unroll
  for (int k = 0; k < 64; k += 4) {
    float w0 = W3[(k + 0) * 64 + j];
    float w1 = W3[(k + 1) * 64 + j];
    float w2 = W3[(k + 2) * 64 + j];
    float w3 = W3[(k + 3) * 64 + j];
#pragma unroll
    for (int e = 0; e < EPW; ++e) {
      float4 ev4 = *(const float4*)&sE[wv][e][k];
      acc[e] += ev4.x * w0 + ev4.y * w1 + ev4.z * w2 + ev4.w * w3;
    }
  }
  const float mg = msgG[j], mbe = msgBe[j];
#pragma unroll
  for (int e = 0; e < EPW; ++e) {
    float m = ln64(silu_f(acc[e]), mg, mbe);
    if (ebase + e < nedges) unsafeAtomicAdd(&agg[(size_t)dIdx[e] * 64 + j], m);
  }
}

// ---------- FUSED: update(in-place) -> hw1/hw2(next layer), agg=0 ----------
__global__ __launch_bounds__(256) void k_update_msgw(
    float* h, float* agg,                       // agg read then zeroed
    const float* __restrict__ W, const float* __restrict__ b,
    const float* __restrict__ ug, const float* __restrict__ ube,
    const float* __restrict__ ng, const float* __restrict__ nbe,
    const float* __restrict__ Wn,               // next layer msg_w rows 0..127
    float* __restrict__ hw1, float* __restrict__ hw2, int n) {
  __shared__ float sRow[4][64];
  const int row = (blockIdx.x * 256 + threadIdx.x) >> 6;
  const int wv = threadIdx.x >> 6;
  const int j  = threadIdx.x & 63;
  if (row >= n) return;

  float* hr = h + (size_t)row * 64;
  float* ar = agg + (size_t)row * 64;
  float acc = b[j];
  float hj = hr[j];
#pragma unroll
  for (int k = 0; k < 64; k += 4) {
    float4 hv = *(const float4*)&hr[k];
    float4 av = *(const float4*)&ar[k];
    acc += (hv.x + av.x) * W[(k + 0) * 64 + j] + (hv.y + av.y) * W[(k + 1) * 64 + j] +
           (hv.z + av.z) * W[(k + 2) * 64 + j] + (hv.w + av.w) * W[(k + 3) * 64 + j];
  }
  float u = ln64(silu_f(acc), ug[j], ube[j]);
  float hn = ln64(u + hj, ng[j], nbe[j]);
  hr[j] = hn;
  ar[j] = 0.0f;                        // zero agg for next layer
  sRow[wv][j] = hn;                    // same-wave ordered

  float a1 = 0.0f, a2 = 0.0f;
#pragma unroll
  for (int k = 0; k < 64; k += 4) {
    float4 r = *(const float4*)&sRow[wv][k];
    a1 += r.x * Wn[(k + 0) * 64 + j] + r.y * Wn[(k + 1) * 64 + j] +
          r.z * Wn[(k + 2) * 64 + j] + r.w * Wn[(k + 3) * 64 + j];
    a2 += r.x * Wn[(64 + k + 0) * 64 + j] + r.y * Wn[(64 + k + 1) * 64 + j] +
          r.z * Wn[(64 + k + 2) * 64 + j] + r.w * Wn[(64 + k + 3) * 64 + j];
  }
  hw1[(size_t)row * 64 + j] = a1;
  hw2[(size_t)row * 64 + j] = a2;
}

// ---------- FUSED: final update(in-place) -> pool atomics ----------
__global__ __launch_bounds__(256) void k_update_pool(
    float* h, const float* __restrict__ agg,
    const float* __restrict__ W, const float* __restrict__ b,
    const float* __restrict__ ug, const float* __restrict__ ube,
    const float* __restrict__ ng, const float* __restrict__ nbe,
    const int* __restrict__ batch, float* __restrict__ gsum,
    float* __restrict__ gcnt, int n) {
  const int row = (blockIdx.x * 256 + threadIdx.x) >> 6;
  const int j  = threadIdx.x & 63;
  if (row >= n) return;

  float* hr = h + (size_t)row * 64;
  const float* ar = agg + (size_t)row * 64;
  float acc = b[j];
  float hj = hr[j];
#pragma unroll
  for (int k = 0; k < 64; k += 4) {
    float4 hv = *(const float4*)&hr[k];
    float4 av = *(const float4*)&ar[k];
    acc += (hv.x + av.x) * W[(k + 0) * 64 + j] + (hv.y + av.y) * W[(k + 1) * 64 + j] +
           (hv.z + av.z) * W[(k + 2) * 64 + j] + (hv.w + av.w) * W[(k + 3) * 64 + j];
  }
  float u = ln64(silu_f(acc), ug[j], ube[j]);
  float hn = ln64(u + hj, ng[j], nbe[j]);

  int bb = batch[row];
  unsafeAtomicAdd(&gsum[(size_t)bb * 64 + j], hn);
  if (j == 0) unsafeAtomicAdd(&gcnt[bb], 1.0f);
}

// ---------- head: out = silu(LN(g@h1_w+b)) @ h2_w + h2_b ----------
__global__ __launch_bounds__(64) void k_head(
    const float* __restrict__ gsum, const float* __restrict__ gcnt,
    const float* __restrict__ w1, const float* __restrict__ b1,
    const float* __restrict__ g1, const float* __restrict__ be1,
    const float* __restrict__ w2, const float* __restrict__ b2,
    float* __restrict__ out, int ngraphs) {
  int gidx = blockIdx.x;
  int j = threadIdx.x;
  if (gidx >= ngraphs) return;
  __shared__ float sg[64];
  float cnt = fmaxf(gcnt[gidx], 1.0f);
  sg[j] = gsum[(size_t)gidx * 64 + j] / cnt;
  float acc = 0.0f;
  if (j < 32) {
    acc = b1[j];
#pragma unroll 8
    for (int k = 0; k < 64; ++k) acc += sg[k] * w1[k * 32 + j];
  }
  float s = acc, s2 = acc * acc;
#pragma unroll
  for (int m = 16; m > 0; m >>= 1) {
    s  += __shfl_xor(s,  m, 64);
    s2 += __shfl_xor(s2, m, 64);
  }
  float mean = s * 0.03125f;
  float var  = fmaxf(s2 * 0.03125f - mean * mean, 0.0f);
  float z = 0.0f;
  if (j < 32) {
    float nv = (acc - mean) * rsqrtf(var + 1e-5f) * g1[j] + be1[j];
    z = silu_f(nv) * w2[j];
  }
#pragma unroll
  for (int m = 32; m > 0; m >>= 1) z += __shfl_xor(z, m, 64);
  if (j == 0) out[gidx] = z + b2[0];
}

// ---------- launch ----------
extern "C" void kernel_launch(void* const* d_in, const int* in_sizes, int n_in,
                              void* d_out, int out_size, void* d_ws, size_t ws_size,
                              hipStream_t stream) {
  const float* x      = (const float*)d_in[0];
  const float* ea     = (const float*)d_in[1];
  const float* ne_w   = (const float*)d_in[2];
  const float* ne_b   = (const float*)d_in[3];
  const float* ne_g   = (const float*)d_in[4];
  const float* ne_be  = (const float*)d_in[5];
  const float* ee_w   = (const float*)d_in[6];
  const float* ee_b   = (const float*)d_in[7];
  const float* ee_g   = (const float*)d_in[8];
  const float* ee_be  = (const float*)d_in[9];
  const float* msg_w  = (const float*)d_in[10];
  const float* msg_b  = (const float*)d_in[11];
  const float* msg_g  = (const float*)d_in[12];
  const float* msg_be = (const float*)d_in[13];
  const float* upd_w  = (const float*)d_in[14];
  const float* upd_b  = (const float*)d_in[15];
  const float* upd_g  = (const float*)d_in[16];
  const float* upd_be = (const float*)d_in[17];
  const float* nrm_g  = (const float*)d_in[18];
  const float* nrm_be = (const float*)d_in[19];
  const float* h1_w   = (const float*)d_in[20];
  const float* h1_b   = (const float*)d_in[21];
  const float* h1_g   = (const float*)d_in[22];
  const float* h1_be  = (const float*)d_in[23];
  const float* h2_w   = (const float*)d_in[24];
  const float* h2_b   = (const float*)d_in[25];
  const int*   ei     = (const int*)d_in[26];
  const int*   batch  = (const int*)d_in[27];
  float* out = (float*)d_out;

  const int N = in_sizes[0] / 16;
  const int E = in_sizes[1] / 8;
  const int G = out_size;
  const int* srcI = ei;       // edge_index[0] = src (x_j)
  const int* dstI = ei + E;   // edge_index[1] = dst (x_i)

  float* ws  = (float*)d_ws;
  float* h    = ws;
  float* hw1  = h   + (size_t)N * 64;
  float* hw2  = hw1 + (size_t)N * 64;
  float* agg  = hw2 + (size_t)N * 64;
  float* gsum = agg + (size_t)N * 64;
  float* gcnt = gsum + (size_t)G * 64;
  float* ebuf = gcnt + G;     // pre path: [E,64] edge embeddings

  const size_t fixed_floats = (size_t)N * 64 * 4 + (size_t)G * 64 + G;
  const bool pre = (ws_size / 4 >= fixed_floats + (size_t)E * 64);

  const int nblk  = (N + 3) / 4;                     // 4 node rows per block
  const int eblkE = (E + 15) / 16;                   // edge-embed blocks
  const int eblkP = (E + 63) / 64;                   // 64 edges per block (pre4)
  const int eblkF = (E + 15) / 16;                   // fallback blocks

  // embed + msgw(layer0) + agg=0
  k_embed_msgw<<<nblk, 256, 0, stream>>>(
      x, ne_w, ne_b, ne_g, ne_be, msg_w, h, hw1, hw2, agg, N);
  if (pre)
    k_edge_embed<<<eblkE, 256, 0, stream>>>(ea, ee_w, ee_b, ee_g, ee_be, ebuf, E);

  // ---- layer 0 ----
  if (pre) {
    k_edge_msg_pre4<<<eblkP, 256, 0, stream>>>(
        ebuf, msg_w + 128 * 64, msg_b, msg_g, msg_be,
        hw1, hw2, srcI, dstI, agg, E);
  } else {
    k_edge_msg_fb<<<eblkF, 256, 0, stream>>>(
        ea, ee_w, ee_b, ee_g, ee_be,
        msg_w + 128 * 64, msg_b, msg_g, msg_be,
        hw1, hw2, srcI, dstI, agg, E);
  }
  // update(l=0) + msgw(layer1) + agg=0
  k_update_msgw<<<nblk, 256, 0, stream>>>(
      h, agg, upd_w, upd_b, upd_g, upd_be, nrm_g, nrm_be,
      msg_w + (size_t)192 * 64, hw1, hw2, N);

  // ---- layer 1 ----
  if (pre) {
    k_edge_msg_pre4<<<eblkP, 256, 0, stream>>>(
        ebuf, msg_w + (size_t)192 * 64 + 128 * 64, msg_b + 64, msg_g + 64,
        msg_be + 64, hw1, hw2, srcI, dstI, agg, E);
  } else {
    k_edge_msg_fb<<<eblkF, 256, 0, stream>>>(
        ea, ee_w, ee_b, ee_g, ee_be,
        msg_w + (size_t)192 * 64 + 128 * 64, msg_b + 64, msg_g + 64,
        msg_be + 64, hw1, hw2, srcI, dstI, agg, E);
  }
  hipMemsetAsync(gsum, 0, ((size_t)G * 64 + G) * sizeof(float), stream);
  // update(l=1) + pool
  k_update_pool<<<nblk, 256, 0, stream>>>(
      h, agg, upd_w + (size_t)64 * 64, upd_b + 64, upd_g + 64, upd_be + 64,
      nrm_g + 64, nrm_be + 64, batch, gsum, gcnt, N);

  k_head<<<G, 64, 0, stream>>>(gsum, gcnt, h1_w, h1_b, h1_g, h1_be, h2_w, h2_b, out, G);
}

// Round 16
// 1195.640 us; speedup vs baseline: 1.9848x; 1.9848x over previous
//
#include <hip/hip_runtime.h>
#include <math.h>

// ---------- helpers ----------
__device__ __forceinline__ float silu_f(float x) { return x / (1.0f + __expf(-x)); }

// LayerNorm across a 64-lane wave; two reduce chains explicitly interleaved
__device__ __forceinline__ float ln64(float v, float g, float b) {
  float s = v, s2 = v * v;
#pragma unroll
  for (int m = 32; m > 0; m >>= 1) {
    s  += __shfl_xor(s,  m, 64);
    s2 += __shfl_xor(s2, m, 64);
  }
  float mean = s * 0.015625f;
  float var  = fmaxf(s2 * 0.015625f - mean * mean, 0.0f);
  return (v - mean) * rsqrtf(var + 1e-5f) * g + b;
}

// ---------- FUSED: node embed -> h, hw1/hw2(layer0), agg=0 ----------
__global__ __launch_bounds__(256) void k_embed_msgw(
    const float* __restrict__ x, const float* __restrict__ neW,
    const float* __restrict__ neB, const float* __restrict__ neG,
    const float* __restrict__ neBe, const float* __restrict__ W,   // msg_w[0], rows 0..127
    float* __restrict__ h, float* __restrict__ hw1, float* __restrict__ hw2,
    float* __restrict__ agg, int n) {
  __shared__ float sRow[4][64];
  const int row = (blockIdx.x * 256 + threadIdx.x) >> 6;
  const int wv = threadIdx.x >> 6;
  const int j  = threadIdx.x & 63;
  if (row >= n) return;

  const float* xr = x + (size_t)row * 16;
  float acc = neB[j];
#pragma unroll
  for (int k = 0; k < 16; k += 4) {
    float4 xv = *(const float4*)&xr[k];
    acc += xv.x * neW[(k + 0) * 64 + j] + xv.y * neW[(k + 1) * 64 + j] +
           xv.z * neW[(k + 2) * 64 + j] + xv.w * neW[(k + 3) * 64 + j];
  }
  float hv = silu_f(ln64(acc, neG[j], neBe[j]));
  h[(size_t)row * 64 + j] = hv;
  agg[(size_t)row * 64 + j] = 0.0f;
  sRow[wv][j] = hv;                    // same-wave write->read: ordered

  float a1 = 0.0f, a2 = 0.0f;
#pragma unroll
  for (int k = 0; k < 64; k += 4) {
    float4 r = *(const float4*)&sRow[wv][k];
    a1 += r.x * W[(k + 0) * 64 + j] + r.y * W[(k + 1) * 64 + j] +
          r.z * W[(k + 2) * 64 + j] + r.w * W[(k + 3) * 64 + j];
    a2 += r.x * W[(64 + k + 0) * 64 + j] + r.y * W[(64 + k + 1) * 64 + j] +
          r.z * W[(64 + k + 2) * 64 + j] + r.w * W[(64 + k + 3) * 64 + j];
  }
  hw1[(size_t)row * 64 + j] = a1;
  hw2[(size_t)row * 64 + j] = a2;
}

// ---------- edge embedding (ONCE, layer-independent): ebuf = silu(LN(ea@eeW)) ----------
__global__ __launch_bounds__(256) void k_edge_embed(
    const float* __restrict__ ea, const float* __restrict__ eeW,
    const float* __restrict__ eeB, const float* __restrict__ eeG,
    const float* __restrict__ eeBe, float* __restrict__ ebuf, int nedges) {
  __shared__ float sEA[4][32];         // per-wave 4 edges x 8 attrs

  const int wv = threadIdx.x >> 6;
  const int j  = threadIdx.x & 63;
  const int ebase = (blockIdx.x * 4 + wv) * 4;
  if (ebase >= nedges) return;

  if (j < 32) {
    long long gi = (long long)ebase * 8 + j;
    long long gmax = (long long)nedges * 8 - 1;
    if (gi > gmax) gi = gmax;
    sEA[wv][j] = ea[gi];               // same-wave write->read: ordered
  }

  float ewc[8];
#pragma unroll
  for (int k = 0; k < 8; ++k) ewc[k] = eeW[k * 64 + j];
  const float eb = eeB[j], eg = eeG[j], ebe = eeBe[j];

#pragma unroll
  for (int e = 0; e < 4; ++e) {
    const float* ar = &sEA[wv][e * 8];
    float ev = eb;
#pragma unroll
    for (int k = 0; k < 8; ++k) ev += ar[k] * ewc[k];
    ev = silu_f(ln64(ev, eg, ebe));
    if (ebase + e < nedges) ebuf[(size_t)(ebase + e) * 64 + j] = ev;
  }
}

// ---------- edge message (r12 proven body, 2-wave/128-thread blocks) ----------
// m = LN(silu(hw1[dst] + hw2[src] + e@W3 + msg_b)); agg[dst] += m
#define EPW 4
__global__ __launch_bounds__(128) void k_edge_msg_pre2(
    const float* __restrict__ ebuf, const float* __restrict__ W3,
    const float* __restrict__ msgB, const float* __restrict__ msgG,
    const float* __restrict__ msgBe,
    const float* __restrict__ hw1, const float* __restrict__ hw2,
    const int* __restrict__ srcI, const int* __restrict__ dstI,
    float* __restrict__ agg, int nedges) {
  __shared__ float sE[2][EPW][64];     // 2 KB

  const int wv = threadIdx.x >> 6;     // 0..1
  const int j  = threadIdx.x & 63;
  const int ebase = (blockIdx.x * 2 + wv) * EPW;
  if (ebase >= nedges) return;

  // coalesced e-row staging: lane j -> edge (j>>4), cols (j&15)*4 .. +3
  {
    long long gi = (long long)ebase * 64 + j * 4;
    long long gmax = (long long)nedges * 64 - 4;
    if (gi > gmax) gi = gmax;
    float4 v = *(const float4*)&ebuf[gi];
    *(float4*)&sE[wv][j >> 4][(j & 15) * 4] = v;   // same-wave: ordered
  }

  // gathers issued up-front; results not needed until epilogue
  int dIdx[EPW];
  float g1[EPW], g2[EPW];
#pragma unroll
  for (int e = 0; e < EPW; ++e) {
    int ce = min(ebase + e, nedges - 1);
    int s = srcI[ce];
    dIdx[e] = dstI[ce];
    g1[e] = hw1[(size_t)dIdx[e] * 64 + j];
    g2[e] = hw2[(size_t)s * 64 + j];
  }

  // MAC from LDS + L1-resident W3
  float macc[EPW] = {0.f, 0.f, 0.f, 0.f};
#pragma unroll
  for (int k = 0; k < 64; k += 4) {
    float w0 = W3[(k + 0) * 64 + j];
    float w1 = W3[(k + 1) * 64 + j];
    float w2 = W3[(k + 2) * 64 + j];
    float w3 = W3[(k + 3) * 64 + j];
#pragma unroll
    for (int e = 0; e < EPW; ++e) {
      float4 ev4 = *(const float4*)&sE[wv][e][k];
      macc[e] += ev4.x * w0 + ev4.y * w1 + ev4.z * w2 + ev4.w * w3;
    }
  }

  // epilogue: fold gathers + bias, silu, LN, scatter-add
  const float bj = msgB[j], mg = msgG[j], mbe = msgBe[j];
#pragma unroll
  for (int e = 0; e < EPW; ++e) {
    float m = ln64(silu_f(macc[e] + g1[e] + g2[e] + bj), mg, mbe);
    if (ebase + e < nedges) unsafeAtomicAdd(&agg[(size_t)dIdx[e] * 64 + j], m);
  }
}

// ---------- edge message FALLBACK (ws too small): r9 proven kernel ----------
__global__ __launch_bounds__(256) void k_edge_msg_fb(
    const float* __restrict__ ea, const float* __restrict__ eeW,
    const float* __restrict__ eeB, const float* __restrict__ eeG,
    const float* __restrict__ eeBe,
    const float* __restrict__ W3, const float* __restrict__ msgB,
    const float* __restrict__ msgG, const float* __restrict__ msgBe,
    const float* __restrict__ hw1, const float* __restrict__ hw2,
    const int* __restrict__ srcI, const int* __restrict__ dstI,
    float* __restrict__ agg, int nedges) {
  __shared__ float sE[4][EPW][64];
  __shared__ float sEA[4][EPW * 8];

  const int wv = threadIdx.x >> 6;
  const int j  = threadIdx.x & 63;
  const int ebase = (blockIdx.x * 4 + wv) * EPW;
  if (ebase >= nedges) return;

  if (j < 32) {
    long long gi = (long long)ebase * 8 + j;
    long long gmax = (long long)nedges * 8 - 1;
    if (gi > gmax) gi = gmax;
    sEA[wv][j] = ea[gi];
  }

  const float bj = msgB[j];
  int dIdx[EPW];
  float acc[EPW];
#pragma unroll
  for (int e = 0; e < EPW; ++e) {
    int ce = min(ebase + e, nedges - 1);
    int s = srcI[ce];
    dIdx[e] = dstI[ce];
    acc[e] = hw1[(size_t)dIdx[e] * 64 + j] + hw2[(size_t)s * 64 + j] + bj;
  }
  {
    float ewc[8];
#pragma unroll
    for (int k = 0; k < 8; ++k) ewc[k] = eeW[k * 64 + j];
    const float eb = eeB[j], eg = eeG[j], ebe = eeBe[j];
#pragma unroll
    for (int e = 0; e < EPW; ++e) {
      const float* ar = &sEA[wv][e * 8];
      float ev = eb;
#pragma unroll
      for (int k = 0; k < 8; ++k) ev += ar[k] * ewc[k];
      ev = silu_f(ln64(ev, eg, ebe));
      sE[wv][e][j] = ev;
    }
  }
#pragma unroll
  for (int k = 0; k < 64; k += 4) {
    float w0 = W3[(k + 0) * 64 + j];
    float w1 = W3[(k + 1) * 64 + j];
    float w2 = W3[(k + 2) * 64 + j];
    float w3 = W3[(k + 3) * 64 + j];
#pragma unroll
    for (int e = 0; e < EPW; ++e) {
      float4 ev4 = *(const float4*)&sE[wv][e][k];
      acc[e] += ev4.x * w0 + ev4.y * w1 + ev4.z * w2 + ev4.w * w3;
    }
  }
  const float mg = msgG[j], mbe = msgBe[j];
#pragma unroll
  for (int e = 0; e < EPW; ++e) {
    float m = ln64(silu_f(acc[e]), mg, mbe);
    if (ebase + e < nedges) unsafeAtomicAdd(&agg[(size_t)dIdx[e] * 64 + j], m);
  }
}

// ---------- FUSED: update(in-place) -> hw1/hw2(next layer), agg=0 ----------
__global__ __launch_bounds__(256) void k_update_msgw(
    float* h, float* agg,                       // agg read then zeroed
    const float* __restrict__ W, const float* __restrict__ b,
    const float* __restrict__ ug, const float* __restrict__ ube,
    const float* __restrict__ ng, const float* __restrict__ nbe,
    const float* __restrict__ Wn,               // next layer msg_w rows 0..127
    float* __restrict__ hw1, float* __restrict__ hw2, int n) {
  __shared__ float sRow[4][64];
  const int row = (blockIdx.x * 256 + threadIdx.x) >> 6;
  const int wv = threadIdx.x >> 6;
  const int j  = threadIdx.x & 63;
  if (row >= n) return;

  float* hr = h + (size_t)row * 64;
  float* ar = agg + (size_t)row * 64;
  float acc = b[j];
  float hj = hr[j];
#pragma unroll
  for (int k = 0; k < 64; k += 4) {
    float4 hv = *(const float4*)&hr[k];
    float4 av = *(const float4*)&ar[k];
    acc += (hv.x + av.x) * W[(k + 0) * 64 + j] + (hv.y + av.y) * W[(k + 1) * 64 + j] +
           (hv.z + av.z) * W[(k + 2) * 64 + j] + (hv.w + av.w) * W[(k + 3) * 64 + j];
  }
  float u = ln64(silu_f(acc), ug[j], ube[j]);
  float hn = ln64(u + hj, ng[j], nbe[j]);
  hr[j] = hn;
  ar[j] = 0.0f;                        // zero agg for next layer
  sRow[wv][j] = hn;                    // same-wave ordered

  float a1 = 0.0f, a2 = 0.0f;
#pragma unroll
  for (int k = 0; k < 64; k += 4) {
    float4 r = *(const float4*)&sRow[wv][k];
    a1 += r.x * Wn[(k + 0) * 64 + j] + r.y * Wn[(k + 1) * 64 + j] +
          r.z * Wn[(k + 2) * 64 + j] + r.w * Wn[(k + 3) * 64 + j];
    a2 += r.x * Wn[(64 + k + 0) * 64 + j] + r.y * Wn[(64 + k + 1) * 64 + j] +
          r.z * Wn[(64 + k + 2) * 64 + j] + r.w * Wn[(64 + k + 3) * 64 + j];
  }
  hw1[(size_t)row * 64 + j] = a1;
  hw2[(size_t)row * 64 + j] = a2;
}

// ---------- FUSED: final update(in-place) -> pool atomics ----------
__global__ __launch_bounds__(256) void k_update_pool(
    float* h, const float* __restrict__ agg,
    const float* __restrict__ W, const float* __restrict__ b,
    const float* __restrict__ ug, const float* __restrict__ ube,
    const float* __restrict__ ng, const float* __restrict__ nbe,
    const int* __restrict__ batch, float* __restrict__ gsum,
    float* __restrict__ gcnt, int n) {
  const int row = (blockIdx.x * 256 + threadIdx.x) >> 6;
  const int j  = threadIdx.x & 63;
  if (row >= n) return;

  float* hr = h + (size_t)row * 64;
  const float* ar = agg + (size_t)row * 64;
  float acc = b[j];
  float hj = hr[j];
#pragma unroll
  for (int k = 0; k < 64; k += 4) {
    float4 hv = *(const float4*)&hr[k];
    float4 av = *(const float4*)&ar[k];
    acc += (hv.x + av.x) * W[(k + 0) * 64 + j] + (hv.y + av.y) * W[(k + 1) * 64 + j] +
           (hv.z + av.z) * W[(k + 2) * 64 + j] + (hv.w + av.w) * W[(k + 3) * 64 + j];
  }
  float u = ln64(silu_f(acc), ug[j], ube[j]);
  float hn = ln64(u + hj, ng[j], nbe[j]);

  int bb = batch[row];
  unsafeAtomicAdd(&gsum[(size_t)bb * 64 + j], hn);
  if (j == 0) unsafeAtomicAdd(&gcnt[bb], 1.0f);
}

// ---------- head: out = silu(LN(g@h1_w+b)) @ h2_w + h2_b ----------
__global__ __launch_bounds__(64) void k_head(
    const float* __restrict__ gsum, const float* __restrict__ gcnt,
    const float* __restrict__ w1, const float* __restrict__ b1,
    const float* __restrict__ g1, const float* __restrict__ be1,
    const float* __restrict__ w2, const float* __restrict__ b2,
    float* __restrict__ out, int ngraphs) {
  int gidx = blockIdx.x;
  int j = threadIdx.x;
  if (gidx >= ngraphs) return;
  __shared__ float sg[64];
  float cnt = fmaxf(gcnt[gidx], 1.0f);
  sg[j] = gsum[(size_t)gidx * 64 + j] / cnt;
  float acc = 0.0f;
  if (j < 32) {
    acc = b1[j];
#pragma unroll 8
    for (int k = 0; k < 64; ++k) acc += sg[k] * w1[k * 32 + j];
  }
  float s = acc, s2 = acc * acc;
#pragma unroll
  for (int m = 16; m > 0; m >>= 1) {
    s  += __shfl_xor(s,  m, 64);
    s2 += __shfl_xor(s2, m, 64);
  }
  float mean = s * 0.03125f;
  float var  = fmaxf(s2 * 0.03125f - mean * mean, 0.0f);
  float z = 0.0f;
  if (j < 32) {
    float nv = (acc - mean) * rsqrtf(var + 1e-5f) * g1[j] + be1[j];
    z = silu_f(nv) * w2[j];
  }
#pragma unroll
  for (int m = 32; m > 0; m >>= 1) z += __shfl_xor(z, m, 64);
  if (j == 0) out[gidx] = z + b2[0];
}

// ---------- launch ----------
extern "C" void kernel_launch(void* const* d_in, const int* in_sizes, int n_in,
                              void* d_out, int out_size, void* d_ws, size_t ws_size,
                              hipStream_t stream) {
  const float* x      = (const float*)d_in[0];
  const float* ea     = (const float*)d_in[1];
  const float* ne_w   = (const float*)d_in[2];
  const float* ne_b   = (const float*)d_in[3];
  const float* ne_g   = (const float*)d_in[4];
  const float* ne_be  = (const float*)d_in[5];
  const float* ee_w   = (const float*)d_in[6];
  const float* ee_b   = (const float*)d_in[7];
  const float* ee_g   = (const float*)d_in[8];
  const float* ee_be  = (const float*)d_in[9];
  const float* msg_w  = (const float*)d_in[10];
  const float* msg_b  = (const float*)d_in[11];
  const float* msg_g  = (const float*)d_in[12];
  const float* msg_be = (const float*)d_in[13];
  const float* upd_w  = (const float*)d_in[14];
  const float* upd_b  = (const float*)d_in[15];
  const float* upd_g  = (const float*)d_in[16];
  const float* upd_be = (const float*)d_in[17];
  const float* nrm_g  = (const float*)d_in[18];
  const float* nrm_be = (const float*)d_in[19];
  const float* h1_w   = (const float*)d_in[20];
  const float* h1_b   = (const float*)d_in[21];
  const float* h1_g   = (const float*)d_in[22];
  const float* h1_be  = (const float*)d_in[23];
  const float* h2_w   = (const float*)d_in[24];
  const float* h2_b   = (const float*)d_in[25];
  const int*   ei     = (const int*)d_in[26];
  const int*   batch  = (const int*)d_in[27];
  float* out = (float*)d_out;

  const int N = in_sizes[0] / 16;
  const int E = in_sizes[1] / 8;
  const int G = out_size;
  const int* srcI = ei;       // edge_index[0] = src (x_j)
  const int* dstI = ei + E;   // edge_index[1] = dst (x_i)

  float* ws  = (float*)d_ws;
  float* h    = ws;
  float* hw1  = h   + (size_t)N * 64;
  float* hw2  = hw1 + (size_t)N * 64;
  float* agg  = hw2 + (size_t)N * 64;
  float* gsum = agg + (size_t)N * 64;
  float* gcnt = gsum + (size_t)G * 64;
  float* ebuf = gcnt + G;     // pre path: [E,64] edge embeddings

  const size_t fixed_floats = (size_t)N * 64 * 4 + (size_t)G * 64 + G;
  const bool pre = (ws_size / 4 >= fixed_floats + (size_t)E * 64);

  const int nblk  = (N + 3) / 4;                     // 4 node rows per block
  const int eblkE = (E + 15) / 16;                   // edge-embed blocks
  const int eblkP = (E + 2 * EPW - 1) / (2 * EPW);   // 8 edges / 128-thr block
  const int eblkF = (E + 15) / 16;                   // fallback blocks

  // embed + msgw(layer0) + agg=0
  k_embed_msgw<<<nblk, 256, 0, stream>>>(
      x, ne_w, ne_b, ne_g, ne_be, msg_w, h, hw1, hw2, agg, N);
  if (pre)
    k_edge_embed<<<eblkE, 256, 0, stream>>>(ea, ee_w, ee_b, ee_g, ee_be, ebuf, E);

  // ---- layer 0 ----
  if (pre) {
    k_edge_msg_pre2<<<eblkP, 128, 0, stream>>>(
        ebuf, msg_w + 128 * 64, msg_b, msg_g, msg_be,
        hw1, hw2, srcI, dstI, agg, E);
  } else {
    k_edge_msg_fb<<<eblkF, 256, 0, stream>>>(
        ea, ee_w, ee_b, ee_g, ee_be,
        msg_w + 128 * 64, msg_b, msg_g, msg_be,
        hw1, hw2, srcI, dstI, agg, E);
  }
  // update(l=0) + msgw(layer1) + agg=0
  k_update_msgw<<<nblk, 256, 0, stream>>>(
      h, agg, upd_w, upd_b, upd_g, upd_be, nrm_g, nrm_be,
      msg_w + (size_t)192 * 64, hw1, hw2, N);

  // ---- layer 1 ----
  if (pre) {
    k_edge_msg_pre2<<<eblkP, 128, 0, stream>>>(
        ebuf, msg_w + (size_t)192 * 64 + 128 * 64, msg_b + 64, msg_g + 64,
        msg_be + 64, hw1, hw2, srcI, dstI, agg, E);
  } else {
    k_edge_msg_fb<<<eblkF, 256, 0, stream>>>(
        ea, ee_w, ee_b, ee_g, ee_be,
        msg_w + (size_t)192 * 64 + 128 * 64, msg_b + 64, msg_g + 64,
        msg_be + 64, hw1, hw2, srcI, dstI, agg, E);
  }
  hipMemsetAsync(gsum, 0, ((size_t)G * 64 + G) * sizeof(float), stream);
  // update(l=1) + pool
  k_update_pool<<<nblk, 256, 0, stream>>>(
      h, agg, upd_w + (size_t)64 * 64, upd_b + 64, upd_g + 64, upd_be + 64,
      nrm_g + 64, nrm_be + 64, batch, gsum, gcnt, N);

  k_head<<<G, 64, 0, stream>>>(gsum, gcnt, h1_w, h1_b, h1_g, h1_be, h2_w, h2_b, out, G);
}

// Round 17
// 1161.441 us; speedup vs baseline: 2.0432x; 1.0294x over previous
//
#include <hip/hip_runtime.h>
#include <math.h>

// ---------- helpers ----------
__device__ __forceinline__ float silu_f(float x) { return x / (1.0f + __expf(-x)); }

// f32 -> bf16 with round-to-nearest-even (finite values only)
__device__ __forceinline__ unsigned short f2bf(float f) {
  unsigned int u = __float_as_uint(f);
  unsigned int r = (u + 0x7fffu + ((u >> 16) & 1u)) >> 16;
  return (unsigned short)r;
}

// LayerNorm across a 64-lane wave; two reduce chains explicitly interleaved
__device__ __forceinline__ float ln64(float v, float g, float b) {
  float s = v, s2 = v * v;
#pragma unroll
  for (int m = 32; m > 0; m >>= 1) {
    s  += __shfl_xor(s,  m, 64);
    s2 += __shfl_xor(s2, m, 64);
  }
  float mean = s * 0.015625f;
  float var  = fmaxf(s2 * 0.015625f - mean * mean, 0.0f);
  return (v - mean) * rsqrtf(var + 1e-5f) * g + b;
}

// ---------- FUSED: node embed -> h, hw1/hw2(layer0), agg=0 ----------
__global__ __launch_bounds__(256) void k_embed_msgw(
    const float* __restrict__ x, const float* __restrict__ neW,
    const float* __restrict__ neB, const float* __restrict__ neG,
    const float* __restrict__ neBe, const float* __restrict__ W,   // msg_w[0], rows 0..127
    float* __restrict__ h, float* __restrict__ hw1, float* __restrict__ hw2,
    float* __restrict__ agg, int n) {
  __shared__ float sRow[4][64];
  const int row = (blockIdx.x * 256 + threadIdx.x) >> 6;
  const int wv = threadIdx.x >> 6;
  const int j  = threadIdx.x & 63;
  if (row >= n) return;

  const float* xr = x + (size_t)row * 16;
  float acc = neB[j];
#pragma unroll
  for (int k = 0; k < 16; k += 4) {
    float4 xv = *(const float4*)&xr[k];
    acc += xv.x * neW[(k + 0) * 64 + j] + xv.y * neW[(k + 1) * 64 + j] +
           xv.z * neW[(k + 2) * 64 + j] + xv.w * neW[(k + 3) * 64 + j];
  }
  float hv = silu_f(ln64(acc, neG[j], neBe[j]));
  h[(size_t)row * 64 + j] = hv;
  agg[(size_t)row * 64 + j] = 0.0f;
  sRow[wv][j] = hv;                    // same-wave write->read: ordered

  float a1 = 0.0f, a2 = 0.0f;
#pragma unroll
  for (int k = 0; k < 64; k += 4) {
    float4 r = *(const float4*)&sRow[wv][k];
    a1 += r.x * W[(k + 0) * 64 + j] + r.y * W[(k + 1) * 64 + j] +
          r.z * W[(k + 2) * 64 + j] + r.w * W[(k + 3) * 64 + j];
    a2 += r.x * W[(64 + k + 0) * 64 + j] + r.y * W[(64 + k + 1) * 64 + j] +
          r.z * W[(64 + k + 2) * 64 + j] + r.w * W[(64 + k + 3) * 64 + j];
  }
  hw1[(size_t)row * 64 + j] = a1;
  hw2[(size_t)row * 64 + j] = a2;
}

// ---------- edge embedding (ONCE): ebuf16 = bf16(silu(LN(ea@eeW))) ----------
__global__ __launch_bounds__(256) void k_edge_embed(
    const float* __restrict__ ea, const float* __restrict__ eeW,
    const float* __restrict__ eeB, const float* __restrict__ eeG,
    const float* __restrict__ eeBe, unsigned short* __restrict__ ebuf16,
    int nedges) {
  __shared__ float sEA[4][32];         // per-wave 4 edges x 8 attrs

  const int wv = threadIdx.x >> 6;
  const int j  = threadIdx.x & 63;
  const int ebase = (blockIdx.x * 4 + wv) * 4;
  if (ebase >= nedges) return;

  if (j < 32) {
    long long gi = (long long)ebase * 8 + j;
    long long gmax = (long long)nedges * 8 - 1;
    if (gi > gmax) gi = gmax;
    sEA[wv][j] = ea[gi];               // same-wave write->read: ordered
  }

  float ewc[8];
#pragma unroll
  for (int k = 0; k < 8; ++k) ewc[k] = eeW[k * 64 + j];
  const float eb = eeB[j], eg = eeG[j], ebe = eeBe[j];

#pragma unroll
  for (int e = 0; e < 4; ++e) {
    const float* ar = &sEA[wv][e * 8];
    float ev = eb;
#pragma unroll
    for (int k = 0; k < 8; ++k) ev += ar[k] * ewc[k];
    ev = silu_f(ln64(ev, eg, ebe));
    if (ebase + e < nedges) ebuf16[(size_t)(ebase + e) * 64 + j] = f2bf(ev);
  }
}

// ---------- edge message (r12 proven body, bf16 ebuf, 128-thread blocks) ----------
// m = LN(silu(hw1[dst] + hw2[src] + e@W3 + msg_b)); agg[dst] += m
#define EPW 4
__global__ __launch_bounds__(128) void k_edge_msg_pre2(
    const unsigned short* __restrict__ ebuf16, const float* __restrict__ W3,
    const float* __restrict__ msgB, const float* __restrict__ msgG,
    const float* __restrict__ msgBe,
    const float* __restrict__ hw1, const float* __restrict__ hw2,
    const int* __restrict__ srcI, const int* __restrict__ dstI,
    float* __restrict__ agg, int nedges) {
  __shared__ float sE[2][EPW][64];     // 2 KB

  const int wv = threadIdx.x >> 6;     // 0..1
  const int j  = threadIdx.x & 63;
  const int ebase = (blockIdx.x * 2 + wv) * EPW;
  if (ebase >= nedges) return;

  // coalesced bf16 e-row staging: lane j -> 4 elems (8B), unpack, LDS f32
  {
    long long gi = (long long)ebase * 64 + j * 4;    // element index
    long long gmax = (long long)nedges * 64 - 4;
    if (gi > gmax) gi = gmax;
    uint2 v = *(const uint2*)&ebuf16[gi];            // 8B aligned (gi % 4 == 0)
    float4 f;
    f.x = __uint_as_float(v.x << 16);
    f.y = __uint_as_float(v.x & 0xffff0000u);
    f.z = __uint_as_float(v.y << 16);
    f.w = __uint_as_float(v.y & 0xffff0000u);
    *(float4*)&sE[wv][j >> 4][(j & 15) * 4] = f;     // same-wave: ordered
  }

  // gathers issued up-front; results not needed until epilogue
  int dIdx[EPW];
  float g1[EPW], g2[EPW];
#pragma unroll
  for (int e = 0; e < EPW; ++e) {
    int ce = min(ebase + e, nedges - 1);
    int s = srcI[ce];
    dIdx[e] = dstI[ce];
    g1[e] = hw1[(size_t)dIdx[e] * 64 + j];
    g2[e] = hw2[(size_t)s * 64 + j];
  }

  // MAC from LDS + L1-resident W3
  float macc[EPW] = {0.f, 0.f, 0.f, 0.f};
#pragma unroll
  for (int k = 0; k < 64; k += 4) {
    float w0 = W3[(k + 0) * 64 + j];
    float w1 = W3[(k + 1) * 64 + j];
    float w2 = W3[(k + 2) * 64 + j];
    float w3 = W3[(k + 3) * 64 + j];
#pragma unroll
    for (int e = 0; e < EPW; ++e) {
      float4 ev4 = *(const float4*)&sE[wv][e][k];
      macc[e] += ev4.x * w0 + ev4.y * w1 + ev4.z * w2 + ev4.w * w3;
    }
  }

  // epilogue: fold gathers + bias, silu, LN, scatter-add
  const float bj = msgB[j], mg = msgG[j], mbe = msgBe[j];
#pragma unroll
  for (int e = 0; e < EPW; ++e) {
    float m = ln64(silu_f(macc[e] + g1[e] + g2[e] + bj), mg, mbe);
    if (ebase + e < nedges) unsafeAtomicAdd(&agg[(size_t)dIdx[e] * 64 + j], m);
  }
}

// ---------- edge message FALLBACK (ws too small): r9 proven kernel ----------
__global__ __launch_bounds__(256) void k_edge_msg_fb(
    const float* __restrict__ ea, const float* __restrict__ eeW,
    const float* __restrict__ eeB, const float* __restrict__ eeG,
    const float* __restrict__ eeBe,
    const float* __restrict__ W3, const float* __restrict__ msgB,
    const float* __restrict__ msgG, const float* __restrict__ msgBe,
    const float* __restrict__ hw1, const float* __restrict__ hw2,
    const int* __restrict__ srcI, const int* __restrict__ dstI,
    float* __restrict__ agg, int nedges) {
  __shared__ float sE[4][EPW][64];
  __shared__ float sEA[4][EPW * 8];

  const int wv = threadIdx.x >> 6;
  const int j  = threadIdx.x & 63;
  const int ebase = (blockIdx.x * 4 + wv) * EPW;
  if (ebase >= nedges) return;

  if (j < 32) {
    long long gi = (long long)ebase * 8 + j;
    long long gmax = (long long)nedges * 8 - 1;
    if (gi > gmax) gi = gmax;
    sEA[wv][j] = ea[gi];
  }

  const float bj = msgB[j];
  int dIdx[EPW];
  float acc[EPW];
#pragma unroll
  for (int e = 0; e < EPW; ++e) {
    int ce = min(ebase + e, nedges - 1);
    int s = srcI[ce];
    dIdx[e] = dstI[ce];
    acc[e] = hw1[(size_t)dIdx[e] * 64 + j] + hw2[(size_t)s * 64 + j] + bj;
  }
  {
    float ewc[8];
#pragma unroll
    for (int k = 0; k < 8; ++k) ewc[k] = eeW[k * 64 + j];
    const float eb = eeB[j], eg = eeG[j], ebe = eeBe[j];
#pragma unroll
    for (int e = 0; e < EPW; ++e) {
      const float* ar = &sEA[wv][e * 8];
      float ev = eb;
#pragma unroll
      for (int k = 0; k < 8; ++k) ev += ar[k] * ewc[k];
      ev = silu_f(ln64(ev, eg, ebe));
      sE[wv][e][j] = ev;
    }
  }
#pragma unroll
  for (int k = 0; k < 64; k += 4) {
    float w0 = W3[(k + 0) * 64 + j];
    float w1 = W3[(k + 1) * 64 + j];
    float w2 = W3[(k + 2) * 64 + j];
    float w3 = W3[(k + 3) * 64 + j];
#pragma unroll
    for (int e = 0; e < EPW; ++e) {
      float4 ev4 = *(const float4*)&sE[wv][e][k];
      acc[e] += ev4.x * w0 + ev4.y * w1 + ev4.z * w2 + ev4.w * w3;
    }
  }
  const float mg = msgG[j], mbe = msgBe[j];
#pragma unroll
  for (int e = 0; e < EPW; ++e) {
    float m = ln64(silu_f(acc[e]), mg, mbe);
    if (ebase + e < nedges) unsafeAtomicAdd(&agg[(size_t)dIdx[e] * 64 + j], m);
  }
}

// ---------- FUSED: update(in-place) -> hw1/hw2(next layer), agg=0 ----------
__global__ __launch_bounds__(256) void k_update_msgw(
    float* h, float* agg,                       // agg read then zeroed
    const float* __restrict__ W, const float* __restrict__ b,
    const float* __restrict__ ug, const float* __restrict__ ube,
    const float* __restrict__ ng, const float* __restrict__ nbe,
    const float* __restrict__ Wn,               // next layer msg_w rows 0..127
    float* __restrict__ hw1, float* __restrict__ hw2, int n) {
  __shared__ float sRow[4][64];
  const int row = (blockIdx.x * 256 + threadIdx.x) >> 6;
  const int wv = threadIdx.x >> 6;
  const int j  = threadIdx.x & 63;
  if (row >= n) return;

  float* hr = h + (size_t)row * 64;
  float* ar = agg + (size_t)row * 64;
  float acc = b[j];
  float hj = hr[j];
#pragma unroll
  for (int k = 0; k < 64; k += 4) {
    float4 hv = *(const float4*)&hr[k];
    float4 av = *(const float4*)&ar[k];
    acc += (hv.x + av.x) * W[(k + 0) * 64 + j] + (hv.y + av.y) * W[(k + 1) * 64 + j] +
           (hv.z + av.z) * W[(k + 2) * 64 + j] + (hv.w + av.w) * W[(k + 3) * 64 + j];
  }
  float u = ln64(silu_f(acc), ug[j], ube[j]);
  float hn = ln64(u + hj, ng[j], nbe[j]);
  hr[j] = hn;
  ar[j] = 0.0f;                        // zero agg for next layer
  sRow[wv][j] = hn;                    // same-wave ordered

  float a1 = 0.0f, a2 = 0.0f;
#pragma unroll
  for (int k = 0; k < 64; k += 4) {
    float4 r = *(const float4*)&sRow[wv][k];
    a1 += r.x * Wn[(k + 0) * 64 + j] + r.y * Wn[(k + 1) * 64 + j] +
          r.z * Wn[(k + 2) * 64 + j] + r.w * Wn[(k + 3) * 64 + j];
    a2 += r.x * Wn[(64 + k + 0) * 64 + j] + r.y * Wn[(64 + k + 1) * 64 + j] +
          r.z * Wn[(64 + k + 2) * 64 + j] + r.w * Wn[(64 + k + 3) * 64 + j];
  }
  hw1[(size_t)row * 64 + j] = a1;
  hw2[(size_t)row * 64 + j] = a2;
}

// ---------- FUSED: final update(in-place) -> pool atomics ----------
__global__ __launch_bounds__(256) void k_update_pool(
    float* h, const float* __restrict__ agg,
    const float* __restrict__ W, const float* __restrict__ b,
    const float* __restrict__ ug, const float* __restrict__ ube,
    const float* __restrict__ ng, const float* __restrict__ nbe,
    const int* __restrict__ batch, float* __restrict__ gsum,
    float* __restrict__ gcnt, int n) {
  const int row = (blockIdx.x * 256 + threadIdx.x) >> 6;
  const int j  = threadIdx.x & 63;
  if (row >= n) return;

  float* hr = h + (size_t)row * 64;
  const float* ar = agg + (size_t)row * 64;
  float acc = b[j];
  float hj = hr[j];
#pragma unroll
  for (int k = 0; k < 64; k += 4) {
    float4 hv = *(const float4*)&hr[k];
    float4 av = *(const float4*)&ar[k];
    acc += (hv.x + av.x) * W[(k + 0) * 64 + j] + (hv.y + av.y) * W[(k + 1) * 64 + j] +
           (hv.z + av.z) * W[(k + 2) * 64 + j] + (hv.w + av.w) * W[(k + 3) * 64 + j];
  }
  float u = ln64(silu_f(acc), ug[j], ube[j]);
  float hn = ln64(u + hj, ng[j], nbe[j]);

  int bb = batch[row];
  unsafeAtomicAdd(&gsum[(size_t)bb * 64 + j], hn);
  if (j == 0) unsafeAtomicAdd(&gcnt[bb], 1.0f);
}

// ---------- head: out = silu(LN(g@h1_w+b)) @ h2_w + h2_b ----------
__global__ __launch_bounds__(64) void k_head(
    const float* __restrict__ gsum, const float* __restrict__ gcnt,
    const float* __restrict__ w1, const float* __restrict__ b1,
    const float* __restrict__ g1, const float* __restrict__ be1,
    const float* __restrict__ w2, const float* __restrict__ b2,
    float* __restrict__ out, int ngraphs) {
  int gidx = blockIdx.x;
  int j = threadIdx.x;
  if (gidx >= ngraphs) return;
  __shared__ float sg[64];
  float cnt = fmaxf(gcnt[gidx], 1.0f);
  sg[j] = gsum[(size_t)gidx * 64 + j] / cnt;
  float acc = 0.0f;
  if (j < 32) {
    acc = b1[j];
#pragma unroll 8
    for (int k = 0; k < 64; ++k) acc += sg[k] * w1[k * 32 + j];
  }
  float s = acc, s2 = acc * acc;
#pragma unroll
  for (int m = 16; m > 0; m >>= 1) {
    s  += __shfl_xor(s,  m, 64);
    s2 += __shfl_xor(s2, m, 64);
  }
  float mean = s * 0.03125f;
  float var  = fmaxf(s2 * 0.03125f - mean * mean, 0.0f);
  float z = 0.0f;
  if (j < 32) {
    float nv = (acc - mean) * rsqrtf(var + 1e-5f) * g1[j] + be1[j];
    z = silu_f(nv) * w2[j];
  }
#pragma unroll
  for (int m = 32; m > 0; m >>= 1) z += __shfl_xor(z, m, 64);
  if (j == 0) out[gidx] = z + b2[0];
}

// ---------- launch ----------
extern "C" void kernel_launch(void* const* d_in, const int* in_sizes, int n_in,
                              void* d_out, int out_size, void* d_ws, size_t ws_size,
                              hipStream_t stream) {
  const float* x      = (const float*)d_in[0];
  const float* ea     = (const float*)d_in[1];
  const float* ne_w   = (const float*)d_in[2];
  const float* ne_b   = (const float*)d_in[3];
  const float* ne_g   = (const float*)d_in[4];
  const float* ne_be  = (const float*)d_in[5];
  const float* ee_w   = (const float*)d_in[6];
  const float* ee_b   = (const float*)d_in[7];
  const float* ee_g   = (const float*)d_in[8];
  const float* ee_be  = (const float*)d_in[9];
  const float* msg_w  = (const float*)d_in[10];
  const float* msg_b  = (const float*)d_in[11];
  const float* msg_g  = (const float*)d_in[12];
  const float* msg_be = (const float*)d_in[13];
  const float* upd_w  = (const float*)d_in[14];
  const float* upd_b  = (const float*)d_in[15];
  const float* upd_g  = (const float*)d_in[16];
  const float* upd_be = (const float*)d_in[17];
  const float* nrm_g  = (const float*)d_in[18];
  const float* nrm_be = (const float*)d_in[19];
  const float* h1_w   = (const float*)d_in[20];
  const float* h1_b   = (const float*)d_in[21];
  const float* h1_g   = (const float*)d_in[22];
  const float* h1_be  = (const float*)d_in[23];
  const float* h2_w   = (const float*)d_in[24];
  const float* h2_b   = (const float*)d_in[25];
  const int*   ei     = (const int*)d_in[26];
  const int*   batch  = (const int*)d_in[27];
  float* out = (float*)d_out;

  const int N = in_sizes[0] / 16;
  const int E = in_sizes[1] / 8;
  const int G = out_size;
  const int* srcI = ei;       // edge_index[0] = src (x_j)
  const int* dstI = ei + E;   // edge_index[1] = dst (x_i)

  float* ws  = (float*)d_ws;
  float* h    = ws;
  float* hw1  = h   + (size_t)N * 64;
  float* hw2  = hw1 + (size_t)N * 64;
  float* agg  = hw2 + (size_t)N * 64;
  float* gsum = agg + (size_t)N * 64;
  float* gcnt = gsum + (size_t)G * 64;
  unsigned short* ebuf16 = (unsigned short*)(gcnt + G);  // [E,64] bf16

  const size_t fixed_floats = (size_t)N * 64 * 4 + (size_t)G * 64 + G;
  const bool pre = (ws_size / 4 >= fixed_floats + (size_t)E * 32);

  const int nblk  = (N + 3) / 4;                     // 4 node rows per block
  const int eblkE = (E + 15) / 16;                   // edge-embed blocks
  const int eblkP = (E + 2 * EPW - 1) / (2 * EPW);   // 8 edges / 128-thr block
  const int eblkF = (E + 15) / 16;                   // fallback blocks

  // embed + msgw(layer0) + agg=0
  k_embed_msgw<<<nblk, 256, 0, stream>>>(
      x, ne_w, ne_b, ne_g, ne_be, msg_w, h, hw1, hw2, agg, N);
  if (pre)
    k_edge_embed<<<eblkE, 256, 0, stream>>>(ea, ee_w, ee_b, ee_g, ee_be, ebuf16, E);

  // ---- layer 0 ----
  if (pre) {
    k_edge_msg_pre2<<<eblkP, 128, 0, stream>>>(
        ebuf16, msg_w + 128 * 64, msg_b, msg_g, msg_be,
        hw1, hw2, srcI, dstI, agg, E);
  } else {
    k_edge_msg_fb<<<eblkF, 256, 0, stream>>>(
        ea, ee_w, ee_b, ee_g, ee_be,
        msg_w + 128 * 64, msg_b, msg_g, msg_be,
        hw1, hw2, srcI, dstI, agg, E);
  }
  // update(l=0) + msgw(layer1) + agg=0
  k_update_msgw<<<nblk, 256, 0, stream>>>(
      h, agg, upd_w, upd_b, upd_g, upd_be, nrm_g, nrm_be,
      msg_w + (size_t)192 * 64, hw1, hw2, N);

  // ---- layer 1 ----
  if (pre) {
    k_edge_msg_pre2<<<eblkP, 128, 0, stream>>>(
        ebuf16, msg_w + (size_t)192 * 64 + 128 * 64, msg_b + 64, msg_g + 64,
        msg_be + 64, hw1, hw2, srcI, dstI, agg, E);
  } else {
    k_edge_msg_fb<<<eblkF, 256, 0, stream>>>(
        ea, ee_w, ee_b, ee_g, ee_be,
        msg_w + (size_t)192 * 64 + 128 * 64, msg_b + 64, msg_g + 64,
        msg_be + 64, hw1, hw2, srcI, dstI, agg, E);
  }
  hipMemsetAsync(gsum, 0, ((size_t)G * 64 + G) * sizeof(float), stream);
  // update(l=1) + pool
  k_update_pool<<<nblk, 256, 0, stream>>>(
      h, agg, upd_w + (size_t)64 * 64, upd_b + 64, upd_g + 64, upd_be + 64,
      nrm_g + 64, nrm_be + 64, batch, gsum, gcnt, N);

  k_head<<<G, 64, 0, stream>>>(gsum, gcnt, h1_w, h1_b, h1_g, h1_be, h2_w, h2_b, out, G);
}

// Round 18
// 780.003 us; speedup vs baseline: 3.0424x; 1.4890x over previous
//
#include <hip/hip_runtime.h>
#include <math.h>

typedef __attribute__((ext_vector_type(8))) short short8;
typedef __attribute__((ext_vector_type(4))) float f32x4;

// ---------- helpers ----------
__device__ __forceinline__ float silu_f(float x) { return x / (1.0f + __expf(-x)); }

// f32 -> bf16 round-to-nearest-even (finite values only)
__device__ __forceinline__ unsigned short f2bf(float f) {
  unsigned int u = __float_as_uint(f);
  unsigned int r = (u + 0x7fffu + ((u >> 16) & 1u)) >> 16;
  return (unsigned short)r;
}

// LayerNorm across a 64-lane wave; two reduce chains explicitly interleaved
__device__ __forceinline__ float ln64(float v, float g, float b) {
  float s = v, s2 = v * v;
#pragma unroll
  for (int m = 32; m > 0; m >>= 1) {
    s  += __shfl_xor(s,  m, 64);
    s2 += __shfl_xor(s2, m, 64);
  }
  float mean = s * 0.015625f;
  float var  = fmaxf(s2 * 0.015625f - mean * mean, 0.0f);
  return (v - mean) * rsqrtf(var + 1e-5f) * g + b;
}

// ---------- FUSED: node embed -> h, hw1/hw2(layer0), agg=0 ----------
__global__ __launch_bounds__(256) void k_embed_msgw(
    const float* __restrict__ x, const float* __restrict__ neW,
    const float* __restrict__ neB, const float* __restrict__ neG,
    const float* __restrict__ neBe, const float* __restrict__ W,   // msg_w[0], rows 0..127
    float* __restrict__ h, float* __restrict__ hw1, float* __restrict__ hw2,
    float* __restrict__ agg, int n) {
  __shared__ float sRow[4][64];
  const int row = (blockIdx.x * 256 + threadIdx.x) >> 6;
  const int wv = threadIdx.x >> 6;
  const int j  = threadIdx.x & 63;
  if (row >= n) return;

  const float* xr = x + (size_t)row * 16;
  float acc = neB[j];
#pragma unroll
  for (int k = 0; k < 16; k += 4) {
    float4 xv = *(const float4*)&xr[k];
    acc += xv.x * neW[(k + 0) * 64 + j] + xv.y * neW[(k + 1) * 64 + j] +
           xv.z * neW[(k + 2) * 64 + j] + xv.w * neW[(k + 3) * 64 + j];
  }
  float hv = silu_f(ln64(acc, neG[j], neBe[j]));
  h[(size_t)row * 64 + j] = hv;
  agg[(size_t)row * 64 + j] = 0.0f;
  sRow[wv][j] = hv;                    // same-wave write->read: ordered

  float a1 = 0.0f, a2 = 0.0f;
#pragma unroll
  for (int k = 0; k < 64; k += 4) {
    float4 r = *(const float4*)&sRow[wv][k];
    a1 += r.x * W[(k + 0) * 64 + j] + r.y * W[(k + 1) * 64 + j] +
          r.z * W[(k + 2) * 64 + j] + r.w * W[(k + 3) * 64 + j];
    a2 += r.x * W[(64 + k + 0) * 64 + j] + r.y * W[(64 + k + 1) * 64 + j] +
          r.z * W[(64 + k + 2) * 64 + j] + r.w * W[(64 + k + 3) * 64 + j];
  }
  hw1[(size_t)row * 64 + j] = a1;
  hw2[(size_t)row * 64 + j] = a2;
}

// ---------- edge embedding (ONCE): ebuf16 = bf16(silu(LN(ea@eeW))) ----------
__global__ __launch_bounds__(256) void k_edge_embed(
    const float* __restrict__ ea, const float* __restrict__ eeW,
    const float* __restrict__ eeB, const float* __restrict__ eeG,
    const float* __restrict__ eeBe, unsigned short* __restrict__ ebuf16,
    int nedges) {
  __shared__ float sEA[4][32];         // per-wave 4 edges x 8 attrs

  const int wv = threadIdx.x >> 6;
  const int j  = threadIdx.x & 63;
  const int ebase = (blockIdx.x * 4 + wv) * 4;
  if (ebase >= nedges) return;

  if (j < 32) {
    long long gi = (long long)ebase * 8 + j;
    long long gmax = (long long)nedges * 8 - 1;
    if (gi > gmax) gi = gmax;
    sEA[wv][j] = ea[gi];               // same-wave write->read: ordered
  }

  float ewc[8];
#pragma unroll
  for (int k = 0; k < 8; ++k) ewc[k] = eeW[k * 64 + j];
  const float eb = eeB[j], eg = eeG[j], ebe = eeBe[j];

#pragma unroll
  for (int e = 0; e < 4; ++e) {
    const float* ar = &sEA[wv][e * 8];
    float ev = eb;
#pragma unroll
    for (int k = 0; k < 8; ++k) ev += ar[k] * ewc[k];
    ev = silu_f(ln64(ev, eg, ebe));
    if (ebase + e < nedges) ebuf16[(size_t)(ebase + e) * 64 + j] = f2bf(ev);
  }
}

// ---------- W3 pack (ONCE): bf16 MFMA B-fragments for both layers ----------
// w3f[((L*2+kh)*4+jt)*64 + l][i] = bf16(W3_L[(kh*32+(l>>4)*8+i)*64 + jt*16+(l&15)])
__global__ __launch_bounds__(256) void k_w3_pack(
    const float* __restrict__ W3a, const float* __restrict__ W3b,
    unsigned short* __restrict__ w3f) {
  int t = blockIdx.x * 256 + threadIdx.x;     // 1024 lane-chunks
  if (t >= 1024) return;
  int L  = t >> 9;
  int kh = (t >> 8) & 1;
  int jt = (t >> 6) & 3;
  int l  = t & 63;
  const float* W3 = L ? W3b : W3a;
  unsigned short* dst = w3f + (size_t)t * 8;
#pragma unroll
  for (int i = 0; i < 8; ++i)
    dst[i] = f2bf(W3[(kh * 32 + (l >> 4) * 8 + i) * 64 + jt * 16 + (l & 15)]);
}

// ---------- edge message via MFMA: 16 edges/wave ----------
// msg = LN(silu(e@W3 + hw1[dst] + hw2[src] + msg_b)); agg[dst] += msg
// A: lane l holds e[ebase+(l&15)][k=(l>>4)*8+i]; B pre-swizzled (k_w3_pack);
// D: lane l holds edge (l>>4)*4+r (reg r), feature jt*16+(l&15).
__global__ __launch_bounds__(256) void k_edge_msg_mfma(
    const unsigned short* __restrict__ ebuf16,
    const unsigned short* __restrict__ w3f,   // this layer's 4096 shorts
    const float* __restrict__ msgB, const float* __restrict__ msgG,
    const float* __restrict__ msgBe,
    const float* __restrict__ hw1, const float* __restrict__ hw2,
    const int* __restrict__ srcI, const int* __restrict__ dstI,
    float* __restrict__ agg, int nedges) {
  const int wv = threadIdx.x >> 6;
  const int l  = threadIdx.x & 63;
  const int ebase = (blockIdx.x * 4 + wv) * 16;
  if (ebase >= nedges) return;

  const int lo = l & 15, hi = l >> 4;

  // A fragments (two K-halves), rows = edges ebase+lo
  const int arow = min(ebase + lo, nedges - 1);
  const unsigned short* ar = ebuf16 + (size_t)arow * 64;
  short8 a0 = *(const short8*)(ar + hi * 8);
  short8 a1 = *(const short8*)(ar + 32 + hi * 8);

  // indices + gathers for my 4 edges (edge = ebase + hi*4 + r)
  int dIdx[4];
  float g1[4][4], g2[4][4];
#pragma unroll
  for (int r = 0; r < 4; ++r) {
    int ce = min(ebase + hi * 4 + r, nedges - 1);
    int s = srcI[ce];
    dIdx[r] = dstI[ce];
#pragma unroll
    for (int jt = 0; jt < 4; ++jt) {
      g1[r][jt] = hw1[(size_t)dIdx[r] * 64 + jt * 16 + lo];
      g2[r][jt] = hw2[(size_t)s * 64 + jt * 16 + lo];
    }
  }

  // MFMA: 4 j-tiles x 2 K-halves (B frags L1-resident, shared by all waves)
  f32x4 acc[4];
#pragma unroll
  for (int jt = 0; jt < 4; ++jt) {
    short8 b0 = *(const short8*)(w3f + ((size_t)(0 * 4 + jt) * 64 + l) * 8);
    short8 b1 = *(const short8*)(w3f + ((size_t)(1 * 4 + jt) * 64 + l) * 8);
    f32x4 c = {0.f, 0.f, 0.f, 0.f};
    c = __builtin_amdgcn_mfma_f32_16x16x32_bf16(a0, b0, c, 0, 0, 0);
    c = __builtin_amdgcn_mfma_f32_16x16x32_bf16(a1, b1, c, 0, 0, 0);
    acc[jt] = c;
  }

  // per-lane params for features jt*16+lo
  float mB[4], mG[4], mBe[4];
#pragma unroll
  for (int jt = 0; jt < 4; ++jt) {
    mB[jt]  = msgB[jt * 16 + lo];
    mG[jt]  = msgG[jt * 16 + lo];
    mBe[jt] = msgBe[jt * 16 + lo];
  }

  // epilogue per edge-reg r: bias+gathers, silu, LN over 16-lane group, scatter
#pragma unroll
  for (int r = 0; r < 4; ++r) {
    float mp[4];
    float s = 0.0f, s2 = 0.0f;
#pragma unroll
    for (int jt = 0; jt < 4; ++jt) {
      float v = acc[jt][r] + g1[r][jt] + g2[r][jt] + mB[jt];
      v = silu_f(v);
      mp[jt] = v;
      s += v;
      s2 += v * v;
    }
#pragma unroll
    for (int m = 8; m > 0; m >>= 1) {          // 16-lane group reduce
      s  += __shfl_xor(s,  m, 64);
      s2 += __shfl_xor(s2, m, 64);
    }
    float mean = s * 0.015625f;
    float var  = fmaxf(s2 * 0.015625f - mean * mean, 0.0f);
    float rsq  = rsqrtf(var + 1e-5f);
    if (ebase + hi * 4 + r < nedges) {
#pragma unroll
      for (int jt = 0; jt < 4; ++jt) {
        float m2 = (mp[jt] - mean) * rsq * mG[jt] + mBe[jt];
        unsafeAtomicAdd(&agg[(size_t)dIdx[r] * 64 + jt * 16 + lo], m2);
      }
    }
  }
}

// ---------- edge message FALLBACK (ws too small): r9 proven kernel ----------
#define EPW 4
__global__ __launch_bounds__(256) void k_edge_msg_fb(
    const float* __restrict__ ea, const float* __restrict__ eeW,
    const float* __restrict__ eeB, const float* __restrict__ eeG,
    const float* __restrict__ eeBe,
    const float* __restrict__ W3, const float* __restrict__ msgB,
    const float* __restrict__ msgG, const float* __restrict__ msgBe,
    const float* __restrict__ hw1, const float* __restrict__ hw2,
    const int* __restrict__ srcI, const int* __restrict__ dstI,
    float* __restrict__ agg, int nedges) {
  __shared__ float sE[4][EPW][64];
  __shared__ float sEA[4][EPW * 8];

  const int wv = threadIdx.x >> 6;
  const int j  = threadIdx.x & 63;
  const int ebase = (blockIdx.x * 4 + wv) * EPW;
  if (ebase >= nedges) return;

  if (j < 32) {
    long long gi = (long long)ebase * 8 + j;
    long long gmax = (long long)nedges * 8 - 1;
    if (gi > gmax) gi = gmax;
    sEA[wv][j] = ea[gi];
  }

  const float bj = msgB[j];
  int dIdx[EPW];
  float acc[EPW];
#pragma unroll
  for (int e = 0; e < EPW; ++e) {
    int ce = min(ebase + e, nedges - 1);
    int s = srcI[ce];
    dIdx[e] = dstI[ce];
    acc[e] = hw1[(size_t)dIdx[e] * 64 + j] + hw2[(size_t)s * 64 + j] + bj;
  }
  {
    float ewc[8];
#pragma unroll
    for (int k = 0; k < 8; ++k) ewc[k] = eeW[k * 64 + j];
    const float eb = eeB[j], eg = eeG[j], ebe = eeBe[j];
#pragma unroll
    for (int e = 0; e < EPW; ++e) {
      const float* ar = &sEA[wv][e * 8];
      float ev = eb;
#pragma unroll
      for (int k = 0; k < 8; ++k) ev += ar[k] * ewc[k];
      ev = silu_f(ln64(ev, eg, ebe));
      sE[wv][e][j] = ev;
    }
  }
#pragma unroll
  for (int k = 0; k < 64; k += 4) {
    float w0 = W3[(k + 0) * 64 + j];
    float w1 = W3[(k + 1) * 64 + j];
    float w2 = W3[(k + 2) * 64 + j];
    float w3 = W3[(k + 3) * 64 + j];
#pragma unroll
    for (int e = 0; e < EPW; ++e) {
      float4 ev4 = *(const float4*)&sE[wv][e][k];
      acc[e] += ev4.x * w0 + ev4.y * w1 + ev4.z * w2 + ev4.w * w3;
    }
  }
  const float mg = msgG[j], mbe = msgBe[j];
#pragma unroll
  for (int e = 0; e < EPW; ++e) {
    float m = ln64(silu_f(acc[e]), mg, mbe);
    if (ebase + e < nedges) unsafeAtomicAdd(&agg[(size_t)dIdx[e] * 64 + j], m);
  }
}

// ---------- FUSED: update(in-place) -> hw1/hw2(next layer), agg=0 ----------
__global__ __launch_bounds__(256) void k_update_msgw(
    float* h, float* agg,                       // agg read then zeroed
    const float* __restrict__ W, const float* __restrict__ b,
    const float* __restrict__ ug, const float* __restrict__ ube,
    const float* __restrict__ ng, const float* __restrict__ nbe,
    const float* __restrict__ Wn,               // next layer msg_w rows 0..127
    float* __restrict__ hw1, float* __restrict__ hw2, int n) {
  __shared__ float sRow[4][64];
  const int row = (blockIdx.x * 256 + threadIdx.x) >> 6;
  const int wv = threadIdx.x >> 6;
  const int j  = threadIdx.x & 63;
  if (row >= n) return;

  float* hr = h + (size_t)row * 64;
  float* ar = agg + (size_t)row * 64;
  float acc = b[j];
  float hj = hr[j];
#pragma unroll
  for (int k = 0; k < 64; k += 4) {
    float4 hv = *(const float4*)&hr[k];
    float4 av = *(const float4*)&ar[k];
    acc += (hv.x + av.x) * W[(k + 0) * 64 + j] + (hv.y + av.y) * W[(k + 1) * 64 + j] +
           (hv.z + av.z) * W[(k + 2) * 64 + j] + (hv.w + av.w) * W[(k + 3) * 64 + j];
  }
  float u = ln64(silu_f(acc), ug[j], ube[j]);
  float hn = ln64(u + hj, ng[j], nbe[j]);
  hr[j] = hn;
  ar[j] = 0.0f;                        // zero agg for next layer
  sRow[wv][j] = hn;                    // same-wave ordered

  float a1 = 0.0f, a2 = 0.0f;
#pragma unroll
  for (int k = 0; k < 64; k += 4) {
    float4 r = *(const float4*)&sRow[wv][k];
    a1 += r.x * Wn[(k + 0) * 64 + j] + r.y * Wn[(k + 1) * 64 + j] +
          r.z * Wn[(k + 2) * 64 + j] + r.w * Wn[(k + 3) * 64 + j];
    a2 += r.x * Wn[(64 + k + 0) * 64 + j] + r.y * Wn[(64 + k + 1) * 64 + j] +
          r.z * Wn[(64 + k + 2) * 64 + j] + r.w * Wn[(64 + k + 3) * 64 + j];
  }
  hw1[(size_t)row * 64 + j] = a1;
  hw2[(size_t)row * 64 + j] = a2;
}

// ---------- FUSED: final update(in-place) -> pool atomics ----------
__global__ __launch_bounds__(256) void k_update_pool(
    float* h, const float* __restrict__ agg,
    const float* __restrict__ W, const float* __restrict__ b,
    const float* __restrict__ ug, const float* __restrict__ ube,
    const float* __restrict__ ng, const float* __restrict__ nbe,
    const int* __restrict__ batch, float* __restrict__ gsum,
    float* __restrict__ gcnt, int n) {
  const int row = (blockIdx.x * 256 + threadIdx.x) >> 6;
  const int j  = threadIdx.x & 63;
  if (row >= n) return;

  float* hr = h + (size_t)row * 64;
  const float* ar = agg + (size_t)row * 64;
  float acc = b[j];
  float hj = hr[j];
#pragma unroll
  for (int k = 0; k < 64; k += 4) {
    float4 hv = *(const float4*)&hr[k];
    float4 av = *(const float4*)&ar[k];
    acc += (hv.x + av.x) * W[(k + 0) * 64 + j] + (hv.y + av.y) * W[(k + 1) * 64 + j] +
           (hv.z + av.z) * W[(k + 2) * 64 + j] + (hv.w + av.w) * W[(k + 3) * 64 + j];
  }
  float u = ln64(silu_f(acc), ug[j], ube[j]);
  float hn = ln64(u + hj, ng[j], nbe[j]);

  int bb = batch[row];
  unsafeAtomicAdd(&gsum[(size_t)bb * 64 + j], hn);
  if (j == 0) unsafeAtomicAdd(&gcnt[bb], 1.0f);
}

// ---------- head: out = silu(LN(g@h1_w+b)) @ h2_w + h2_b ----------
__global__ __launch_bounds__(64) void k_head(
    const float* __restrict__ gsum, const float* __restrict__ gcnt,
    const float* __restrict__ w1, const float* __restrict__ b1,
    const float* __restrict__ g1, const float* __restrict__ be1,
    const float* __restrict__ w2, const float* __restrict__ b2,
    float* __restrict__ out, int ngraphs) {
  int gidx = blockIdx.x;
  int j = threadIdx.x;
  if (gidx >= ngraphs) return;
  __shared__ float sg[64];
  float cnt = fmaxf(gcnt[gidx], 1.0f);
  sg[j] = gsum[(size_t)gidx * 64 + j] / cnt;
  float acc = 0.0f;
  if (j < 32) {
    acc = b1[j];
#pragma unroll 8
    for (int k = 0; k < 64; ++k) acc += sg[k] * w1[k * 32 + j];
  }
  float s = acc, s2 = acc * acc;
#pragma unroll
  for (int m = 16; m > 0; m >>= 1) {
    s  += __shfl_xor(s,  m, 64);
    s2 += __shfl_xor(s2, m, 64);
  }
  float mean = s * 0.03125f;
  float var  = fmaxf(s2 * 0.03125f - mean * mean, 0.0f);
  float z = 0.0f;
  if (j < 32) {
    float nv = (acc - mean) * rsqrtf(var + 1e-5f) * g1[j] + be1[j];
    z = silu_f(nv) * w2[j];
  }
#pragma unroll
  for (int m = 32; m > 0; m >>= 1) z += __shfl_xor(z, m, 64);
  if (j == 0) out[gidx] = z + b2[0];
}

// ---------- launch ----------
extern "C" void kernel_launch(void* const* d_in, const int* in_sizes, int n_in,
                              void* d_out, int out_size, void* d_ws, size_t ws_size,
                              hipStream_t stream) {
  const float* x      = (const float*)d_in[0];
  const float* ea     = (const float*)d_in[1];
  const float* ne_w   = (const float*)d_in[2];
  const float* ne_b   = (const float*)d_in[3];
  const float* ne_g   = (const float*)d_in[4];
  const float* ne_be  = (const float*)d_in[5];
  const float* ee_w   = (const float*)d_in[6];
  const float* ee_b   = (const float*)d_in[7];
  const float* ee_g   = (const float*)d_in[8];
  const float* ee_be  = (const float*)d_in[9];
  const float* msg_w  = (const float*)d_in[10];
  const float* msg_b  = (const float*)d_in[11];
  const float* msg_g  = (const float*)d_in[12];
  const float* msg_be = (const float*)d_in[13];
  const float* upd_w  = (const float*)d_in[14];
  const float* upd_b  = (const float*)d_in[15];
  const float* upd_g  = (const float*)d_in[16];
  const float* upd_be = (const float*)d_in[17];
  const float* nrm_g  = (const float*)d_in[18];
  const float* nrm_be = (const float*)d_in[19];
  const float* h1_w   = (const float*)d_in[20];
  const float* h1_b   = (const float*)d_in[21];
  const float* h1_g   = (const float*)d_in[22];
  const float* h1_be  = (const float*)d_in[23];
  const float* h2_w   = (const float*)d_in[24];
  const float* h2_b   = (const float*)d_in[25];
  const int*   ei     = (const int*)d_in[26];
  const int*   batch  = (const int*)d_in[27];
  float* out = (float*)d_out;

  const int N = in_sizes[0] / 16;
  const int E = in_sizes[1] / 8;
  const int G = out_size;
  const int* srcI = ei;       // edge_index[0] = src (x_j)
  const int* dstI = ei + E;   // edge_index[1] = dst (x_i)

  float* ws  = (float*)d_ws;
  float* h    = ws;
  float* hw1  = h   + (size_t)N * 64;
  float* hw2  = hw1 + (size_t)N * 64;
  float* agg  = hw2 + (size_t)N * 64;
  float* gsum = agg + (size_t)N * 64;
  float* gcnt = gsum + (size_t)G * 64;
  unsigned short* ebuf16 = (unsigned short*)(gcnt + G);  // [E,64] bf16
  unsigned short* w3f    = ebuf16 + (size_t)E * 64;      // 2 layers x 4096 bf16

  const float* W3a = msg_w + 128 * 64;
  const float* W3b = msg_w + (size_t)192 * 64 + 128 * 64;

  const size_t fixed_floats = (size_t)N * 64 * 4 + (size_t)G * 64 + G;
  const bool pre = (ws_size / 4 >= fixed_floats + (size_t)E * 16 + 2048 + 16);

  const int nblk  = (N + 3) / 4;                     // 4 node rows per block
  const int eblkE = (E + 15) / 16;                   // edge-embed blocks
  const int eblkM = (E + 63) / 64;                   // 64 edges / 256-thr block
  const int eblkF = (E + 15) / 16;                   // fallback blocks

  // embed + msgw(layer0) + agg=0
  k_embed_msgw<<<nblk, 256, 0, stream>>>(
      x, ne_w, ne_b, ne_g, ne_be, msg_w, h, hw1, hw2, agg, N);
  if (pre) {
    k_edge_embed<<<eblkE, 256, 0, stream>>>(ea, ee_w, ee_b, ee_g, ee_be, ebuf16, E);
    k_w3_pack<<<4, 256, 0, stream>>>(W3a, W3b, w3f);
  }

  // ---- layer 0 ----
  if (pre) {
    k_edge_msg_mfma<<<eblkM, 256, 0, stream>>>(
        ebuf16, w3f, msg_b, msg_g, msg_be,
        hw1, hw2, srcI, dstI, agg, E);
  } else {
    k_edge_msg_fb<<<eblkF, 256, 0, stream>>>(
        ea, ee_w, ee_b, ee_g, ee_be,
        W3a, msg_b, msg_g, msg_be,
        hw1, hw2, srcI, dstI, agg, E);
  }
  // update(l=0) + msgw(layer1) + agg=0
  k_update_msgw<<<nblk, 256, 0, stream>>>(
      h, agg, upd_w, upd_b, upd_g, upd_be, nrm_g, nrm_be,
      msg_w + (size_t)192 * 64, hw1, hw2, N);

  // ---- layer 1 ----
  if (pre) {
    k_edge_msg_mfma<<<eblkM, 256, 0, stream>>>(
        ebuf16, w3f + 4096, msg_b + 64, msg_g + 64, msg_be + 64,
        hw1, hw2, srcI, dstI, agg, E);
  } else {
    k_edge_msg_fb<<<eblkF, 256, 0, stream>>>(
        ea, ee_w, ee_b, ee_g, ee_be,
        W3b, msg_b + 64, msg_g + 64, msg_be + 64,
        hw1, hw2, srcI, dstI, agg, E);
  }
  hipMemsetAsync(gsum, 0, ((size_t)G * 64 + G) * sizeof(float), stream);
  // update(l=1) + pool
  k_update_pool<<<nblk, 256, 0, stream>>>(
      h, agg, upd_w + (size_t)64 * 64, upd_b + 64, upd_g + 64, upd_be + 64,
      nrm_g + 64, nrm_be + 64, batch, gsum, gcnt, N);

  k_head<<<G, 64, 0, stream>>>(gsum, gcnt, h1_w, h1_b, h1_g, h1_be, h2_w, h2_b, out, G);
}

// Round 19
// 665.489 us; speedup vs baseline: 3.5659x; 1.1721x over previous
//
#include <hip/hip_runtime.h>
#include <math.h>

typedef __attribute__((ext_vector_type(8))) short short8;
typedef __attribute__((ext_vector_type(4))) float f32x4;

// ---------- helpers ----------
__device__ __forceinline__ float silu_f(float x) { return x / (1.0f + __expf(-x)); }

// f32 -> bf16 round-to-nearest-even (finite values only)
__device__ __forceinline__ unsigned short f2bf(float f) {
  unsigned int u = __float_as_uint(f);
  unsigned int r = (u + 0x7fffu + ((u >> 16) & 1u)) >> 16;
  return (unsigned short)r;
}

// LayerNorm across a 64-lane wave; two reduce chains explicitly interleaved
__device__ __forceinline__ float ln64(float v, float g, float b) {
  float s = v, s2 = v * v;
#pragma unroll
  for (int m = 32; m > 0; m >>= 1) {
    s  += __shfl_xor(s,  m, 64);
    s2 += __shfl_xor(s2, m, 64);
  }
  float mean = s * 0.015625f;
  float var  = fmaxf(s2 * 0.015625f - mean * mean, 0.0f);
  return (v - mean) * rsqrtf(var + 1e-5f) * g + b;
}

// ---------- FUSED: node embed -> h, hw1/hw2(layer0), agg=0 ----------
__global__ __launch_bounds__(256) void k_embed_msgw(
    const float* __restrict__ x, const float* __restrict__ neW,
    const float* __restrict__ neB, const float* __restrict__ neG,
    const float* __restrict__ neBe, const float* __restrict__ W,   // msg_w[0], rows 0..127
    float* __restrict__ h, float* __restrict__ hw1, float* __restrict__ hw2,
    float* __restrict__ agg, int n) {
  __shared__ float sRow[4][64];
  const int row = (blockIdx.x * 256 + threadIdx.x) >> 6;
  const int wv = threadIdx.x >> 6;
  const int j  = threadIdx.x & 63;
  if (row >= n) return;

  const float* xr = x + (size_t)row * 16;
  float acc = neB[j];
#pragma unroll
  for (int k = 0; k < 16; k += 4) {
    float4 xv = *(const float4*)&xr[k];
    acc += xv.x * neW[(k + 0) * 64 + j] + xv.y * neW[(k + 1) * 64 + j] +
           xv.z * neW[(k + 2) * 64 + j] + xv.w * neW[(k + 3) * 64 + j];
  }
  float hv = silu_f(ln64(acc, neG[j], neBe[j]));
  h[(size_t)row * 64 + j] = hv;
  agg[(size_t)row * 64 + j] = 0.0f;
  sRow[wv][j] = hv;                    // same-wave write->read: ordered

  float a1 = 0.0f, a2 = 0.0f;
#pragma unroll
  for (int k = 0; k < 64; k += 4) {
    float4 r = *(const float4*)&sRow[wv][k];
    a1 += r.x * W[(k + 0) * 64 + j] + r.y * W[(k + 1) * 64 + j] +
          r.z * W[(k + 2) * 64 + j] + r.w * W[(k + 3) * 64 + j];
    a2 += r.x * W[(64 + k + 0) * 64 + j] + r.y * W[(64 + k + 1) * 64 + j] +
          r.z * W[(64 + k + 2) * 64 + j] + r.w * W[(64 + k + 3) * 64 + j];
  }
  hw1[(size_t)row * 64 + j] = a1;
  hw2[(size_t)row * 64 + j] = a2;
}

// ---------- pack (ONCE): bf16 MFMA B-fragments for W3 (both layers) + eeW ----
// W3 frags: w3f[((L*2+kh)*4+jt)*64+l][i] = bf16(W3_L[(kh*32+(l>>4)*8+i)*64 + jt*16+(l&15)])
// eeW frags (K padded 8->32): w3f[8192 + (jt*64+l)*8 + i] =
//   (l>>4)==0 ? bf16(eeW[i*64 + jt*16+(l&15)]) : 0
__global__ __launch_bounds__(256) void k_w3_pack(
    const float* __restrict__ W3a, const float* __restrict__ W3b,
    const float* __restrict__ eeW, unsigned short* __restrict__ w3f) {
  int t = blockIdx.x * 256 + threadIdx.x;
  if (t < 1024) {
    int L  = t >> 9;
    int kh = (t >> 8) & 1;
    int jt = (t >> 6) & 3;
    int l  = t & 63;
    const float* W3 = L ? W3b : W3a;
    unsigned short* dst = w3f + (size_t)t * 8;
#pragma unroll
    for (int i = 0; i < 8; ++i)
      dst[i] = f2bf(W3[(kh * 32 + (l >> 4) * 8 + i) * 64 + jt * 16 + (l & 15)]);
  } else if (t < 1280) {
    int tt = t - 1024;
    int jt = tt >> 6;
    int l  = tt & 63;
    unsigned short* dst = w3f + 8192 + (size_t)tt * 8;
    int hi = l >> 4;
#pragma unroll
    for (int i = 0; i < 8; ++i)
      dst[i] = (hi == 0) ? f2bf(eeW[i * 64 + jt * 16 + (l & 15)])
                         : (unsigned short)0;
  }
}

// ---------- edge message, FULLY FUSED via MFMA: 16 edges/wave ----------
// e = silu(LN(ea@eeW + eeB)); msg = LN(silu(e@W3 + hw1[dst]+hw2[src]+msg_b));
// agg[dst] += msg.  Phase1 D-layout -> LDS (72-short padded rows) -> phase2 A.
__global__ __launch_bounds__(256) void k_edge_msg_mfma(
    const float* __restrict__ ea,
    const unsigned short* __restrict__ w3l,    // this layer's W3 frags
    const unsigned short* __restrict__ eewf,   // eeW frags
    const float* __restrict__ eeB, const float* __restrict__ eeG,
    const float* __restrict__ eeBe,
    const float* __restrict__ msgB, const float* __restrict__ msgG,
    const float* __restrict__ msgBe,
    const float* __restrict__ hw1, const float* __restrict__ hw2,
    const int* __restrict__ srcI, const int* __restrict__ dstI,
    float* __restrict__ agg, int nedges) {
  __shared__ __align__(16) unsigned short sEB[4][16][72];   // 9216 B (pad: no 128B-stride conflict)

  const int wv = threadIdx.x >> 6;
  const int l  = threadIdx.x & 63;
  const int ebase = (blockIdx.x * 4 + wv) * 16;
  if (ebase >= nedges) return;
  const int lo = l & 15, hi = l >> 4;

  // ---- phase 1: edge embedding via MFMA (K zero-padded 8->32) ----
  short8 ae = {0, 0, 0, 0, 0, 0, 0, 0};
  if (hi == 0) {
    const float* ar = ea + (size_t)min(ebase + lo, nedges - 1) * 8;
    float4 p0 = *(const float4*)ar;
    float4 p1 = *(const float4*)(ar + 4);
    ae[0] = (short)f2bf(p0.x); ae[1] = (short)f2bf(p0.y);
    ae[2] = (short)f2bf(p0.z); ae[3] = (short)f2bf(p0.w);
    ae[4] = (short)f2bf(p1.x); ae[5] = (short)f2bf(p1.y);
    ae[6] = (short)f2bf(p1.z); ae[7] = (short)f2bf(p1.w);
  }
  f32x4 acc_e[4];
#pragma unroll
  for (int jt = 0; jt < 4; ++jt) {
    short8 be = *(const short8*)(eewf + (size_t)(jt * 64 + l) * 8);
    f32x4 c = {0.f, 0.f, 0.f, 0.f};
    acc_e[jt] = __builtin_amdgcn_mfma_f32_16x16x32_bf16(ae, be, c, 0, 0, 0);
  }
  {
    float ebv[4], egv[4], ebev[4];
#pragma unroll
    for (int jt = 0; jt < 4; ++jt) {
      ebv[jt]  = eeB[jt * 16 + lo];
      egv[jt]  = eeG[jt * 16 + lo];
      ebev[jt] = eeBe[jt * 16 + lo];
    }
#pragma unroll
    for (int r = 0; r < 4; ++r) {
      float v[4];
      float s = 0.f, s2 = 0.f;
#pragma unroll
      for (int jt = 0; jt < 4; ++jt) {
        float t = acc_e[jt][r] + ebv[jt];
        v[jt] = t; s += t; s2 += t * t;
      }
#pragma unroll
      for (int m = 8; m > 0; m >>= 1) {      // 16-lane group reduce
        s  += __shfl_xor(s,  m, 64);
        s2 += __shfl_xor(s2, m, 64);
      }
      float mean = s * 0.015625f;
      float var  = fmaxf(s2 * 0.015625f - mean * mean, 0.f);
      float rsq  = rsqrtf(var + 1e-5f);
#pragma unroll
      for (int jt = 0; jt < 4; ++jt) {
        float ev = silu_f((v[jt] - mean) * rsq * egv[jt] + ebev[jt]);
        sEB[wv][hi * 4 + r][jt * 16 + lo] = f2bf(ev);   // same-wave ordered
      }
    }
  }

  // ---- gathers (issued now; consumed only in epilogue) ----
  int dIdx[4];
  float g1[4][4], g2[4][4];
#pragma unroll
  for (int r = 0; r < 4; ++r) {
    int ce = min(ebase + hi * 4 + r, nedges - 1);
    int s = srcI[ce];
    dIdx[r] = dstI[ce];
#pragma unroll
    for (int jt = 0; jt < 4; ++jt) {
      g1[r][jt] = hw1[(size_t)dIdx[r] * 64 + jt * 16 + lo];
      g2[r][jt] = hw2[(size_t)s * 64 + jt * 16 + lo];
    }
  }

  // ---- phase 2: A-frags from LDS (transposed for free), W3 MFMAs ----
  const unsigned short* rowp = &sEB[wv][lo][0];
  short8 a0 = *(const short8*)(rowp + hi * 8);
  short8 a1 = *(const short8*)(rowp + 32 + hi * 8);

  f32x4 acc[4];
#pragma unroll
  for (int jt = 0; jt < 4; ++jt) {
    short8 b0 = *(const short8*)(w3l + ((size_t)(0 * 4 + jt) * 64 + l) * 8);
    short8 b1 = *(const short8*)(w3l + ((size_t)(1 * 4 + jt) * 64 + l) * 8);
    f32x4 c = {0.f, 0.f, 0.f, 0.f};
    c = __builtin_amdgcn_mfma_f32_16x16x32_bf16(a0, b0, c, 0, 0, 0);
    c = __builtin_amdgcn_mfma_f32_16x16x32_bf16(a1, b1, c, 0, 0, 0);
    acc[jt] = c;
  }

  float mB[4], mG[4], mBe[4];
#pragma unroll
  for (int jt = 0; jt < 4; ++jt) {
    mB[jt]  = msgB[jt * 16 + lo];
    mG[jt]  = msgG[jt * 16 + lo];
    mBe[jt] = msgBe[jt * 16 + lo];
  }

  // epilogue per edge-reg r: bias+gathers, silu, LN over 16-lane group, scatter
#pragma unroll
  for (int r = 0; r < 4; ++r) {
    float mp[4];
    float s = 0.0f, s2 = 0.0f;
#pragma unroll
    for (int jt = 0; jt < 4; ++jt) {
      float v = acc[jt][r] + g1[r][jt] + g2[r][jt] + mB[jt];
      v = silu_f(v);
      mp[jt] = v;
      s += v;
      s2 += v * v;
    }
#pragma unroll
    for (int m = 8; m > 0; m >>= 1) {
      s  += __shfl_xor(s,  m, 64);
      s2 += __shfl_xor(s2, m, 64);
    }
    float mean = s * 0.015625f;
    float var  = fmaxf(s2 * 0.015625f - mean * mean, 0.0f);
    float rsq  = rsqrtf(var + 1e-5f);
    if (ebase + hi * 4 + r < nedges) {
#pragma unroll
      for (int jt = 0; jt < 4; ++jt) {
        float m2 = (mp[jt] - mean) * rsq * mG[jt] + mBe[jt];
        unsafeAtomicAdd(&agg[(size_t)dIdx[r] * 64 + jt * 16 + lo], m2);
      }
    }
  }
}

// ---------- edge message FALLBACK (ws too small): r9 proven kernel ----------
#define EPW 4
__global__ __launch_bounds__(256) void k_edge_msg_fb(
    const float* __restrict__ ea, const float* __restrict__ eeW,
    const float* __restrict__ eeB, const float* __restrict__ eeG,
    const float* __restrict__ eeBe,
    const float* __restrict__ W3, const float* __restrict__ msgB,
    const float* __restrict__ msgG, const float* __restrict__ msgBe,
    const float* __restrict__ hw1, const float* __restrict__ hw2,
    const int* __restrict__ srcI, const int* __restrict__ dstI,
    float* __restrict__ agg, int nedges) {
  __shared__ float sE[4][EPW][64];
  __shared__ float sEA[4][EPW * 8];

  const int wv = threadIdx.x >> 6;
  const int j  = threadIdx.x & 63;
  const int ebase = (blockIdx.x * 4 + wv) * EPW;
  if (ebase >= nedges) return;

  if (j < 32) {
    long long gi = (long long)ebase * 8 + j;
    long long gmax = (long long)nedges * 8 - 1;
    if (gi > gmax) gi = gmax;
    sEA[wv][j] = ea[gi];
  }

  const float bj = msgB[j];
  int dIdx[EPW];
  float acc[EPW];
#pragma unroll
  for (int e = 0; e < EPW; ++e) {
    int ce = min(ebase + e, nedges - 1);
    int s = srcI[ce];
    dIdx[e] = dstI[ce];
    acc[e] = hw1[(size_t)dIdx[e] * 64 + j] + hw2[(size_t)s * 64 + j] + bj;
  }
  {
    float ewc[8];
#pragma unroll
    for (int k = 0; k < 8; ++k) ewc[k] = eeW[k * 64 + j];
    const float eb = eeB[j], eg = eeG[j], ebe = eeBe[j];
#pragma unroll
    for (int e = 0; e < EPW; ++e) {
      const float* ar = &sEA[wv][e * 8];
      float ev = eb;
#pragma unroll
      for (int k = 0; k < 8; ++k) ev += ar[k] * ewc[k];
      ev = silu_f(ln64(ev, eg, ebe));
      sE[wv][e][j] = ev;
    }
  }
#pragma unroll
  for (int k = 0; k < 64; k += 4) {
    float w0 = W3[(k + 0) * 64 + j];
    float w1 = W3[(k + 1) * 64 + j];
    float w2 = W3[(k + 2) * 64 + j];
    float w3 = W3[(k + 3) * 64 + j];
#pragma unroll
    for (int e = 0; e < EPW; ++e) {
      float4 ev4 = *(const float4*)&sE[wv][e][k];
      acc[e] += ev4.x * w0 + ev4.y * w1 + ev4.z * w2 + ev4.w * w3;
    }
  }
  const float mg = msgG[j], mbe = msgBe[j];
#pragma unroll
  for (int e = 0; e < EPW; ++e) {
    float m = ln64(silu_f(acc[e]), mg, mbe);
    if (ebase + e < nedges) unsafeAtomicAdd(&agg[(size_t)dIdx[e] * 64 + j], m);
  }
}

// ---------- FUSED: update(in-place) -> hw1/hw2(next layer), agg=0 ----------
__global__ __launch_bounds__(256) void k_update_msgw(
    float* h, float* agg,                       // agg read then zeroed
    const float* __restrict__ W, const float* __restrict__ b,
    const float* __restrict__ ug, const float* __restrict__ ube,
    const float* __restrict__ ng, const float* __restrict__ nbe,
    const float* __restrict__ Wn,               // next layer msg_w rows 0..127
    float* __restrict__ hw1, float* __restrict__ hw2, int n) {
  __shared__ float sRow[4][64];
  const int row = (blockIdx.x * 256 + threadIdx.x) >> 6;
  const int wv = threadIdx.x >> 6;
  const int j  = threadIdx.x & 63;
  if (row >= n) return;

  float* hr = h + (size_t)row * 64;
  float* ar = agg + (size_t)row * 64;
  float acc = b[j];
  float hj = hr[j];
#pragma unroll
  for (int k = 0; k < 64; k += 4) {
    float4 hv = *(const float4*)&hr[k];
    float4 av = *(const float4*)&ar[k];
    acc += (hv.x + av.x) * W[(k + 0) * 64 + j] + (hv.y + av.y) * W[(k + 1) * 64 + j] +
           (hv.z + av.z) * W[(k + 2) * 64 + j] + (hv.w + av.w) * W[(k + 3) * 64 + j];
  }
  float u = ln64(silu_f(acc), ug[j], ube[j]);
  float hn = ln64(u + hj, ng[j], nbe[j]);
  hr[j] = hn;
  ar[j] = 0.0f;                        // zero agg for next layer
  sRow[wv][j] = hn;                    // same-wave ordered

  float a1 = 0.0f, a2 = 0.0f;
#pragma unroll
  for (int k = 0; k < 64; k += 4) {
    float4 r = *(const float4*)&sRow[wv][k];
    a1 += r.x * Wn[(k + 0) * 64 + j] + r.y * Wn[(k + 1) * 64 + j] +
          r.z * Wn[(k + 2) * 64 + j] + r.w * Wn[(k + 3) * 64 + j];
    a2 += r.x * Wn[(64 + k + 0) * 64 + j] + r.y * Wn[(64 + k + 1) * 64 + j] +
          r.z * Wn[(64 + k + 2) * 64 + j] + r.w * Wn[(64 + k + 3) * 64 + j];
  }
  hw1[(size_t)row * 64 + j] = a1;
  hw2[(size_t)row * 64 + j] = a2;
}

// ---------- FUSED: final update(in-place) -> pool atomics ----------
__global__ __launch_bounds__(256) void k_update_pool(
    float* h, const float* __restrict__ agg,
    const float* __restrict__ W, const float* __restrict__ b,
    const float* __restrict__ ug, const float* __restrict__ ube,
    const float* __restrict__ ng, const float* __restrict__ nbe,
    const int* __restrict__ batch, float* __restrict__ gsum,
    float* __restrict__ gcnt, int n) {
  const int row = (blockIdx.x * 256 + threadIdx.x) >> 6;
  const int j  = threadIdx.x & 63;
  if (row >= n) return;

  float* hr = h + (size_t)row * 64;
  const float* ar = agg + (size_t)row * 64;
  float acc = b[j];
  float hj = hr[j];
#pragma unroll
  for (int k = 0; k < 64; k += 4) {
    float4 hv = *(const float4*)&hr[k];
    float4 av = *(const float4*)&ar[k];
    acc += (hv.x + av.x) * W[(k + 0) * 64 + j] + (hv.y + av.y) * W[(k + 1) * 64 + j] +
           (hv.z + av.z) * W[(k + 2) * 64 + j] + (hv.w + av.w) * W[(k + 3) * 64 + j];
  }
  float u = ln64(silu_f(acc), ug[j], ube[j]);
  float hn = ln64(u + hj, ng[j], nbe[j]);

  int bb = batch[row];
  unsafeAtomicAdd(&gsum[(size_t)bb * 64 + j], hn);
  if (j == 0) unsafeAtomicAdd(&gcnt[bb], 1.0f);
}

// ---------- head: out = silu(LN(g@h1_w+b)) @ h2_w + h2_b ----------
__global__ __launch_bounds__(64) void k_head(
    const float* __restrict__ gsum, const float* __restrict__ gcnt,
    const float* __restrict__ w1, const float* __restrict__ b1,
    const float* __restrict__ g1, const float* __restrict__ be1,
    const float* __restrict__ w2, const float* __restrict__ b2,
    float* __restrict__ out, int ngraphs) {
  int gidx = blockIdx.x;
  int j = threadIdx.x;
  if (gidx >= ngraphs) return;
  __shared__ float sg[64];
  float cnt = fmaxf(gcnt[gidx], 1.0f);
  sg[j] = gsum[(size_t)gidx * 64 + j] / cnt;
  float acc = 0.0f;
  if (j < 32) {
    acc = b1[j];
#pragma unroll 8
    for (int k = 0; k < 64; ++k) acc += sg[k] * w1[k * 32 + j];
  }
  float s = acc, s2 = acc * acc;
#pragma unroll
  for (int m = 16; m > 0; m >>= 1) {
    s  += __shfl_xor(s,  m, 64);
    s2 += __shfl_xor(s2, m, 64);
  }
  float mean = s * 0.03125f;
  float var  = fmaxf(s2 * 0.03125f - mean * mean, 0.0f);
  float z = 0.0f;
  if (j < 32) {
    float nv = (acc - mean) * rsqrtf(var + 1e-5f) * g1[j] + be1[j];
    z = silu_f(nv) * w2[j];
  }
#pragma unroll
  for (int m = 32; m > 0; m >>= 1) z += __shfl_xor(z, m, 64);
  if (j == 0) out[gidx] = z + b2[0];
}

// ---------- launch ----------
extern "C" void kernel_launch(void* const* d_in, const int* in_sizes, int n_in,
                              void* d_out, int out_size, void* d_ws, size_t ws_size,
                              hipStream_t stream) {
  const float* x      = (const float*)d_in[0];
  const float* ea     = (const float*)d_in[1];
  const float* ne_w   = (const float*)d_in[2];
  const float* ne_b   = (const float*)d_in[3];
  const float* ne_g   = (const float*)d_in[4];
  const float* ne_be  = (const float*)d_in[5];
  const float* ee_w   = (const float*)d_in[6];
  const float* ee_b   = (const float*)d_in[7];
  const float* ee_g   = (const float*)d_in[8];
  const float* ee_be  = (const float*)d_in[9];
  const float* msg_w  = (const float*)d_in[10];
  const float* msg_b  = (const float*)d_in[11];
  const float* msg_g  = (const float*)d_in[12];
  const float* msg_be = (const float*)d_in[13];
  const float* upd_w  = (const float*)d_in[14];
  const float* upd_b  = (const float*)d_in[15];
  const float* upd_g  = (const float*)d_in[16];
  const float* upd_be = (const float*)d_in[17];
  const float* nrm_g  = (const float*)d_in[18];
  const float* nrm_be = (const float*)d_in[19];
  const float* h1_w   = (const float*)d_in[20];
  const float* h1_b   = (const float*)d_in[21];
  const float* h1_g   = (const float*)d_in[22];
  const float* h1_be  = (const float*)d_in[23];
  const float* h2_w   = (const float*)d_in[24];
  const float* h2_b   = (const float*)d_in[25];
  const int*   ei     = (const int*)d_in[26];
  const int*   batch  = (const int*)d_in[27];
  float* out = (float*)d_out;

  const int N = in_sizes[0] / 16;
  const int E = in_sizes[1] / 8;
  const int G = out_size;
  const int* srcI = ei;       // edge_index[0] = src (x_j)
  const int* dstI = ei + E;   // edge_index[1] = dst (x_i)

  float* ws  = (float*)d_ws;
  float* h    = ws;
  float* hw1  = h   + (size_t)N * 64;
  float* hw2  = hw1 + (size_t)N * 64;
  float* agg  = hw2 + (size_t)N * 64;
  float* gsum = agg + (size_t)N * 64;
  float* gcnt = gsum + (size_t)G * 64;
  unsigned short* w3f = (unsigned short*)(gcnt + G);  // 10240 bf16 fragments

  const float* W3a = msg_w + 128 * 64;
  const float* W3b = msg_w + (size_t)192 * 64 + 128 * 64;

  const size_t fixed_floats = (size_t)N * 64 * 4 + (size_t)G * 64 + G;
  const bool pre = (ws_size / 4 >= fixed_floats + 5120 + 16);

  const int nblk  = (N + 3) / 4;                     // 4 node rows per block
  const int eblkM = (E + 63) / 64;                   // 64 edges / 256-thr block
  const int eblkF = (E + 15) / 16;                   // fallback blocks

  // embed + msgw(layer0) + agg=0
  k_embed_msgw<<<nblk, 256, 0, stream>>>(
      x, ne_w, ne_b, ne_g, ne_be, msg_w, h, hw1, hw2, agg, N);
  if (pre)
    k_w3_pack<<<5, 256, 0, stream>>>(W3a, W3b, ee_w, w3f);

  // ---- layer 0 ----
  if (pre) {
    k_edge_msg_mfma<<<eblkM, 256, 0, stream>>>(
        ea, w3f, w3f + 8192, ee_b, ee_g, ee_be,
        msg_b, msg_g, msg_be, hw1, hw2, srcI, dstI, agg, E);
  } else {
    k_edge_msg_fb<<<eblkF, 256, 0, stream>>>(
        ea, ee_w, ee_b, ee_g, ee_be,
        W3a, msg_b, msg_g, msg_be,
        hw1, hw2, srcI, dstI, agg, E);
  }
  // update(l=0) + msgw(layer1) + agg=0
  k_update_msgw<<<nblk, 256, 0, stream>>>(
      h, agg, upd_w, upd_b, upd_g, upd_be, nrm_g, nrm_be,
      msg_w + (size_t)192 * 64, hw1, hw2, N);

  // ---- layer 1 ----
  if (pre) {
    k_edge_msg_mfma<<<eblkM, 256, 0, stream>>>(
        ea, w3f + 4096, w3f + 8192, ee_b, ee_g, ee_be,
        msg_b + 64, msg_g + 64, msg_be + 64,
        hw1, hw2, srcI, dstI, agg, E);
  } else {
    k_edge_msg_fb<<<eblkF, 256, 0, stream>>>(
        ea, ee_w, ee_b, ee_g, ee_be,
        W3b, msg_b + 64, msg_g + 64, msg_be + 64,
        hw1, hw2, srcI, dstI, agg, E);
  }
  hipMemsetAsync(gsum, 0, ((size_t)G * 64 + G) * sizeof(float), stream);
  // update(l=1) + pool
  k_update_pool<<<nblk, 256, 0, stream>>>(
      h, agg, upd_w + (size_t)64 * 64, upd_b + 64, upd_g + 64, upd_be + 64,
      nrm_g + 64, nrm_be + 64, batch, gsum, gcnt, N);

  k_head<<<G, 64, 0, stream>>>(gsum, gcnt, h1_w, h1_b, h1_g, h1_be, h2_w, h2_b, out, G);
}

// Round 20
// 490.560 us; speedup vs baseline: 4.8374x; 1.3566x over previous
//
#include <hip/hip_runtime.h>
#include <math.h>

typedef __attribute__((ext_vector_type(8))) short short8;
typedef __attribute__((ext_vector_type(4))) float f32x4;

// ---------- helpers ----------
__device__ __forceinline__ float silu_f(float x) { return x / (1.0f + __expf(-x)); }

// f32 -> bf16 round-to-nearest-even (finite values only)
__device__ __forceinline__ unsigned short f2bf(float f) {
  unsigned int u = __float_as_uint(f);
  unsigned int r = (u + 0x7fffu + ((u >> 16) & 1u)) >> 16;
  return (unsigned short)r;
}

// LayerNorm across a 64-lane wave (scalar fallback path)
__device__ __forceinline__ float ln64(float v, float g, float b) {
  float s = v, s2 = v * v;
#pragma unroll
  for (int m = 32; m > 0; m >>= 1) {
    s  += __shfl_xor(s,  m, 64);
    s2 += __shfl_xor(s2, m, 64);
  }
  float mean = s * 0.015625f;
  float var  = fmaxf(s2 * 0.015625f - mean * mean, 0.0f);
  return (v - mean) * rsqrtf(var + 1e-5f) * g + b;
}

// dual reduce over 16-lane group
__device__ __forceinline__ void red16(float& s, float& s2) {
#pragma unroll
  for (int m = 8; m > 0; m >>= 1) {
    s  += __shfl_xor(s,  m, 64);
    s2 += __shfl_xor(s2, m, 64);
  }
}

// ---------- pack kernels (ONCE): f32 [K,64] -> bf16 MFMA B-fragments ----------
// frag f=kh*4+jt: dst[(f*64+l)*8+i] = bf16(src[(kh*32+(l>>4)*8+i)*64 + jt*16+(l&15)])
__global__ __launch_bounds__(256) void k_pack_mat(
    const float* __restrict__ src, unsigned short* __restrict__ dst, int nfrag) {
  int t = blockIdx.x * 256 + threadIdx.x;
  if (t >= nfrag * 64) return;
  int f = t >> 6, l = t & 63;
  int kh = f >> 2, jt = f & 3;
  unsigned short* d = dst + (size_t)t * 8;
#pragma unroll
  for (int i = 0; i < 8; ++i)
    d[i] = f2bf(src[(kh * 32 + (l >> 4) * 8 + i) * 64 + jt * 16 + (l & 15)]);
}

// K-real < 32, zero-padded to one K-half (4 frags)
__global__ __launch_bounds__(256) void k_pack_pad(
    const float* __restrict__ src, unsigned short* __restrict__ dst, int Kreal) {
  int t = threadIdx.x;
  int l = t & 63;
  unsigned short* d = dst + (size_t)t * 8;
#pragma unroll
  for (int i = 0; i < 8; ++i) {
    int row = (l >> 4) * 8 + i;
    d[i] = (row < Kreal) ? f2bf(src[row * 64 + (t >> 6) * 16 + (l & 15)])
                         : (unsigned short)0;
  }
}

// ---------- MFMA node embed: h = silu(LN(x@neW+b)); hw1/hw2(l0); agg=0 ----------
__global__ __launch_bounds__(256) void k_embed_msgw_mfma(
    const float* __restrict__ x,
    const unsigned short* __restrict__ neWf,   // 4 frags (K 16->32 padded)
    const float* __restrict__ neB, const float* __restrict__ neG,
    const float* __restrict__ neBe,
    const unsigned short* __restrict__ msgWf,  // 16 frags (rows 0..127)
    float* __restrict__ h, float* __restrict__ hw1, float* __restrict__ hw2,
    float* __restrict__ agg, int n) {
  __shared__ __align__(16) unsigned short sEB[4][16][72];
  const int wv = threadIdx.x >> 6;
  const int l  = threadIdx.x & 63;
  const int rbase = (blockIdx.x * 4 + wv) * 16;
  if (rbase >= n) return;
  const int lo = l & 15, hi = l >> 4;

  short8 ax = {0, 0, 0, 0, 0, 0, 0, 0};
  if (hi < 2) {
    const float* xr = x + (size_t)min(rbase + lo, n - 1) * 16 + hi * 8;
    float4 p0 = *(const float4*)xr;
    float4 p1 = *(const float4*)(xr + 4);
    ax[0] = (short)f2bf(p0.x); ax[1] = (short)f2bf(p0.y);
    ax[2] = (short)f2bf(p0.z); ax[3] = (short)f2bf(p0.w);
    ax[4] = (short)f2bf(p1.x); ax[5] = (short)f2bf(p1.y);
    ax[6] = (short)f2bf(p1.z); ax[7] = (short)f2bf(p1.w);
  }
  f32x4 acc[4];
#pragma unroll
  for (int jt = 0; jt < 4; ++jt) {
    short8 b = *(const short8*)(neWf + (size_t)(jt * 64 + l) * 8);
    f32x4 c = {0.f, 0.f, 0.f, 0.f};
    acc[jt] = __builtin_amdgcn_mfma_f32_16x16x32_bf16(ax, b, c, 0, 0, 0);
  }
  float nb[4], ngv[4], nbev[4];
#pragma unroll
  for (int jt = 0; jt < 4; ++jt) {
    nb[jt] = neB[jt * 16 + lo]; ngv[jt] = neG[jt * 16 + lo]; nbev[jt] = neBe[jt * 16 + lo];
  }
#pragma unroll
  for (int r = 0; r < 4; ++r) {
    int row = rbase + hi * 4 + r;
    float v[4]; float s = 0.f, s2 = 0.f;
#pragma unroll
    for (int jt = 0; jt < 4; ++jt) { float t = acc[jt][r] + nb[jt]; v[jt] = t; s += t; s2 += t * t; }
    red16(s, s2);
    float mean = s * 0.015625f;
    float var  = fmaxf(s2 * 0.015625f - mean * mean, 0.f);
    float rsq  = rsqrtf(var + 1e-5f);
#pragma unroll
    for (int jt = 0; jt < 4; ++jt) {
      float hv = silu_f((v[jt] - mean) * rsq * ngv[jt] + nbev[jt]);
      if (row < n) {
        h[(size_t)row * 64 + jt * 16 + lo] = hv;
        agg[(size_t)row * 64 + jt * 16 + lo] = 0.0f;
      }
      sEB[wv][hi * 4 + r][jt * 16 + lo] = f2bf(hv);   // same-wave ordered
    }
  }
  // phase 2: hw1 = h@msgW rows0..63 (kh 0,1); hw2 = rows64..127 (kh 2,3)
  const unsigned short* rowp = &sEB[wv][lo][0];
  short8 a0 = *(const short8*)(rowp + hi * 8);
  short8 a1 = *(const short8*)(rowp + 32 + hi * 8);
  f32x4 c1[4], c2[4];
#pragma unroll
  for (int jt = 0; jt < 4; ++jt) {
    f32x4 z = {0.f, 0.f, 0.f, 0.f};
    f32x4 t1 = __builtin_amdgcn_mfma_f32_16x16x32_bf16(
        a0, *(const short8*)(msgWf + (size_t)((0 * 4 + jt) * 64 + l) * 8), z, 0, 0, 0);
    t1 = __builtin_amdgcn_mfma_f32_16x16x32_bf16(
        a1, *(const short8*)(msgWf + (size_t)((1 * 4 + jt) * 64 + l) * 8), t1, 0, 0, 0);
    c1[jt] = t1;
    f32x4 t2 = __builtin_amdgcn_mfma_f32_16x16x32_bf16(
        a0, *(const short8*)(msgWf + (size_t)((2 * 4 + jt) * 64 + l) * 8), z, 0, 0, 0);
    t2 = __builtin_amdgcn_mfma_f32_16x16x32_bf16(
        a1, *(const short8*)(msgWf + (size_t)((3 * 4 + jt) * 64 + l) * 8), t2, 0, 0, 0);
    c2[jt] = t2;
  }
#pragma unroll
  for (int r = 0; r < 4; ++r) {
    int row = rbase + hi * 4 + r;
    if (row < n) {
#pragma unroll
      for (int jt = 0; jt < 4; ++jt) {
        hw1[(size_t)row * 64 + jt * 16 + lo] = c1[jt][r];
        hw2[(size_t)row * 64 + jt * 16 + lo] = c2[jt][r];
      }
    }
  }
}

// ---------- MFMA update (+msgw next layer): in-place h, agg read+zero ----------
__global__ __launch_bounds__(256) void k_update_msgw_mfma(
    float* h, float* agg,
    const unsigned short* __restrict__ updWf,  // 8 frags
    const float* __restrict__ ub, const float* __restrict__ ug,
    const float* __restrict__ ube, const float* __restrict__ ng,
    const float* __restrict__ nbe,
    const unsigned short* __restrict__ msgWfN, // 16 frags, next layer
    float* __restrict__ hw1, float* __restrict__ hw2, int n) {
  __shared__ __align__(16) unsigned short sEB[4][16][72];
  const int wv = threadIdx.x >> 6;
  const int l  = threadIdx.x & 63;
  const int rbase = (blockIdx.x * 4 + wv) * 16;
  if (rbase >= n) return;
  const int lo = l & 15, hi = l >> 6 == 0 ? (l >> 4) : (l >> 4);  // l>>4

  // A-frags of (h+agg), row rbase+lo (reads OLD h; stores come later)
  const int crow = min(rbase + lo, n - 1);
  const float* hrA = h + (size_t)crow * 64;
  const float* arA = agg + (size_t)crow * 64;
  short8 au0, au1;
  {
    float4 p0 = *(const float4*)(hrA + hi * 8);
    float4 p1 = *(const float4*)(hrA + hi * 8 + 4);
    float4 q0 = *(const float4*)(arA + hi * 8);
    float4 q1 = *(const float4*)(arA + hi * 8 + 4);
    au0[0] = (short)f2bf(p0.x + q0.x); au0[1] = (short)f2bf(p0.y + q0.y);
    au0[2] = (short)f2bf(p0.z + q0.z); au0[3] = (short)f2bf(p0.w + q0.w);
    au0[4] = (short)f2bf(p1.x + q1.x); au0[5] = (short)f2bf(p1.y + q1.y);
    au0[6] = (short)f2bf(p1.z + q1.z); au0[7] = (short)f2bf(p1.w + q1.w);
    float4 r0 = *(const float4*)(hrA + 32 + hi * 8);
    float4 r1 = *(const float4*)(hrA + 32 + hi * 8 + 4);
    float4 s0 = *(const float4*)(arA + 32 + hi * 8);
    float4 s1 = *(const float4*)(arA + 32 + hi * 8 + 4);
    au1[0] = (short)f2bf(r0.x + s0.x); au1[1] = (short)f2bf(r0.y + s0.y);
    au1[2] = (short)f2bf(r0.z + s0.z); au1[3] = (short)f2bf(r0.w + s0.w);
    au1[4] = (short)f2bf(r1.x + s1.x); au1[5] = (short)f2bf(r1.y + s1.y);
    au1[6] = (short)f2bf(r1.z + s1.z); au1[7] = (short)f2bf(r1.w + s1.w);
  }
  // residual h (old values) for my D-rows — read BEFORE any hn store
  float hres[4][4];
#pragma unroll
  for (int r = 0; r < 4; ++r) {
    int row = min(rbase + hi * 4 + r, n - 1);
#pragma unroll
    for (int jt = 0; jt < 4; ++jt)
      hres[r][jt] = h[(size_t)row * 64 + jt * 16 + lo];
  }

  f32x4 acc[4];
#pragma unroll
  for (int jt = 0; jt < 4; ++jt) {
    f32x4 z = {0.f, 0.f, 0.f, 0.f};
    f32x4 c = __builtin_amdgcn_mfma_f32_16x16x32_bf16(
        au0, *(const short8*)(updWf + (size_t)((0 * 4 + jt) * 64 + l) * 8), z, 0, 0, 0);
    c = __builtin_amdgcn_mfma_f32_16x16x32_bf16(
        au1, *(const short8*)(updWf + (size_t)((1 * 4 + jt) * 64 + l) * 8), c, 0, 0, 0);
    acc[jt] = c;
  }

  float ubv[4], ugv[4], ubev[4], ngv[4], nbev[4];
#pragma unroll
  for (int jt = 0; jt < 4; ++jt) {
    ubv[jt] = ub[jt * 16 + lo]; ugv[jt] = ug[jt * 16 + lo]; ubev[jt] = ube[jt * 16 + lo];
    ngv[jt] = ng[jt * 16 + lo]; nbev[jt] = nbe[jt * 16 + lo];
  }

#pragma unroll
  for (int r = 0; r < 4; ++r) {
    int row = rbase + hi * 4 + r;
    float v[4]; float s = 0.f, s2 = 0.f;
#pragma unroll
    for (int jt = 0; jt < 4; ++jt) {
      float t = silu_f(acc[jt][r] + ubv[jt]);
      v[jt] = t; s += t; s2 += t * t;
    }
    red16(s, s2);
    float mean = s * 0.015625f;
    float var  = fmaxf(s2 * 0.015625f - mean * mean, 0.f);
    float rsq  = rsqrtf(var + 1e-5f);
    float w[4]; float ws_ = 0.f, ws2 = 0.f;
#pragma unroll
    for (int jt = 0; jt < 4; ++jt) {
      float u = (v[jt] - mean) * rsq * ugv[jt] + ubev[jt];
      float t = u + hres[r][jt];
      w[jt] = t; ws_ += t; ws2 += t * t;
    }
    red16(ws_, ws2);
    float mean2 = ws_ * 0.015625f;
    float var2  = fmaxf(ws2 * 0.015625f - mean2 * mean2, 0.f);
    float rsq2  = rsqrtf(var2 + 1e-5f);
#pragma unroll
    for (int jt = 0; jt < 4; ++jt) {
      float hn = (w[jt] - mean2) * rsq2 * ngv[jt] + nbev[jt];
      if (row < n) {
        h[(size_t)row * 64 + jt * 16 + lo] = hn;
        agg[(size_t)row * 64 + jt * 16 + lo] = 0.0f;
      }
      sEB[wv][hi * 4 + r][jt * 16 + lo] = f2bf(hn);
    }
  }

  // phase 2: hw1/hw2 for next layer
  const unsigned short* rowp = &sEB[wv][lo][0];
  short8 a0 = *(const short8*)(rowp + hi * 8);
  short8 a1 = *(const short8*)(rowp + 32 + hi * 8);
  f32x4 c1[4], c2[4];
#pragma unroll
  for (int jt = 0; jt < 4; ++jt) {
    f32x4 z = {0.f, 0.f, 0.f, 0.f};
    f32x4 t1 = __builtin_amdgcn_mfma_f32_16x16x32_bf16(
        a0, *(const short8*)(msgWfN + (size_t)((0 * 4 + jt) * 64 + l) * 8), z, 0, 0, 0);
    t1 = __builtin_amdgcn_mfma_f32_16x16x32_bf16(
        a1, *(const short8*)(msgWfN + (size_t)((1 * 4 + jt) * 64 + l) * 8), t1, 0, 0, 0);
    c1[jt] = t1;
    f32x4 t2 = __builtin_amdgcn_mfma_f32_16x16x32_bf16(
        a0, *(const short8*)(msgWfN + (size_t)((2 * 4 + jt) * 64 + l) * 8), z, 0, 0, 0);
    t2 = __builtin_amdgcn_mfma_f32_16x16x32_bf16(
        a1, *(const short8*)(msgWfN + (size_t)((3 * 4 + jt) * 64 + l) * 8), t2, 0, 0, 0);
    c2[jt] = t2;
  }
#pragma unroll
  for (int r = 0; r < 4; ++r) {
    int row = rbase + hi * 4 + r;
    if (row < n) {
#pragma unroll
      for (int jt = 0; jt < 4; ++jt) {
        hw1[(size_t)row * 64 + jt * 16 + lo] = c1[jt][r];
        hw2[(size_t)row * 64 + jt * 16 + lo] = c2[jt][r];
      }
    }
  }
}

// ---------- MFMA final update + pool atomics ----------
__global__ __launch_bounds__(256) void k_update_pool_mfma(
    float* h, float* agg,
    const unsigned short* __restrict__ updWf,
    const float* __restrict__ ub, const float* __restrict__ ug,
    const float* __restrict__ ube, const float* __restrict__ ng,
    const float* __restrict__ nbe,
    const int* __restrict__ batch, float* __restrict__ gsum,
    float* __restrict__ gcnt, int n) {
  const int wv = threadIdx.x >> 6;
  const int l  = threadIdx.x & 63;
  const int rbase = (blockIdx.x * 4 + wv) * 16;
  if (rbase >= n) return;
  const int lo = l & 15, hi = l >> 4;

  const int crow = min(rbase + lo, n - 1);
  const float* hrA = h + (size_t)crow * 64;
  const float* arA = agg + (size_t)crow * 64;
  short8 au0, au1;
  {
    float4 p0 = *(const float4*)(hrA + hi * 8);
    float4 p1 = *(const float4*)(hrA + hi * 8 + 4);
    float4 q0 = *(const float4*)(arA + hi * 8);
    float4 q1 = *(const float4*)(arA + hi * 8 + 4);
    au0[0] = (short)f2bf(p0.x + q0.x); au0[1] = (short)f2bf(p0.y + q0.y);
    au0[2] = (short)f2bf(p0.z + q0.z); au0[3] = (short)f2bf(p0.w + q0.w);
    au0[4] = (short)f2bf(p1.x + q1.x); au0[5] = (short)f2bf(p1.y + q1.y);
    au0[6] = (short)f2bf(p1.z + q1.z); au0[7] = (short)f2bf(p1.w + q1.w);
    float4 r0 = *(const float4*)(hrA + 32 + hi * 8);
    float4 r1 = *(const float4*)(hrA + 32 + hi * 8 + 4);
    float4 s0 = *(const float4*)(arA + 32 + hi * 8);
    float4 s1 = *(const float4*)(arA + 32 + hi * 8 + 4);
    au1[0] = (short)f2bf(r0.x + s0.x); au1[1] = (short)f2bf(r0.y + s0.y);
    au1[2] = (short)f2bf(r0.z + s0.z); au1[3] = (short)f2bf(r0.w + s0.w);
    au1[4] = (short)f2bf(r1.x + s1.x); au1[5] = (short)f2bf(r1.y + s1.y);
    au1[6] = (short)f2bf(r1.z + s1.z); au1[7] = (short)f2bf(r1.w + s1.w);
  }
  float hres[4][4];
  int bb[4];
#pragma unroll
  for (int r = 0; r < 4; ++r) {
    int row = min(rbase + hi * 4 + r, n - 1);
    bb[r] = batch[row];
#pragma unroll
    for (int jt = 0; jt < 4; ++jt)
      hres[r][jt] = h[(size_t)row * 64 + jt * 16 + lo];
  }

  f32x4 acc[4];
#pragma unroll
  for (int jt = 0; jt < 4; ++jt) {
    f32x4 z = {0.f, 0.f, 0.f, 0.f};
    f32x4 c = __builtin_amdgcn_mfma_f32_16x16x32_bf16(
        au0, *(const short8*)(updWf + (size_t)((0 * 4 + jt) * 64 + l) * 8), z, 0, 0, 0);
    c = __builtin_amdgcn_mfma_f32_16x16x32_bf16(
        au1, *(const short8*)(updWf + (size_t)((1 * 4 + jt) * 64 + l) * 8), c, 0, 0, 0);
    acc[jt] = c;
  }

  float ubv[4], ugv[4], ubev[4], ngv[4], nbev[4];
#pragma unroll
  for (int jt = 0; jt < 4; ++jt) {
    ubv[jt] = ub[jt * 16 + lo]; ugv[jt] = ug[jt * 16 + lo]; ubev[jt] = ube[jt * 16 + lo];
    ngv[jt] = ng[jt * 16 + lo]; nbev[jt] = nbe[jt * 16 + lo];
  }

#pragma unroll
  for (int r = 0; r < 4; ++r) {
    int row = rbase + hi * 4 + r;
    float v[4]; float s = 0.f, s2 = 0.f;
#pragma unroll
    for (int jt = 0; jt < 4; ++jt) {
      float t = silu_f(acc[jt][r] + ubv[jt]);
      v[jt] = t; s += t; s2 += t * t;
    }
    red16(s, s2);
    float mean = s * 0.015625f;
    float var  = fmaxf(s2 * 0.015625f - mean * mean, 0.f);
    float rsq  = rsqrtf(var + 1e-5f);
    float w[4]; float ws_ = 0.f, ws2 = 0.f;
#pragma unroll
    for (int jt = 0; jt < 4; ++jt) {
      float u = (v[jt] - mean) * rsq * ugv[jt] + ubev[jt];
      float t = u + hres[r][jt];
      w[jt] = t; ws_ += t; ws2 += t * t;
    }
    red16(ws_, ws2);
    float mean2 = ws_ * 0.015625f;
    float var2  = fmaxf(ws2 * 0.015625f - mean2 * mean2, 0.f);
    float rsq2  = rsqrtf(var2 + 1e-5f);
    if (row < n) {
#pragma unroll
      for (int jt = 0; jt < 4; ++jt) {
        float hn = (w[jt] - mean2) * rsq2 * ngv[jt] + nbev[jt];
        unsafeAtomicAdd(&gsum[(size_t)bb[r] * 64 + jt * 16 + lo], hn);
      }
      if (lo == 0) unsafeAtomicAdd(&gcnt[bb[r]], 1.0f);
    }
  }
}

// ---------- edge message, FULLY FUSED via MFMA (r19 proven, unchanged) ----------
__global__ __launch_bounds__(256) void k_edge_msg_mfma(
    const float* __restrict__ ea,
    const unsigned short* __restrict__ w3l,
    const unsigned short* __restrict__ eewf,
    const float* __restrict__ eeB, const float* __restrict__ eeG,
    const float* __restrict__ eeBe,
    const float* __restrict__ msgB, const float* __restrict__ msgG,
    const float* __restrict__ msgBe,
    const float* __restrict__ hw1, const float* __restrict__ hw2,
    const int* __restrict__ srcI, const int* __restrict__ dstI,
    float* __restrict__ agg, int nedges) {
  __shared__ __align__(16) unsigned short sEB[4][16][72];

  const int wv = threadIdx.x >> 6;
  const int l  = threadIdx.x & 63;
  const int ebase = (blockIdx.x * 4 + wv) * 16;
  if (ebase >= nedges) return;
  const int lo = l & 15, hi = l >> 4;

  short8 ae = {0, 0, 0, 0, 0, 0, 0, 0};
  if (hi == 0) {
    const float* ar = ea + (size_t)min(ebase + lo, nedges - 1) * 8;
    float4 p0 = *(const float4*)ar;
    float4 p1 = *(const float4*)(ar + 4);
    ae[0] = (short)f2bf(p0.x); ae[1] = (short)f2bf(p0.y);
    ae[2] = (short)f2bf(p0.z); ae[3] = (short)f2bf(p0.w);
    ae[4] = (short)f2bf(p1.x); ae[5] = (short)f2bf(p1.y);
    ae[6] = (short)f2bf(p1.z); ae[7] = (short)f2bf(p1.w);
  }
  f32x4 acc_e[4];
#pragma unroll
  for (int jt = 0; jt < 4; ++jt) {
    short8 be = *(const short8*)(eewf + (size_t)(jt * 64 + l) * 8);
    f32x4 c = {0.f, 0.f, 0.f, 0.f};
    acc_e[jt] = __builtin_amdgcn_mfma_f32_16x16x32_bf16(ae, be, c, 0, 0, 0);
  }
  {
    float ebv[4], egv[4], ebev[4];
#pragma unroll
    for (int jt = 0; jt < 4; ++jt) {
      ebv[jt]  = eeB[jt * 16 + lo];
      egv[jt]  = eeG[jt * 16 + lo];
      ebev[jt] = eeBe[jt * 16 + lo];
    }
#pragma unroll
    for (int r = 0; r < 4; ++r) {
      float v[4];
      float s = 0.f, s2 = 0.f;
#pragma unroll
      for (int jt = 0; jt < 4; ++jt) {
        float t = acc_e[jt][r] + ebv[jt];
        v[jt] = t; s += t; s2 += t * t;
      }
      red16(s, s2);
      float mean = s * 0.015625f;
      float var  = fmaxf(s2 * 0.015625f - mean * mean, 0.f);
      float rsq  = rsqrtf(var + 1e-5f);
#pragma unroll
      for (int jt = 0; jt < 4; ++jt) {
        float ev = silu_f((v[jt] - mean) * rsq * egv[jt] + ebev[jt]);
        sEB[wv][hi * 4 + r][jt * 16 + lo] = f2bf(ev);
      }
    }
  }

  int dIdx[4];
  float g1[4][4], g2[4][4];
#pragma unroll
  for (int r = 0; r < 4; ++r) {
    int ce = min(ebase + hi * 4 + r, nedges - 1);
    int s = srcI[ce];
    dIdx[r] = dstI[ce];
#pragma unroll
    for (int jt = 0; jt < 4; ++jt) {
      g1[r][jt] = hw1[(size_t)dIdx[r] * 64 + jt * 16 + lo];
      g2[r][jt] = hw2[(size_t)s * 64 + jt * 16 + lo];
    }
  }

  const unsigned short* rowp = &sEB[wv][lo][0];
  short8 a0 = *(const short8*)(rowp + hi * 8);
  short8 a1 = *(const short8*)(rowp + 32 + hi * 8);

  f32x4 acc[4];
#pragma unroll
  for (int jt = 0; jt < 4; ++jt) {
    short8 b0 = *(const short8*)(w3l + ((size_t)(0 * 4 + jt) * 64 + l) * 8);
    short8 b1 = *(const short8*)(w3l + ((size_t)(1 * 4 + jt) * 64 + l) * 8);
    f32x4 c = {0.f, 0.f, 0.f, 0.f};
    c = __builtin_amdgcn_mfma_f32_16x16x32_bf16(a0, b0, c, 0, 0, 0);
    c = __builtin_amdgcn_mfma_f32_16x16x32_bf16(a1, b1, c, 0, 0, 0);
    acc[jt] = c;
  }

  float mB[4], mG[4], mBe[4];
#pragma unroll
  for (int jt = 0; jt < 4; ++jt) {
    mB[jt]  = msgB[jt * 16 + lo];
    mG[jt]  = msgG[jt * 16 + lo];
    mBe[jt] = msgBe[jt * 16 + lo];
  }

#pragma unroll
  for (int r = 0; r < 4; ++r) {
    float mp[4];
    float s = 0.0f, s2 = 0.0f;
#pragma unroll
    for (int jt = 0; jt < 4; ++jt) {
      float v = acc[jt][r] + g1[r][jt] + g2[r][jt] + mB[jt];
      v = silu_f(v);
      mp[jt] = v;
      s += v;
      s2 += v * v;
    }
    red16(s, s2);
    float mean = s * 0.015625f;
    float var  = fmaxf(s2 * 0.015625f - mean * mean, 0.0f);
    float rsq  = rsqrtf(var + 1e-5f);
    if (ebase + hi * 4 + r < nedges) {
#pragma unroll
      for (int jt = 0; jt < 4; ++jt) {
        float m2 = (mp[jt] - mean) * rsq * mG[jt] + mBe[jt];
        unsafeAtomicAdd(&agg[(size_t)dIdx[r] * 64 + jt * 16 + lo], m2);
      }
    }
  }
}

// ================== scalar fallback path (ws too small) ==================
__global__ __launch_bounds__(256) void k_embed_msgw(
    const float* __restrict__ x, const float* __restrict__ neW,
    const float* __restrict__ neB, const float* __restrict__ neG,
    const float* __restrict__ neBe, const float* __restrict__ W,
    float* __restrict__ h, float* __restrict__ hw1, float* __restrict__ hw2,
    float* __restrict__ agg, int n) {
  __shared__ float sRow[4][64];
  const int row = (blockIdx.x * 256 + threadIdx.x) >> 6;
  const int wv = threadIdx.x >> 6;
  const int j  = threadIdx.x & 63;
  if (row >= n) return;

  const float* xr = x + (size_t)row * 16;
  float acc = neB[j];
#pragma unroll
  for (int k = 0; k < 16; k += 4) {
    float4 xv = *(const float4*)&xr[k];
    acc += xv.x * neW[(k + 0) * 64 + j] + xv.y * neW[(k + 1) * 64 + j] +
           xv.z * neW[(k + 2) * 64 + j] + xv.w * neW[(k + 3) * 64 + j];
  }
  float hv = silu_f(ln64(acc, neG[j], neBe[j]));
  h[(size_t)row * 64 + j] = hv;
  agg[(size_t)row * 64 + j] = 0.0f;
  sRow[wv][j] = hv;

  float a1 = 0.0f, a2 = 0.0f;
#pragma unroll
  for (int k = 0; k < 64; k += 4) {
    float4 r = *(const float4*)&sRow[wv][k];
    a1 += r.x * W[(k + 0) * 64 + j] + r.y * W[(k + 1) * 64 + j] +
          r.z * W[(k + 2) * 64 + j] + r.w * W[(k + 3) * 64 + j];
    a2 += r.x * W[(64 + k + 0) * 64 + j] + r.y * W[(64 + k + 1) * 64 + j] +
          r.z * W[(64 + k + 2) * 64 + j] + r.w * W[(64 + k + 3) * 64 + j];
  }
  hw1[(size_t)row * 64 + j] = a1;
  hw2[(size_t)row * 64 + j] = a2;
}

#define EPW 4
__global__ __launch_bounds__(256) void k_edge_msg_fb(
    const float* __restrict__ ea, const float* __restrict__ eeW,
    const float* __restrict__ eeB, const float* __restrict__ eeG,
    const float* __restrict__ eeBe,
    const float* __restrict__ W3, const float* __restrict__ msgB,
    const float* __restrict__ msgG, const float* __restrict__ msgBe,
    const float* __restrict__ hw1, const float* __restrict__ hw2,
    const int* __restrict__ srcI, const int* __restrict__ dstI,
    float* __restrict__ agg, int nedges) {
  __shared__ float sE[4][EPW][64];
  __shared__ float sEA[4][EPW * 8];

  const int wv = threadIdx.x >> 6;
  const int j  = threadIdx.x & 63;
  const int ebase = (blockIdx.x * 4 + wv) * EPW;
  if (ebase >= nedges) return;

  if (j < 32) {
    long long gi = (long long)ebase * 8 + j;
    long long gmax = (long long)nedges * 8 - 1;
    if (gi > gmax) gi = gmax;
    sEA[wv][j] = ea[gi];
  }

  const float bj = msgB[j];
  int dIdx[EPW];
  float acc[EPW];
#pragma unroll
  for (int e = 0; e < EPW; ++e) {
    int ce = min(ebase + e, nedges - 1);
    int s = srcI[ce];
    dIdx[e] = dstI[ce];
    acc[e] = hw1[(size_t)dIdx[e] * 64 + j] + hw2[(size_t)s * 64 + j] + bj;
  }
  {
    float ewc[8];
#pragma unroll
    for (int k = 0; k < 8; ++k) ewc[k] = eeW[k * 64 + j];
    const float eb = eeB[j], eg = eeG[j], ebe = eeBe[j];
#pragma unroll
    for (int e = 0; e < EPW; ++e) {
      const float* ar = &sEA[wv][e * 8];
      float ev = eb;
#pragma unroll
      for (int k = 0; k < 8; ++k) ev += ar[k] * ewc[k];
      ev = silu_f(ln64(ev, eg, ebe));
      sE[wv][e][j] = ev;
    }
  }
#pragma unroll
  for (int k = 0; k < 64; k += 4) {
    float w0 = W3[(k + 0) * 64 + j];
    float w1 = W3[(k + 1) * 64 + j];
    float w2 = W3[(k + 2) * 64 + j];
    float w3 = W3[(k + 3) * 64 + j];
#pragma unroll
    for (int e = 0; e < EPW; ++e) {
      float4 ev4 = *(const float4*)&sE[wv][e][k];
      acc[e] += ev4.x * w0 + ev4.y * w1 + ev4.z * w2 + ev4.w * w3;
    }
  }
  const float mg = msgG[j], mbe = msgBe[j];
#pragma unroll
  for (int e = 0; e < EPW; ++e) {
    float m = ln64(silu_f(acc[e]), mg, mbe);
    if (ebase + e < nedges) unsafeAtomicAdd(&agg[(size_t)dIdx[e] * 64 + j], m);
  }
}

__global__ __launch_bounds__(256) void k_update_msgw(
    float* h, float* agg,
    const float* __restrict__ W, const float* __restrict__ b,
    const float* __restrict__ ug, const float* __restrict__ ube,
    const float* __restrict__ ng, const float* __restrict__ nbe,
    const float* __restrict__ Wn,
    float* __restrict__ hw1, float* __restrict__ hw2, int n) {
  __shared__ float sRow[4][64];
  const int row = (blockIdx.x * 256 + threadIdx.x) >> 6;
  const int wv = threadIdx.x >> 6;
  const int j  = threadIdx.x & 63;
  if (row >= n) return;

  float* hr = h + (size_t)row * 64;
  float* ar = agg + (size_t)row * 64;
  float acc = b[j];
  float hj = hr[j];
#pragma unroll
  for (int k = 0; k < 64; k += 4) {
    float4 hv = *(const float4*)&hr[k];
    float4 av = *(const float4*)&ar[k];
    acc += (hv.x + av.x) * W[(k + 0) * 64 + j] + (hv.y + av.y) * W[(k + 1) * 64 + j] +
           (hv.z + av.z) * W[(k + 2) * 64 + j] + (hv.w + av.w) * W[(k + 3) * 64 + j];
  }
  float u = ln64(silu_f(acc), ug[j], ube[j]);
  float hn = ln64(u + hj, ng[j], nbe[j]);
  hr[j] = hn;
  ar[j] = 0.0f;
  sRow[wv][j] = hn;

  float a1 = 0.0f, a2 = 0.0f;
#pragma unroll
  for (int k = 0; k < 64; k += 4) {
    float4 r = *(const float4*)&sRow[wv][k];
    a1 += r.x * Wn[(k + 0) * 64 + j] + r.y * Wn[(k + 1) * 64 + j] +
          r.z * Wn[(k + 2) * 64 + j] + r.w * Wn[(k + 3) * 64 + j];
    a2 += r.x * Wn[(64 + k + 0) * 64 + j] + r.y * Wn[(64 + k + 1) * 64 + j] +
          r.z * Wn[(64 + k + 2) * 64 + j] + r.w * Wn[(64 + k + 3) * 64 + j];
  }
  hw1[(size_t)row * 64 + j] = a1;
  hw2[(size_t)row * 64 + j] = a2;
}

__global__ __launch_bounds__(256) void k_update_pool(
    float* h, const float* __restrict__ agg,
    const float* __restrict__ W, const float* __restrict__ b,
    const float* __restrict__ ug, const float* __restrict__ ube,
    const float* __restrict__ ng, const float* __restrict__ nbe,
    const int* __restrict__ batch, float* __restrict__ gsum,
    float* __restrict__ gcnt, int n) {
  const int row = (blockIdx.x * 256 + threadIdx.x) >> 6;
  const int j  = threadIdx.x & 63;
  if (row >= n) return;

  float* hr = h + (size_t)row * 64;
  const float* ar = agg + (size_t)row * 64;
  float acc = b[j];
  float hj = hr[j];
#pragma unroll
  for (int k = 0; k < 64; k += 4) {
    float4 hv = *(const float4*)&hr[k];
    float4 av = *(const float4*)&ar[k];
    acc += (hv.x + av.x) * W[(k + 0) * 64 + j] + (hv.y + av.y) * W[(k + 1) * 64 + j] +
           (hv.z + av.z) * W[(k + 2) * 64 + j] + (hv.w + av.w) * W[(k + 3) * 64 + j];
  }
  float u = ln64(silu_f(acc), ug[j], ube[j]);
  float hn = ln64(u + hj, ng[j], nbe[j]);

  int bb = batch[row];
  unsafeAtomicAdd(&gsum[(size_t)bb * 64 + j], hn);
  if (j == 0) unsafeAtomicAdd(&gcnt[bb], 1.0f);
}

// ---------- head ----------
__global__ __launch_bounds__(64) void k_head(
    const float* __restrict__ gsum, const float* __restrict__ gcnt,
    const float* __restrict__ w1, const float* __restrict__ b1,
    const float* __restrict__ g1, const float* __restrict__ be1,
    const float* __restrict__ w2, const float* __restrict__ b2,
    float* __restrict__ out, int ngraphs) {
  int gidx = blockIdx.x;
  int j = threadIdx.x;
  if (gidx >= ngraphs) return;
  __shared__ float sg[64];
  float cnt = fmaxf(gcnt[gidx], 1.0f);
  sg[j] = gsum[(size_t)gidx * 64 + j] / cnt;
  float acc = 0.0f;
  if (j < 32) {
    acc = b1[j];
#pragma unroll 8
    for (int k = 0; k < 64; ++k) acc += sg[k] * w1[k * 32 + j];
  }
  float s = acc, s2 = acc * acc;
#pragma unroll
  for (int m = 16; m > 0; m >>= 1) {
    s  += __shfl_xor(s,  m, 64);
    s2 += __shfl_xor(s2, m, 64);
  }
  float mean = s * 0.03125f;
  float var  = fmaxf(s2 * 0.03125f - mean * mean, 0.0f);
  float z = 0.0f;
  if (j < 32) {
    float nv = (acc - mean) * rsqrtf(var + 1e-5f) * g1[j] + be1[j];
    z = silu_f(nv) * w2[j];
  }
#pragma unroll
  for (int m = 32; m > 0; m >>= 1) z += __shfl_xor(z, m, 64);
  if (j == 0) out[gidx] = z + b2[0];
}

// ---------- launch ----------
extern "C" void kernel_launch(void* const* d_in, const int* in_sizes, int n_in,
                              void* d_out, int out_size, void* d_ws, size_t ws_size,
                              hipStream_t stream) {
  const float* x      = (const float*)d_in[0];
  const float* ea     = (const float*)d_in[1];
  const float* ne_w   = (const float*)d_in[2];
  const float* ne_b   = (const float*)d_in[3];
  const float* ne_g   = (const float*)d_in[4];
  const float* ne_be  = (const float*)d_in[5];
  const float* ee_w   = (const float*)d_in[6];
  const float* ee_b   = (const float*)d_in[7];
  const float* ee_g   = (const float*)d_in[8];
  const float* ee_be  = (const float*)d_in[9];
  const float* msg_w  = (const float*)d_in[10];
  const float* msg_b  = (const float*)d_in[11];
  const float* msg_g  = (const float*)d_in[12];
  const float* msg_be = (const float*)d_in[13];
  const float* upd_w  = (const float*)d_in[14];
  const float* upd_b  = (const float*)d_in[15];
  const float* upd_g  = (const float*)d_in[16];
  const float* upd_be = (const float*)d_in[17];
  const float* nrm_g  = (const float*)d_in[18];
  const float* nrm_be = (const float*)d_in[19];
  const float* h1_w   = (const float*)d_in[20];
  const float* h1_b   = (const float*)d_in[21];
  const float* h1_g   = (const float*)d_in[22];
  const float* h1_be  = (const float*)d_in[23];
  const float* h2_w   = (const float*)d_in[24];
  const float* h2_b   = (const float*)d_in[25];
  const int*   ei     = (const int*)d_in[26];
  const int*   batch  = (const int*)d_in[27];
  float* out = (float*)d_out;

  const int N = in_sizes[0] / 16;
  const int E = in_sizes[1] / 8;
  const int G = out_size;
  const int* srcI = ei;       // edge_index[0] = src (x_j)
  const int* dstI = ei + E;   // edge_index[1] = dst (x_i)

  float* ws  = (float*)d_ws;
  float* h    = ws;
  float* hw1  = h   + (size_t)N * 64;
  float* hw2  = hw1 + (size_t)N * 64;
  float* agg  = hw2 + (size_t)N * 64;
  float* gsum = agg + (size_t)N * 64;
  float* gcnt = gsum + (size_t)G * 64;
  unsigned short* wsf = (unsigned short*)(gcnt + G);
  // fragment pool layout (shorts):
  unsigned short* W3f0   = wsf + 0;       // 4096
  unsigned short* W3f1   = wsf + 4096;    // 4096
  unsigned short* eeWf   = wsf + 8192;    // 2048
  unsigned short* updWf0 = wsf + 10240;   // 4096
  unsigned short* updWf1 = wsf + 14336;   // 4096
  unsigned short* msgWf0 = wsf + 18432;   // 8192
  unsigned short* msgWf1 = wsf + 26624;   // 8192
  unsigned short* neWf   = wsf + 34816;   // 2048  -> total 36864 shorts

  const float* W3a = msg_w + 128 * 64;
  const float* W3b = msg_w + (size_t)192 * 64 + 128 * 64;

  const size_t fixed_floats = (size_t)N * 64 * 4 + (size_t)G * 64 + G;
  const bool pre = (ws_size / 4 >= fixed_floats + 18432 + 64);

  const int nblk  = (N + 3) / 4;     // scalar node blocks
  const int nblkM = (N + 63) / 64;   // MFMA node blocks (64 rows)
  const int eblkM = (E + 63) / 64;   // MFMA edge blocks
  const int eblkF = (E + 15) / 16;   // fallback edge blocks

  if (pre) {
    k_pack_mat<<<2, 256, 0, stream>>>(W3a, W3f0, 8);
    k_pack_mat<<<2, 256, 0, stream>>>(W3b, W3f1, 8);
    k_pack_pad<<<1, 256, 0, stream>>>(ee_w, eeWf, 8);
    k_pack_mat<<<2, 256, 0, stream>>>(upd_w, updWf0, 8);
    k_pack_mat<<<2, 256, 0, stream>>>(upd_w + (size_t)64 * 64, updWf1, 8);
    k_pack_mat<<<4, 256, 0, stream>>>(msg_w, msgWf0, 16);
    k_pack_mat<<<4, 256, 0, stream>>>(msg_w + (size_t)192 * 64, msgWf1, 16);
    k_pack_pad<<<1, 256, 0, stream>>>(ne_w, neWf, 16);

    k_embed_msgw_mfma<<<nblkM, 256, 0, stream>>>(
        x, neWf, ne_b, ne_g, ne_be, msgWf0, h, hw1, hw2, agg, N);
    // layer 0
    k_edge_msg_mfma<<<eblkM, 256, 0, stream>>>(
        ea, W3f0, eeWf, ee_b, ee_g, ee_be,
        msg_b, msg_g, msg_be, hw1, hw2, srcI, dstI, agg, E);
    k_update_msgw_mfma<<<nblkM, 256, 0, stream>>>(
        h, agg, updWf0, upd_b, upd_g, upd_be, nrm_g, nrm_be,
        msgWf1, hw1, hw2, N);
    // layer 1
    k_edge_msg_mfma<<<eblkM, 256, 0, stream>>>(
        ea, W3f1, eeWf, ee_b, ee_g, ee_be,
        msg_b + 64, msg_g + 64, msg_be + 64, hw1, hw2, srcI, dstI, agg, E);
    hipMemsetAsync(gsum, 0, ((size_t)G * 64 + G) * sizeof(float), stream);
    k_update_pool_mfma<<<nblkM, 256, 0, stream>>>(
        h, agg, updWf1, upd_b + 64, upd_g + 64, upd_be + 64,
        nrm_g + 64, nrm_be + 64, batch, gsum, gcnt, N);
  } else {
    k_embed_msgw<<<nblk, 256, 0, stream>>>(
        x, ne_w, ne_b, ne_g, ne_be, msg_w, h, hw1, hw2, agg, N);
    k_edge_msg_fb<<<eblkF, 256, 0, stream>>>(
        ea, ee_w, ee_b, ee_g, ee_be, W3a, msg_b, msg_g, msg_be,
        hw1, hw2, srcI, dstI, agg, E);
    k_update_msgw<<<nblk, 256, 0, stream>>>(
        h, agg, upd_w, upd_b, upd_g, upd_be, nrm_g, nrm_be,
        msg_w + (size_t)192 * 64, hw1, hw2, N);
    k_edge_msg_fb<<<eblkF, 256, 0, stream>>>(
        ea, ee_w, ee_b, ee_g, ee_be, W3b, msg_b + 64, msg_g + 64, msg_be + 64,
        hw1, hw2, srcI, dstI, agg, E);
    hipMemsetAsync(gsum, 0, ((size_t)G * 64 + G) * sizeof(float), stream);
    k_update_pool<<<nblk, 256, 0, stream>>>(
        h, agg, upd_w + (size_t)64 * 64, upd_b + 64, upd_g + 64, upd_be + 64,
        nrm_g + 64, nrm_be + 64, batch, gsum, gcnt, N);
  }

  k_head<<<G, 64, 0, stream>>>(gsum, gcnt, h1_w, h1_b, h1_g, h1_be, h2_w, h2_b, out, G);
}

// Round 21
// 470.957 us; speedup vs baseline: 5.0388x; 1.0416x over previous
//
#include <hip/hip_runtime.h>
#include <math.h>

typedef __attribute__((ext_vector_type(8))) short short8;
typedef __attribute__((ext_vector_type(4))) float f32x4;

// ---------- helpers ----------
__device__ __forceinline__ float silu_f(float x) { return x / (1.0f + __expf(-x)); }

// f32 -> bf16 round-to-nearest-even (finite values only)
__device__ __forceinline__ unsigned short f2bf(float f) {
  unsigned int u = __float_as_uint(f);
  unsigned int r = (u + 0x7fffu + ((u >> 16) & 1u)) >> 16;
  return (unsigned short)r;
}

// LayerNorm across a 64-lane wave (scalar fallback path)
__device__ __forceinline__ float ln64(float v, float g, float b) {
  float s = v, s2 = v * v;
#pragma unroll
  for (int m = 32; m > 0; m >>= 1) {
    s  += __shfl_xor(s,  m, 64);
    s2 += __shfl_xor(s2, m, 64);
  }
  float mean = s * 0.015625f;
  float var  = fmaxf(s2 * 0.015625f - mean * mean, 0.0f);
  return (v - mean) * rsqrtf(var + 1e-5f) * g + b;
}

// dual reduce over 16-lane group
__device__ __forceinline__ void red16(float& s, float& s2) {
#pragma unroll
  for (int m = 8; m > 0; m >>= 1) {
    s  += __shfl_xor(s,  m, 64);
    s2 += __shfl_xor(s2, m, 64);
  }
}

// ---------- pack task helpers ----------
__device__ __forceinline__ void pack_mat_task(
    const float* __restrict__ src, unsigned short* __restrict__ dst, int t) {
  int f = t >> 6, l = t & 63;
  int kh = f >> 2, jt = f & 3;
  unsigned short* d = dst + (size_t)t * 8;
#pragma unroll
  for (int i = 0; i < 8; ++i)
    d[i] = f2bf(src[(kh * 32 + (l >> 4) * 8 + i) * 64 + jt * 16 + (l & 15)]);
}
__device__ __forceinline__ void pack_pad_task(
    const float* __restrict__ src, unsigned short* __restrict__ dst, int t, int Kreal) {
  int l = t & 63;
  unsigned short* d = dst + (size_t)t * 8;
#pragma unroll
  for (int i = 0; i < 8; ++i) {
    int row = (l >> 4) * 8 + i;
    d[i] = (row < Kreal) ? f2bf(src[row * 64 + (t >> 6) * 16 + (l & 15)])
                         : (unsigned short)0;
  }
}

// ---------- ONE pack kernel: all 8 fragment sets + zero gsum/gcnt ----------
__global__ __launch_bounds__(256) void k_pack_all(
    const float* __restrict__ ne_w, const float* __restrict__ ee_w,
    const float* __restrict__ msg_w, const float* __restrict__ upd_w,
    unsigned short* __restrict__ wsf, float* __restrict__ gsum, int G) {
  const float* W3a = msg_w + 128 * 64;
  const float* W3b = msg_w + (size_t)192 * 64 + 128 * 64;
  unsigned short* W3f0   = wsf + 0;
  unsigned short* W3f1   = wsf + 4096;
  unsigned short* eeWf   = wsf + 8192;
  unsigned short* updWf0 = wsf + 10240;
  unsigned short* updWf1 = wsf + 14336;
  unsigned short* msgWf0 = wsf + 18432;
  unsigned short* msgWf1 = wsf + 26624;
  unsigned short* neWf   = wsf + 34816;

  int t = blockIdx.x * 256 + threadIdx.x;
  if (t < 512)        pack_mat_task(W3a, W3f0, t);
  else if (t < 1024)  pack_mat_task(W3b, W3f1, t - 512);
  else if (t < 1280)  pack_pad_task(ee_w, eeWf, t - 1024, 8);
  else if (t < 1792)  pack_mat_task(upd_w, updWf0, t - 1280);
  else if (t < 2304)  pack_mat_task(upd_w + (size_t)64 * 64, updWf1, t - 1792);
  else if (t < 3328)  pack_mat_task(msg_w, msgWf0, t - 2304);
  else if (t < 4352)  pack_mat_task(msg_w + (size_t)192 * 64, msgWf1, t - 3328);
  else if (t < 4608)  pack_pad_task(ne_w, neWf, t - 4352, 16);
  else {
    int base = (t - 4608) * 4;              // zero gsum[G*64] + gcnt[G]
    int nz = G * 64 + G;
    if (base < nz) {
      if (nz - base >= 4) {
        *(float4*)&gsum[base] = make_float4(0.f, 0.f, 0.f, 0.f);
      } else {
        for (int i = base; i < nz; ++i) gsum[i] = 0.f;
      }
    }
  }
}

// ---------- MFMA node embed: h = silu(LN(x@neW+b)); hw1/hw2(l0); agg=0 ----------
__global__ __launch_bounds__(256) void k_embed_msgw_mfma(
    const float* __restrict__ x,
    const unsigned short* __restrict__ neWf,   // 4 frags (K 16->32 padded)
    const float* __restrict__ neB, const float* __restrict__ neG,
    const float* __restrict__ neBe,
    const unsigned short* __restrict__ msgWf,  // 16 frags (rows 0..127)
    float* __restrict__ h, float* __restrict__ hw1, float* __restrict__ hw2,
    float* __restrict__ agg, int n) {
  __shared__ __align__(16) unsigned short sEB[4][16][72];
  const int wv = threadIdx.x >> 6;
  const int l  = threadIdx.x & 63;
  const int rbase = (blockIdx.x * 4 + wv) * 16;
  if (rbase >= n) return;
  const int lo = l & 15, hi = l >> 4;

  short8 ax = {0, 0, 0, 0, 0, 0, 0, 0};
  if (hi < 2) {
    const float* xr = x + (size_t)min(rbase + lo, n - 1) * 16 + hi * 8;
    float4 p0 = *(const float4*)xr;
    float4 p1 = *(const float4*)(xr + 4);
    ax[0] = (short)f2bf(p0.x); ax[1] = (short)f2bf(p0.y);
    ax[2] = (short)f2bf(p0.z); ax[3] = (short)f2bf(p0.w);
    ax[4] = (short)f2bf(p1.x); ax[5] = (short)f2bf(p1.y);
    ax[6] = (short)f2bf(p1.z); ax[7] = (short)f2bf(p1.w);
  }
  f32x4 acc[4];
#pragma unroll
  for (int jt = 0; jt < 4; ++jt) {
    short8 b = *(const short8*)(neWf + (size_t)(jt * 64 + l) * 8);
    f32x4 c = {0.f, 0.f, 0.f, 0.f};
    acc[jt] = __builtin_amdgcn_mfma_f32_16x16x32_bf16(ax, b, c, 0, 0, 0);
  }
  float nb[4], ngv[4], nbev[4];
#pragma unroll
  for (int jt = 0; jt < 4; ++jt) {
    nb[jt] = neB[jt * 16 + lo]; ngv[jt] = neG[jt * 16 + lo]; nbev[jt] = neBe[jt * 16 + lo];
  }
#pragma unroll
  for (int r = 0; r < 4; ++r) {
    int row = rbase + hi * 4 + r;
    float v[4]; float s = 0.f, s2 = 0.f;
#pragma unroll
    for (int jt = 0; jt < 4; ++jt) { float t = acc[jt][r] + nb[jt]; v[jt] = t; s += t; s2 += t * t; }
    red16(s, s2);
    float mean = s * 0.015625f;
    float var  = fmaxf(s2 * 0.015625f - mean * mean, 0.f);
    float rsq  = rsqrtf(var + 1e-5f);
#pragma unroll
    for (int jt = 0; jt < 4; ++jt) {
      float hv = silu_f((v[jt] - mean) * rsq * ngv[jt] + nbev[jt]);
      if (row < n) {
        h[(size_t)row * 64 + jt * 16 + lo] = hv;
        agg[(size_t)row * 64 + jt * 16 + lo] = 0.0f;
      }
      sEB[wv][hi * 4 + r][jt * 16 + lo] = f2bf(hv);   // same-wave ordered
    }
  }
  // phase 2: hw1 = h@msgW rows0..63 (kh 0,1); hw2 = rows64..127 (kh 2,3)
  const unsigned short* rowp = &sEB[wv][lo][0];
  short8 a0 = *(const short8*)(rowp + hi * 8);
  short8 a1 = *(const short8*)(rowp + 32 + hi * 8);
  f32x4 c1[4], c2[4];
#pragma unroll
  for (int jt = 0; jt < 4; ++jt) {
    f32x4 z = {0.f, 0.f, 0.f, 0.f};
    f32x4 t1 = __builtin_amdgcn_mfma_f32_16x16x32_bf16(
        a0, *(const short8*)(msgWf + (size_t)((0 * 4 + jt) * 64 + l) * 8), z, 0, 0, 0);
    t1 = __builtin_amdgcn_mfma_f32_16x16x32_bf16(
        a1, *(const short8*)(msgWf + (size_t)((1 * 4 + jt) * 64 + l) * 8), t1, 0, 0, 0);
    c1[jt] = t1;
    f32x4 t2 = __builtin_amdgcn_mfma_f32_16x16x32_bf16(
        a0, *(const short8*)(msgWf + (size_t)((2 * 4 + jt) * 64 + l) * 8), z, 0, 0, 0);
    t2 = __builtin_amdgcn_mfma_f32_16x16x32_bf16(
        a1, *(const short8*)(msgWf + (size_t)((3 * 4 + jt) * 64 + l) * 8), t2, 0, 0, 0);
    c2[jt] = t2;
  }
#pragma unroll
  for (int r = 0; r < 4; ++r) {
    int row = rbase + hi * 4 + r;
    if (row < n) {
#pragma unroll
      for (int jt = 0; jt < 4; ++jt) {
        hw1[(size_t)row * 64 + jt * 16 + lo] = c1[jt][r];
        hw2[(size_t)row * 64 + jt * 16 + lo] = c2[jt][r];
      }
    }
  }
}

// ---------- MFMA update (+msgw next layer): in-place h, agg read+zero ----------
__global__ __launch_bounds__(256) void k_update_msgw_mfma(
    float* h, float* agg,
    const unsigned short* __restrict__ updWf,  // 8 frags
    const float* __restrict__ ub, const float* __restrict__ ug,
    const float* __restrict__ ube, const float* __restrict__ ng,
    const float* __restrict__ nbe,
    const unsigned short* __restrict__ msgWfN, // 16 frags, next layer
    float* __restrict__ hw1, float* __restrict__ hw2, int n) {
  __shared__ __align__(16) unsigned short sEB[4][16][72];
  const int wv = threadIdx.x >> 6;
  const int l  = threadIdx.x & 63;
  const int rbase = (blockIdx.x * 4 + wv) * 16;
  if (rbase >= n) return;
  const int lo = l & 15, hi = l >> 4;

  const int crow = min(rbase + lo, n - 1);
  const float* hrA = h + (size_t)crow * 64;
  const float* arA = agg + (size_t)crow * 64;
  short8 au0, au1;
  {
    float4 p0 = *(const float4*)(hrA + hi * 8);
    float4 p1 = *(const float4*)(hrA + hi * 8 + 4);
    float4 q0 = *(const float4*)(arA + hi * 8);
    float4 q1 = *(const float4*)(arA + hi * 8 + 4);
    au0[0] = (short)f2bf(p0.x + q0.x); au0[1] = (short)f2bf(p0.y + q0.y);
    au0[2] = (short)f2bf(p0.z + q0.z); au0[3] = (short)f2bf(p0.w + q0.w);
    au0[4] = (short)f2bf(p1.x + q1.x); au0[5] = (short)f2bf(p1.y + q1.y);
    au0[6] = (short)f2bf(p1.z + q1.z); au0[7] = (short)f2bf(p1.w + q1.w);
    float4 r0 = *(const float4*)(hrA + 32 + hi * 8);
    float4 r1 = *(const float4*)(hrA + 32 + hi * 8 + 4);
    float4 s0 = *(const float4*)(arA + 32 + hi * 8);
    float4 s1 = *(const float4*)(arA + 32 + hi * 8 + 4);
    au1[0] = (short)f2bf(r0.x + s0.x); au1[1] = (short)f2bf(r0.y + s0.y);
    au1[2] = (short)f2bf(r0.z + s0.z); au1[3] = (short)f2bf(r0.w + s0.w);
    au1[4] = (short)f2bf(r1.x + s1.x); au1[5] = (short)f2bf(r1.y + s1.y);
    au1[6] = (short)f2bf(r1.z + s1.z); au1[7] = (short)f2bf(r1.w + s1.w);
  }
  float hres[4][4];
#pragma unroll
  for (int r = 0; r < 4; ++r) {
    int row = min(rbase + hi * 4 + r, n - 1);
#pragma unroll
    for (int jt = 0; jt < 4; ++jt)
      hres[r][jt] = h[(size_t)row * 64 + jt * 16 + lo];
  }

  f32x4 acc[4];
#pragma unroll
  for (int jt = 0; jt < 4; ++jt) {
    f32x4 z = {0.f, 0.f, 0.f, 0.f};
    f32x4 c = __builtin_amdgcn_mfma_f32_16x16x32_bf16(
        au0, *(const short8*)(updWf + (size_t)((0 * 4 + jt) * 64 + l) * 8), z, 0, 0, 0);
    c = __builtin_amdgcn_mfma_f32_16x16x32_bf16(
        au1, *(const short8*)(updWf + (size_t)((1 * 4 + jt) * 64 + l) * 8), c, 0, 0, 0);
    acc[jt] = c;
  }

  float ubv[4], ugv[4], ubev[4], ngv[4], nbev[4];
#pragma unroll
  for (int jt = 0; jt < 4; ++jt) {
    ubv[jt] = ub[jt * 16 + lo]; ugv[jt] = ug[jt * 16 + lo]; ubev[jt] = ube[jt * 16 + lo];
    ngv[jt] = ng[jt * 16 + lo]; nbev[jt] = nbe[jt * 16 + lo];
  }

#pragma unroll
  for (int r = 0; r < 4; ++r) {
    int row = rbase + hi * 4 + r;
    float v[4]; float s = 0.f, s2 = 0.f;
#pragma unroll
    for (int jt = 0; jt < 4; ++jt) {
      float t = silu_f(acc[jt][r] + ubv[jt]);
      v[jt] = t; s += t; s2 += t * t;
    }
    red16(s, s2);
    float mean = s * 0.015625f;
    float var  = fmaxf(s2 * 0.015625f - mean * mean, 0.f);
    float rsq  = rsqrtf(var + 1e-5f);
    float w[4]; float ws_ = 0.f, ws2 = 0.f;
#pragma unroll
    for (int jt = 0; jt < 4; ++jt) {
      float u = (v[jt] - mean) * rsq * ugv[jt] + ubev[jt];
      float t = u + hres[r][jt];
      w[jt] = t; ws_ += t; ws2 += t * t;
    }
    red16(ws_, ws2);
    float mean2 = ws_ * 0.015625f;
    float var2  = fmaxf(ws2 * 0.015625f - mean2 * mean2, 0.f);
    float rsq2  = rsqrtf(var2 + 1e-5f);
#pragma unroll
    for (int jt = 0; jt < 4; ++jt) {
      float hn = (w[jt] - mean2) * rsq2 * ngv[jt] + nbev[jt];
      if (row < n) {
        h[(size_t)row * 64 + jt * 16 + lo] = hn;
        agg[(size_t)row * 64 + jt * 16 + lo] = 0.0f;
      }
      sEB[wv][hi * 4 + r][jt * 16 + lo] = f2bf(hn);
    }
  }

  // phase 2: hw1/hw2 for next layer
  const unsigned short* rowp = &sEB[wv][lo][0];
  short8 a0 = *(const short8*)(rowp + hi * 8);
  short8 a1 = *(const short8*)(rowp + 32 + hi * 8);
  f32x4 c1[4], c2[4];
#pragma unroll
  for (int jt = 0; jt < 4; ++jt) {
    f32x4 z = {0.f, 0.f, 0.f, 0.f};
    f32x4 t1 = __builtin_amdgcn_mfma_f32_16x16x32_bf16(
        a0, *(const short8*)(msgWfN + (size_t)((0 * 4 + jt) * 64 + l) * 8), z, 0, 0, 0);
    t1 = __builtin_amdgcn_mfma_f32_16x16x32_bf16(
        a1, *(const short8*)(msgWfN + (size_t)((1 * 4 + jt) * 64 + l) * 8), t1, 0, 0, 0);
    c1[jt] = t1;
    f32x4 t2 = __builtin_amdgcn_mfma_f32_16x16x32_bf16(
        a0, *(const short8*)(msgWfN + (size_t)((2 * 4 + jt) * 64 + l) * 8), z, 0, 0, 0);
    t2 = __builtin_amdgcn_mfma_f32_16x16x32_bf16(
        a1, *(const short8*)(msgWfN + (size_t)((3 * 4 + jt) * 64 + l) * 8), t2, 0, 0, 0);
    c2[jt] = t2;
  }
#pragma unroll
  for (int r = 0; r < 4; ++r) {
    int row = rbase + hi * 4 + r;
    if (row < n) {
#pragma unroll
      for (int jt = 0; jt < 4; ++jt) {
        hw1[(size_t)row * 64 + jt * 16 + lo] = c1[jt][r];
        hw2[(size_t)row * 64 + jt * 16 + lo] = c2[jt][r];
      }
    }
  }
}

// ---------- MFMA final update + pool atomics ----------
__global__ __launch_bounds__(256) void k_update_pool_mfma(
    float* h, float* agg,
    const unsigned short* __restrict__ updWf,
    const float* __restrict__ ub, const float* __restrict__ ug,
    const float* __restrict__ ube, const float* __restrict__ ng,
    const float* __restrict__ nbe,
    const int* __restrict__ batch, float* __restrict__ gsum,
    float* __restrict__ gcnt, int n) {
  const int wv = threadIdx.x >> 6;
  const int l  = threadIdx.x & 63;
  const int rbase = (blockIdx.x * 4 + wv) * 16;
  if (rbase >= n) return;
  const int lo = l & 15, hi = l >> 4;

  const int crow = min(rbase + lo, n - 1);
  const float* hrA = h + (size_t)crow * 64;
  const float* arA = agg + (size_t)crow * 64;
  short8 au0, au1;
  {
    float4 p0 = *(const float4*)(hrA + hi * 8);
    float4 p1 = *(const float4*)(hrA + hi * 8 + 4);
    float4 q0 = *(const float4*)(arA + hi * 8);
    float4 q1 = *(const float4*)(arA + hi * 8 + 4);
    au0[0] = (short)f2bf(p0.x + q0.x); au0[1] = (short)f2bf(p0.y + q0.y);
    au0[2] = (short)f2bf(p0.z + q0.z); au0[3] = (short)f2bf(p0.w + q0.w);
    au0[4] = (short)f2bf(p1.x + q1.x); au0[5] = (short)f2bf(p1.y + q1.y);
    au0[6] = (short)f2bf(p1.z + q1.z); au0[7] = (short)f2bf(p1.w + q1.w);
    float4 r0 = *(const float4*)(hrA + 32 + hi * 8);
    float4 r1 = *(const float4*)(hrA + 32 + hi * 8 + 4);
    float4 s0 = *(const float4*)(arA + 32 + hi * 8);
    float4 s1 = *(const float4*)(arA + 32 + hi * 8 + 4);
    au1[0] = (short)f2bf(r0.x + s0.x); au1[1] = (short)f2bf(r0.y + s0.y);
    au1[2] = (short)f2bf(r0.z + s0.z); au1[3] = (short)f2bf(r0.w + s0.w);
    au1[4] = (short)f2bf(r1.x + s1.x); au1[5] = (short)f2bf(r1.y + s1.y);
    au1[6] = (short)f2bf(r1.z + s1.z); au1[7] = (short)f2bf(r1.w + s1.w);
  }
  float hres[4][4];
  int bb[4];
#pragma unroll
  for (int r = 0; r < 4; ++r) {
    int row = min(rbase + hi * 4 + r, n - 1);
    bb[r] = batch[row];
#pragma unroll
    for (int jt = 0; jt < 4; ++jt)
      hres[r][jt] = h[(size_t)row * 64 + jt * 16 + lo];
  }

  f32x4 acc[4];
#pragma unroll
  for (int jt = 0; jt < 4; ++jt) {
    f32x4 z = {0.f, 0.f, 0.f, 0.f};
    f32x4 c = __builtin_amdgcn_mfma_f32_16x16x32_bf16(
        au0, *(const short8*)(updWf + (size_t)((0 * 4 + jt) * 64 + l) * 8), z, 0, 0, 0);
    c = __builtin_amdgcn_mfma_f32_16x16x32_bf16(
        au1, *(const short8*)(updWf + (size_t)((1 * 4 + jt) * 64 + l) * 8), c, 0, 0, 0);
    acc[jt] = c;
  }

  float ubv[4], ugv[4], ubev[4], ngv[4], nbev[4];
#pragma unroll
  for (int jt = 0; jt < 4; ++jt) {
    ubv[jt] = ub[jt * 16 + lo]; ugv[jt] = ug[jt * 16 + lo]; ubev[jt] = ube[jt * 16 + lo];
    ngv[jt] = ng[jt * 16 + lo]; nbev[jt] = nbe[jt * 16 + lo];
  }

#pragma unroll
  for (int r = 0; r < 4; ++r) {
    int row = rbase + hi * 4 + r;
    float v[4]; float s = 0.f, s2 = 0.f;
#pragma unroll
    for (int jt = 0; jt < 4; ++jt) {
      float t = silu_f(acc[jt][r] + ubv[jt]);
      v[jt] = t; s += t; s2 += t * t;
    }
    red16(s, s2);
    float mean = s * 0.015625f;
    float var  = fmaxf(s2 * 0.015625f - mean * mean, 0.f);
    float rsq  = rsqrtf(var + 1e-5f);
    float w[4]; float ws_ = 0.f, ws2 = 0.f;
#pragma unroll
    for (int jt = 0; jt < 4; ++jt) {
      float u = (v[jt] - mean) * rsq * ugv[jt] + ubev[jt];
      float t = u + hres[r][jt];
      w[jt] = t; ws_ += t; ws2 += t * t;
    }
    red16(ws_, ws2);
    float mean2 = ws_ * 0.015625f;
    float var2  = fmaxf(ws2 * 0.015625f - mean2 * mean2, 0.f);
    float rsq2  = rsqrtf(var2 + 1e-5f);
    if (row < n) {
#pragma unroll
      for (int jt = 0; jt < 4; ++jt) {
        float hn = (w[jt] - mean2) * rsq2 * ngv[jt] + nbev[jt];
        unsafeAtomicAdd(&gsum[(size_t)bb[r] * 64 + jt * 16 + lo], hn);
      }
      if (lo == 0) unsafeAtomicAdd(&gcnt[bb[r]], 1.0f);
    }
  }
}

// ---------- edge message, FULLY FUSED via MFMA (r19/r20 proven) ----------
__global__ __launch_bounds__(256) void k_edge_msg_mfma(
    const float* __restrict__ ea,
    const unsigned short* __restrict__ w3l,
    const unsigned short* __restrict__ eewf,
    const float* __restrict__ eeB, const float* __restrict__ eeG,
    const float* __restrict__ eeBe,
    const float* __restrict__ msgB, const float* __restrict__ msgG,
    const float* __restrict__ msgBe,
    const float* __restrict__ hw1, const float* __restrict__ hw2,
    const int* __restrict__ srcI, const int* __restrict__ dstI,
    float* __restrict__ agg, int nedges) {
  __shared__ __align__(16) unsigned short sEB[4][16][72];

  const int wv = threadIdx.x >> 6;
  const int l  = threadIdx.x & 63;
  const int ebase = (blockIdx.x * 4 + wv) * 16;
  if (ebase >= nedges) return;
  const int lo = l & 15, hi = l >> 4;

  short8 ae = {0, 0, 0, 0, 0, 0, 0, 0};
  if (hi == 0) {
    const float* ar = ea + (size_t)min(ebase + lo, nedges - 1) * 8;
    float4 p0 = *(const float4*)ar;
    float4 p1 = *(const float4*)(ar + 4);
    ae[0] = (short)f2bf(p0.x); ae[1] = (short)f2bf(p0.y);
    ae[2] = (short)f2bf(p0.z); ae[3] = (short)f2bf(p0.w);
    ae[4] = (short)f2bf(p1.x); ae[5] = (short)f2bf(p1.y);
    ae[6] = (short)f2bf(p1.z); ae[7] = (short)f2bf(p1.w);
  }
  f32x4 acc_e[4];
#pragma unroll
  for (int jt = 0; jt < 4; ++jt) {
    short8 be = *(const short8*)(eewf + (size_t)(jt * 64 + l) * 8);
    f32x4 c = {0.f, 0.f, 0.f, 0.f};
    acc_e[jt] = __builtin_amdgcn_mfma_f32_16x16x32_bf16(ae, be, c, 0, 0, 0);
  }
  {
    float ebv[4], egv[4], ebev[4];
#pragma unroll
    for (int jt = 0; jt < 4; ++jt) {
      ebv[jt]  = eeB[jt * 16 + lo];
      egv[jt]  = eeG[jt * 16 + lo];
      ebev[jt] = eeBe[jt * 16 + lo];
    }
#pragma unroll
    for (int r = 0; r < 4; ++r) {
      float v[4];
      float s = 0.f, s2 = 0.f;
#pragma unroll
      for (int jt = 0; jt < 4; ++jt) {
        float t = acc_e[jt][r] + ebv[jt];
        v[jt] = t; s += t; s2 += t * t;
      }
      red16(s, s2);
      float mean = s * 0.015625f;
      float var  = fmaxf(s2 * 0.015625f - mean * mean, 0.f);
      float rsq  = rsqrtf(var + 1e-5f);
#pragma unroll
      for (int jt = 0; jt < 4; ++jt) {
        float ev = silu_f((v[jt] - mean) * rsq * egv[jt] + ebev[jt]);
        sEB[wv][hi * 4 + r][jt * 16 + lo] = f2bf(ev);
      }
    }
  }

  int dIdx[4];
  float g1[4][4], g2[4][4];
#pragma unroll
  for (int r = 0; r < 4; ++r) {
    int ce = min(ebase + hi * 4 + r, nedges - 1);
    int s = srcI[ce];
    dIdx[r] = dstI[ce];
#pragma unroll
    for (int jt = 0; jt < 4; ++jt) {
      g1[r][jt] = hw1[(size_t)dIdx[r] * 64 + jt * 16 + lo];
      g2[r][jt] = hw2[(size_t)s * 64 + jt * 16 + lo];
    }
  }

  const unsigned short* rowp = &sEB[wv][lo][0];
  short8 a0 = *(const short8*)(rowp + hi * 8);
  short8 a1 = *(const short8*)(rowp + 32 + hi * 8);

  f32x4 acc[4];
#pragma unroll
  for (int jt = 0; jt < 4; ++jt) {
    short8 b0 = *(const short8*)(w3l + ((size_t)(0 * 4 + jt) * 64 + l) * 8);
    short8 b1 = *(const short8*)(w3l + ((size_t)(1 * 4 + jt) * 64 + l) * 8);
    f32x4 c = {0.f, 0.f, 0.f, 0.f};
    c = __builtin_amdgcn_mfma_f32_16x16x32_bf16(a0, b0, c, 0, 0, 0);
    c = __builtin_amdgcn_mfma_f32_16x16x32_bf16(a1, b1, c, 0, 0, 0);
    acc[jt] = c;
  }

  float mB[4], mG[4], mBe[4];
#pragma unroll
  for (int jt = 0; jt < 4; ++jt) {
    mB[jt]  = msgB[jt * 16 + lo];
    mG[jt]  = msgG[jt * 16 + lo];
    mBe[jt] = msgBe[jt * 16 + lo];
  }

#pragma unroll
  for (int r = 0; r < 4; ++r) {
    float mp[4];
    float s = 0.0f, s2 = 0.0f;
#pragma unroll
    for (int jt = 0; jt < 4; ++jt) {
      float v = acc[jt][r] + g1[r][jt] + g2[r][jt] + mB[jt];
      v = silu_f(v);
      mp[jt] = v;
      s += v;
      s2 += v * v;
    }
    red16(s, s2);
    float mean = s * 0.015625f;
    float var  = fmaxf(s2 * 0.015625f - mean * mean, 0.0f);
    float rsq  = rsqrtf(var + 1e-5f);
    if (ebase + hi * 4 + r < nedges) {
#pragma unroll
      for (int jt = 0; jt < 4; ++jt) {
        float m2 = (mp[jt] - mean) * rsq * mG[jt] + mBe[jt];
        unsafeAtomicAdd(&agg[(size_t)dIdx[r] * 64 + jt * 16 + lo], m2);
      }
    }
  }
}

// ================== scalar fallback path (ws too small) ==================
__global__ __launch_bounds__(256) void k_embed_msgw(
    const float* __restrict__ x, const float* __restrict__ neW,
    const float* __restrict__ neB, const float* __restrict__ neG,
    const float* __restrict__ neBe, const float* __restrict__ W,
    float* __restrict__ h, float* __restrict__ hw1, float* __restrict__ hw2,
    float* __restrict__ agg, int n) {
  __shared__ float sRow[4][64];
  const int row = (blockIdx.x * 256 + threadIdx.x) >> 6;
  const int wv = threadIdx.x >> 6;
  const int j  = threadIdx.x & 63;
  if (row >= n) return;

  const float* xr = x + (size_t)row * 16;
  float acc = neB[j];
#pragma unroll
  for (int k = 0; k < 16; k += 4) {
    float4 xv = *(const float4*)&xr[k];
    acc += xv.x * neW[(k + 0) * 64 + j] + xv.y * neW[(k + 1) * 64 + j] +
           xv.z * neW[(k + 2) * 64 + j] + xv.w * neW[(k + 3) * 64 + j];
  }
  float hv = silu_f(ln64(acc, neG[j], neBe[j]));
  h[(size_t)row * 64 + j] = hv;
  agg[(size_t)row * 64 + j] = 0.0f;
  sRow[wv][j] = hv;

  float a1 = 0.0f, a2 = 0.0f;
#pragma unroll
  for (int k = 0; k < 64; k += 4) {
    float4 r = *(const float4*)&sRow[wv][k];
    a1 += r.x * W[(k + 0) * 64 + j] + r.y * W[(k + 1) * 64 + j] +
          r.z * W[(k + 2) * 64 + j] + r.w * W[(k + 3) * 64 + j];
    a2 += r.x * W[(64 + k + 0) * 64 + j] + r.y * W[(64 + k + 1) * 64 + j] +
          r.z * W[(64 + k + 2) * 64 + j] + r.w * W[(64 + k + 3) * 64 + j];
  }
  hw1[(size_t)row * 64 + j] = a1;
  hw2[(size_t)row * 64 + j] = a2;
}

#define EPW 4
__global__ __launch_bounds__(256) void k_edge_msg_fb(
    const float* __restrict__ ea, const float* __restrict__ eeW,
    const float* __restrict__ eeB, const float* __restrict__ eeG,
    const float* __restrict__ eeBe,
    const float* __restrict__ W3, const float* __restrict__ msgB,
    const float* __restrict__ msgG, const float* __restrict__ msgBe,
    const float* __restrict__ hw1, const float* __restrict__ hw2,
    const int* __restrict__ srcI, const int* __restrict__ dstI,
    float* __restrict__ agg, int nedges) {
  __shared__ float sE[4][EPW][64];
  __shared__ float sEA[4][EPW * 8];

  const int wv = threadIdx.x >> 6;
  const int j  = threadIdx.x & 63;
  const int ebase = (blockIdx.x * 4 + wv) * EPW;
  if (ebase >= nedges) return;

  if (j < 32) {
    long long gi = (long long)ebase * 8 + j;
    long long gmax = (long long)nedges * 8 - 1;
    if (gi > gmax) gi = gmax;
    sEA[wv][j] = ea[gi];
  }

  const float bj = msgB[j];
  int dIdx[EPW];
  float acc[EPW];
#pragma unroll
  for (int e = 0; e < EPW; ++e) {
    int ce = min(ebase + e, nedges - 1);
    int s = srcI[ce];
    dIdx[e] = dstI[ce];
    acc[e] = hw1[(size_t)dIdx[e] * 64 + j] + hw2[(size_t)s * 64 + j] + bj;
  }
  {
    float ewc[8];
#pragma unroll
    for (int k = 0; k < 8; ++k) ewc[k] = eeW[k * 64 + j];
    const float eb = eeB[j], eg = eeG[j], ebe = eeBe[j];
#pragma unroll
    for (int e = 0; e < EPW; ++e) {
      const float* ar = &sEA[wv][e * 8];
      float ev = eb;
#pragma unroll
      for (int k = 0; k < 8; ++k) ev += ar[k] * ewc[k];
      ev = silu_f(ln64(ev, eg, ebe));
      sE[wv][e][j] = ev;
    }
  }
#pragma unroll
  for (int k = 0; k < 64; k += 4) {
    float w0 = W3[(k + 0) * 64 + j];
    float w1 = W3[(k + 1) * 64 + j];
    float w2 = W3[(k + 2) * 64 + j];
    float w3 = W3[(k + 3) * 64 + j];
#pragma unroll
    for (int e = 0; e < EPW; ++e) {
      float4 ev4 = *(const float4*)&sE[wv][e][k];
      acc[e] += ev4.x * w0 + ev4.y * w1 + ev4.z * w2 + ev4.w * w3;
    }
  }
  const float mg = msgG[j], mbe = msgBe[j];
#pragma unroll
  for (int e = 0; e < EPW; ++e) {
    float m = ln64(silu_f(acc[e]), mg, mbe);
    if (ebase + e < nedges) unsafeAtomicAdd(&agg[(size_t)dIdx[e] * 64 + j], m);
  }
}

__global__ __launch_bounds__(256) void k_update_msgw(
    float* h, float* agg,
    const float* __restrict__ W, const float* __restrict__ b,
    const float* __restrict__ ug, const float* __restrict__ ube,
    const float* __restrict__ ng, const float* __restrict__ nbe,
    const float* __restrict__ Wn,
    float* __restrict__ hw1, float* __restrict__ hw2, int n) {
  __shared__ float sRow[4][64];
  const int row = (blockIdx.x * 256 + threadIdx.x) >> 6;
  const int wv = threadIdx.x >> 6;
  const int j  = threadIdx.x & 63;
  if (row >= n) return;

  float* hr = h + (size_t)row * 64;
  float* ar = agg + (size_t)row * 64;
  float acc = b[j];
  float hj = hr[j];
#pragma unroll
  for (int k = 0; k < 64; k += 4) {
    float4 hv = *(const float4*)&hr[k];
    float4 av = *(const float4*)&ar[k];
    acc += (hv.x + av.x) * W[(k + 0) * 64 + j] + (hv.y + av.y) * W[(k + 1) * 64 + j] +
           (hv.z + av.z) * W[(k + 2) * 64 + j] + (hv.w + av.w) * W[(k + 3) * 64 + j];
  }
  float u = ln64(silu_f(acc), ug[j], ube[j]);
  float hn = ln64(u + hj, ng[j], nbe[j]);
  hr[j] = hn;
  ar[j] = 0.0f;
  sRow[wv][j] = hn;

  float a1 = 0.0f, a2 = 0.0f;
#pragma unroll
  for (int k = 0; k < 64; k += 4) {
    float4 r = *(const float4*)&sRow[wv][k];
    a1 += r.x * Wn[(k + 0) * 64 + j] + r.y * Wn[(k + 1) * 64 + j] +
          r.z * Wn[(k + 2) * 64 + j] + r.w * Wn[(k + 3) * 64 + j];
    a2 += r.x * Wn[(64 + k + 0) * 64 + j] + r.y * Wn[(64 + k + 1) * 64 + j] +
          r.z * Wn[(64 + k + 2) * 64 + j] + r.w * Wn[(64 + k + 3) * 64 + j];
  }
  hw1[(size_t)row * 64 + j] = a1;
  hw2[(size_t)row * 64 + j] = a2;
}

__global__ __launch_bounds__(256) void k_update_pool(
    float* h, const float* __restrict__ agg,
    const float* __restrict__ W, const float* __restrict__ b,
    const float* __restrict__ ug, const float* __restrict__ ube,
    const float* __restrict__ ng, const float* __restrict__ nbe,
    const int* __restrict__ batch, float* __restrict__ gsum,
    float* __restrict__ gcnt, int n) {
  const int row = (blockIdx.x * 256 + threadIdx.x) >> 6;
  const int j  = threadIdx.x & 63;
  if (row >= n) return;

  float* hr = h + (size_t)row * 64;
  const float* ar = agg + (size_t)row * 64;
  float acc = b[j];
  float hj = hr[j];
#pragma unroll
  for (int k = 0; k < 64; k += 4) {
    float4 hv = *(const float4*)&hr[k];
    float4 av = *(const float4*)&ar[k];
    acc += (hv.x + av.x) * W[(k + 0) * 64 + j] + (hv.y + av.y) * W[(k + 1) * 64 + j] +
           (hv.z + av.z) * W[(k + 2) * 64 + j] + (hv.w + av.w) * W[(k + 3) * 64 + j];
  }
  float u = ln64(silu_f(acc), ug[j], ube[j]);
  float hn = ln64(u + hj, ng[j], nbe[j]);

  int bb = batch[row];
  unsafeAtomicAdd(&gsum[(size_t)bb * 64 + j], hn);
  if (j == 0) unsafeAtomicAdd(&gcnt[bb], 1.0f);
}

// ---------- head ----------
__global__ __launch_bounds__(64) void k_head(
    const float* __restrict__ gsum, const float* __restrict__ gcnt,
    const float* __restrict__ w1, const float* __restrict__ b1,
    const float* __restrict__ g1, const float* __restrict__ be1,
    const float* __restrict__ w2, const float* __restrict__ b2,
    float* __restrict__ out, int ngraphs) {
  int gidx = blockIdx.x;
  int j = threadIdx.x;
  if (gidx >= ngraphs) return;
  __shared__ float sg[64];
  float cnt = fmaxf(gcnt[gidx], 1.0f);
  sg[j] = gsum[(size_t)gidx * 64 + j] / cnt;
  float acc = 0.0f;
  if (j < 32) {
    acc = b1[j];
#pragma unroll 8
    for (int k = 0; k < 64; ++k) acc += sg[k] * w1[k * 32 + j];
  }
  float s = acc, s2 = acc * acc;
#pragma unroll
  for (int m = 16; m > 0; m >>= 1) {
    s  += __shfl_xor(s,  m, 64);
    s2 += __shfl_xor(s2, m, 64);
  }
  float mean = s * 0.03125f;
  float var  = fmaxf(s2 * 0.03125f - mean * mean, 0.0f);
  float z = 0.0f;
  if (j < 32) {
    float nv = (acc - mean) * rsqrtf(var + 1e-5f) * g1[j] + be1[j];
    z = silu_f(nv) * w2[j];
  }
#pragma unroll
  for (int m = 32; m > 0; m >>= 1) z += __shfl_xor(z, m, 64);
  if (j == 0) out[gidx] = z + b2[0];
}

// ---------- launch ----------
extern "C" void kernel_launch(void* const* d_in, const int* in_sizes, int n_in,
                              void* d_out, int out_size, void* d_ws, size_t ws_size,
                              hipStream_t stream) {
  const float* x      = (const float*)d_in[0];
  const float* ea     = (const float*)d_in[1];
  const float* ne_w   = (const float*)d_in[2];
  const float* ne_b   = (const float*)d_in[3];
  const float* ne_g   = (const float*)d_in[4];
  const float* ne_be  = (const float*)d_in[5];
  const float* ee_w   = (const float*)d_in[6];
  const float* ee_b   = (const float*)d_in[7];
  const float* ee_g   = (const float*)d_in[8];
  const float* ee_be  = (const float*)d_in[9];
  const float* msg_w  = (const float*)d_in[10];
  const float* msg_b  = (const float*)d_in[11];
  const float* msg_g  = (const float*)d_in[12];
  const float* msg_be = (const float*)d_in[13];
  const float* upd_w  = (const float*)d_in[14];
  const float* upd_b  = (const float*)d_in[15];
  const float* upd_g  = (const float*)d_in[16];
  const float* upd_be = (const float*)d_in[17];
  const float* nrm_g  = (const float*)d_in[18];
  const float* nrm_be = (const float*)d_in[19];
  const float* h1_w   = (const float*)d_in[20];
  const float* h1_b   = (const float*)d_in[21];
  const float* h1_g   = (const float*)d_in[22];
  const float* h1_be  = (const float*)d_in[23];
  const float* h2_w   = (const float*)d_in[24];
  const float* h2_b   = (const float*)d_in[25];
  const int*   ei     = (const int*)d_in[26];
  const int*   batch  = (const int*)d_in[27];
  float* out = (float*)d_out;

  const int N = in_sizes[0] / 16;
  const int E = in_sizes[1] / 8;
  const int G = out_size;
  const int* srcI = ei;       // edge_index[0] = src (x_j)
  const int* dstI = ei + E;   // edge_index[1] = dst (x_i)

  float* ws  = (float*)d_ws;
  float* h    = ws;
  float* hw1  = h   + (size_t)N * 64;
  float* hw2  = hw1 + (size_t)N * 64;
  float* agg  = hw2 + (size_t)N * 64;
  float* gsum = agg + (size_t)N * 64;
  float* gcnt = gsum + (size_t)G * 64;
  unsigned short* wsf = (unsigned short*)(gcnt + G);
  unsigned short* W3f0   = wsf + 0;       // 4096
  unsigned short* W3f1   = wsf + 4096;    // 4096
  unsigned short* eeWf   = wsf + 8192;    // 2048
  unsigned short* updWf0 = wsf + 10240;   // 4096
  unsigned short* updWf1 = wsf + 14336;   // 4096
  unsigned short* msgWf0 = wsf + 18432;   // 8192
  unsigned short* msgWf1 = wsf + 26624;   // 8192
  // neWf = wsf + 34816;                  // 2048 -> total 36864 shorts

  const float* W3a = msg_w + 128 * 64;
  const float* W3b = msg_w + (size_t)192 * 64 + 128 * 64;

  const size_t fixed_floats = (size_t)N * 64 * 4 + (size_t)G * 64 + G;
  const bool pre = (ws_size / 4 >= fixed_floats + 18432 + 64);

  const int nblk  = (N + 3) / 4;     // scalar node blocks
  const int nblkM = (N + 63) / 64;   // MFMA node blocks (64 rows)
  const int eblkM = (E + 63) / 64;   // MFMA edge blocks
  const int eblkF = (E + 15) / 16;   // fallback edge blocks
  const int pblk  = (4608 + (G * 64 + G + 3) / 4 + 255) / 256;  // pack+zero

  if (pre) {
    // ONE launch: all fragment packs + gsum/gcnt zero
    k_pack_all<<<pblk, 256, 0, stream>>>(ne_w, ee_w, msg_w, upd_w, wsf, gsum, G);

    k_embed_msgw_mfma<<<nblkM, 256, 0, stream>>>(
        x, wsf + 34816, ne_b, ne_g, ne_be, msgWf0, h, hw1, hw2, agg, N);
    // layer 0
    k_edge_msg_mfma<<<eblkM, 256, 0, stream>>>(
        ea, W3f0, eeWf, ee_b, ee_g, ee_be,
        msg_b, msg_g, msg_be, hw1, hw2, srcI, dstI, agg, E);
    k_update_msgw_mfma<<<nblkM, 256, 0, stream>>>(
        h, agg, updWf0, upd_b, upd_g, upd_be, nrm_g, nrm_be,
        msgWf1, hw1, hw2, N);
    // layer 1
    k_edge_msg_mfma<<<eblkM, 256, 0, stream>>>(
        ea, W3f1, eeWf, ee_b, ee_g, ee_be,
        msg_b + 64, msg_g + 64, msg_be + 64, hw1, hw2, srcI, dstI, agg, E);
    k_update_pool_mfma<<<nblkM, 256, 0, stream>>>(
        h, agg, updWf1, upd_b + 64, upd_g + 64, upd_be + 64,
        nrm_g + 64, nrm_be + 64, batch, gsum, gcnt, N);
  } else {
    k_embed_msgw<<<nblk, 256, 0, stream>>>(
        x, ne_w, ne_b, ne_g, ne_be, msg_w, h, hw1, hw2, agg, N);
    k_edge_msg_fb<<<eblkF, 256, 0, stream>>>(
        ea, ee_w, ee_b, ee_g, ee_be, W3a, msg_b, msg_g, msg_be,
        hw1, hw2, srcI, dstI, agg, E);
    k_update_msgw<<<nblk, 256, 0, stream>>>(
        h, agg, upd_w, upd_b, upd_g, upd_be, nrm_g, nrm_be,
        msg_w + (size_t)192 * 64, hw1, hw2, N);
    k_edge_msg_fb<<<eblkF, 256, 0, stream>>>(
        ea, ee_w, ee_b, ee_g, ee_be, W3b, msg_b + 64, msg_g + 64, msg_be + 64,
        hw1, hw2, srcI, dstI, agg, E);
    hipMemsetAsync(gsum, 0, ((size_t)G * 64 + G) * sizeof(float), stream);
    k_update_pool<<<nblk, 256, 0, stream>>>(
        h, agg, upd_w + (size_t)64 * 64, upd_b + 64, upd_g + 64, upd_be + 64,
        nrm_g + 64, nrm_be + 64, batch, gsum, gcnt, N);
  }

  k_head<<<G, 64, 0, stream>>>(gsum, gcnt, h1_w, h1_b, h1_g, h1_be, h2_w, h2_b, out, G);
}